// Round 22
// baseline (813.767 us; speedup 1.0000x reference)
//
#include <hip/hip_runtime.h>
#include <hip/hip_bf16.h>

typedef short bf16x8 __attribute__((ext_vector_type(8)));
typedef float f32x4 __attribute__((ext_vector_type(4)));

// ---------------- problem sizes ----------------
#define NB   4096
#define NEXP 16
#define DDIM 256
#define HDIM 1024
#define NCLS 1000

// ---------------- workspace layout (bytes) ----------------
// NOTE: Bb (conv2 out, 67 MB at offset 0) is live from conv12 until conv3 completes.
// ALL packed-weight regions below OFF_CHH alias Bb -> their pack kernels MUST run after conv3.
#define OFF_B    ((size_t)0)
#define OFF_P0   ((size_t)0)           // f32 [4096][256] FC partial (kq 0); ALSO yh after gate
#define OFF_P1   ((size_t)4194304)     // f32 [4096][256] FC partial (kq 1); ALSO yl after gate
#define OFF_W1TH ((size_t)8388608)     // bf16 packed [16][64 ht][8 ks][64 lane][8]  8 MB
#define OFF_W1TL ((size_t)16777216)
#define OFF_W2TH ((size_t)25165824)    // bf16 packed [16][16 dt][32 ks][64 lane][8] 8 MB
#define OFF_W2TL ((size_t)33554432)
#define OFF_WFCH ((size_t)41943040)    // fcw packed hi (1 MB)
#define OFF_WFCL ((size_t)42991616)    // fcw packed lo (1 MB)
#define OFF_P2   ((size_t)44040192)    // f32 [4096][256] FC partial (kq 2)
#define OFF_P3   ((size_t)48234496)    // f32 [4096][256] FC partial (kq 3)
#define OFF_OWH  ((size_t)52428800)    // ow packed hi [64 nt][8 ks][64][8] (512 KB)
#define OFF_OWL  ((size_t)53477376)
#define OFF_CHH  ((size_t)67108864)    // conv3 out hi bf16 [4096][2048]; ALSO wBh/wBl/wA1 before conv12
#define OFF_CHL  ((size_t)83886080)    // conv3 out lo bf16
#define OFF_WBL  ((size_t)67145728)
#define OFF_WA1H ((size_t)67182592)
#define OFF_WA1L ((size_t)67184640)
#define OFF_FEAT ((size_t)100663296)   // f32 [4096][256]; ALSO wAh/wAl (288 KB) before k_gate
#define OFF_WAL  ((size_t)100810752)
#define OFF_MOE  ((size_t)104857600)   // f32 [4096][256]
#define OFF_CNT  ((size_t)109051904)   // int [16]
#define OFF_GSUM ((size_t)109051968)   // f32 [16]
#define OFF_LROW ((size_t)109052032)   // int [16][4096]
#define OFF_LG   ((size_t)109314176)   // f32 [16][4096]

__device__ inline unsigned short f2bf(float v) {
  __hip_bfloat16 h = __float2bfloat16(v);
  return *(unsigned short*)&h;
}
__device__ inline float bf2f(unsigned short u) {
  union { unsigned int i; float f; } c; c.i = ((unsigned int)u) << 16; return c.f;
}

// ====== conv1 weight prep: c1w[oc][27] -> wA1[oc][32 K] bf16 hi/lo (K=ic*9+tap, pad 32)
__global__ __launch_bounds__(256) void k_wt1b(const float* __restrict__ w,
    unsigned short* __restrict__ oh, unsigned short* __restrict__ ol) {
  int i = blockIdx.x*256 + threadIdx.x;
  if (i >= 1024) return;
  int k = i & 31, oc = i >> 5;
  float v = (k < 27) ? w[oc*27 + k] : 0.f;
  unsigned short h = f2bf(v);
  oh[i] = h;
  ol[i] = f2bf(v - bf2f(h));
}

// ====== conv2 weight prep: c2w[oc][ic][tap] -> wBh/wBl[tap][oc][ic] bf16 hi/lo ======
__global__ __launch_bounds__(256) void k_wt2b(const float* __restrict__ w,
    unsigned short* __restrict__ wBh, unsigned short* __restrict__ wBl) {
  int i = blockIdx.x*256 + threadIdx.x;
  if (i >= 9*64*32) return;
  int ic = i & 31, rem = i >> 5;
  int oc = rem & 63, tap = rem >> 6;
  float v = w[(oc*32 + ic)*9 + tap];
  unsigned short h = f2bf(v);
  wBh[i] = h;
  wBl[i] = f2bf(v - bf2f(h));
}

// ====== MFMA-native weight pack: in[e][R=k][C=n] -> packed[e][n/16][R/32][64 lane][8] hi/lo
__global__ __launch_bounds__(256) void k_pack(const float* __restrict__ in,
    unsigned short* __restrict__ oh, unsigned short* __restrict__ ol, int R, int C) {
  __shared__ float tile[64][65];
  const int t = threadIdx.x;
  const int e = blockIdx.z;
  const size_t eb = (size_t)e * R * C;
  const int c0 = blockIdx.x*64, r0 = blockIdx.y*64;
  const int cc = t & 63, r4 = t >> 6;
  #pragma unroll
  for (int j = 0; j < 16; ++j) {
    int rr = r4 + j*4;
    tile[rr][cc] = in[eb + (size_t)(r0+rr)*C + c0 + cc];
  }
  __syncthreads();
  const int K32 = R >> 5;
  #pragma unroll
  for (int j = 0; j < 16; ++j) {
    int idx = t + j*256;
    int jin = idx & 7, lane = (idx >> 3) & 63, ksl = (idx >> 9) & 1, ntl = idx >> 10;
    int kl = ksl*32 + ((lane >> 4) << 3) + jin;
    int nl = ntl*16 + (lane & 15);
    float v = tile[kl][nl];
    unsigned short h = f2bf(v);
    size_t o = eb + ((size_t)(((c0 >> 4) + ntl)*K32 + (r0 >> 5) + ksl)*64 + lane)*8 + jin;
    oh[o] = h;
    ol[o] = f2bf(v - bf2f(h));
  }
}

// ====== ow pack: ow[256 k][1000 n] -> packed[64 nt][8 ks][64 lane][8] hi/lo, zero pad n>=1000
__global__ __launch_bounds__(256) void k_packo(const float* __restrict__ ow,
    unsigned short* __restrict__ oh, unsigned short* __restrict__ ol) {
  int i = blockIdx.x*256 + threadIdx.x;   // over 64*8*64*8 = 262144
  int j = i & 7, lane = (i >> 3) & 63, ks = (i >> 9) & 7, nt = i >> 12;
  int k = ks*32 + ((lane >> 4) << 3) + j;
  int n = nt*16 + (lane & 15);
  float v = (n < NCLS) ? ow[(size_t)k*NCLS + n] : 0.f;
  unsigned short h = f2bf(v);
  oh[i] = h;
  ol[i] = f2bf(v - bf2f(h));
}

// ============ fused conv1(reg-im2col bf16x2 MFMA) + conv2(bf16x2 MFMA, 3-term) per image ====
// Register-trimmed (R22): conv1 builds one row's fragments at a time (2 live unions);
// conv2 loads A-frags directly per tap (no prefetch double-buffer). Per-acc math order
// unchanged -> bit-exact with R21. launch_bounds(512,4): 2 blocks/CU (R20 lesson).
__global__ __launch_bounds__(512, 4) void k_conv12(const float* __restrict__ x,
    const unsigned short* __restrict__ wA1h, const unsigned short* __restrict__ wA1l,
    const float* __restrict__ b1,
    const unsigned short* __restrict__ wBh, const unsigned short* __restrict__ wBl,
    const float* __restrict__ b2, float* __restrict__ outB) {
  __shared__ unsigned int xsu[3*34*36];     // packed bf16 hi/lo image (14.7 KB)
  __shared__ unsigned short ishB[2][10368]; // conv1-out hi/lo swizzled (41.5 KB); reused for store
  __shared__ float bs1[32];
  __shared__ float bs2[64];
  const int t = threadIdx.x;
  const int img = blockIdx.x;
  for (int i = t; i < 3*34*36; i += 512) xsu[i] = 0u;
  {
    unsigned int* z = (unsigned int*)&ishB[0][0];
    for (int i = t; i < 10368; i += 512) z[i] = 0u;
  }
  __syncthreads();
  for (int i = t; i < 3072; i += 512) {
    int ic = i >> 10, rem = i & 1023, y = rem >> 5, xx = rem & 31;
    float v = x[(size_t)img*3072 + i];
    unsigned short h = f2bf(v);
    unsigned short l = f2bf(v - bf2f(h));
    xsu[ic*34*36 + (y+1)*36 + (xx+1)] = ((unsigned int)l << 16) | (unsigned int)h;
  }
  if (t < 32) bs1[t] = b1[t];
  else if (t >= 64 && t < 128) bs2[t-64] = b2[t-64];

  const int lane = t & 63, wvv = t >> 6;
  const int lr = lane & 15, lq = lane >> 4;

  const int oct1 = wvv & 1;
  const bf16x8 a1h = *(const bf16x8*)&wA1h[((oct1*16 + lr) << 5) + lq*8];
  const bf16x8 a1l = *(const bf16x8*)&wA1l[((oct1*16 + lr) << 5) + lq*8];

  // per-lane k -> xsu offset table (k = lq*8 + j); koff < 0 marks padded k (>= 27)
  int koff[8];
  #pragma unroll
  for (int j = 0; j < 8; ++j) {
    int k = lq*8 + j;
    if (k < 27) {
      int ic = k/9, tap = k - ic*9, dy = tap/3, dx = tap - dy*3;
      koff[j] = ic*34*36 + dy*36 + dx;
    } else koff[j] = -1;
  }
  __syncthreads();

  // ---- conv1 via MFMA, barrier-free: 8 passes of 4 pre-pool rows ----
  {
    const int rp  = wvv >> 1;
    const int ly0 = (rp >> 1) << 1;      // 0 or 2
    const int xh  = rp & 1;
    const int X   = xh*16 + lr;          // column for this lane's B elements
    for (int ps = 0; ps < 8; ++ps) {
      const int baseA = (ps*4 + ly0)*36 + X;
      f32x4 aA = (f32x4){0.f,0.f,0.f,0.f}, aB = (f32x4){0.f,0.f,0.f,0.f};
      // row A: build frags, 3 MFMAs (same per-acc term order: h*bh, h*bl, l*bh)
      {
        union { unsigned int u[4]; bf16x8 v; } bh_, bl_;
        #pragma unroll
        for (int jj = 0; jj < 4; ++jj) {
          unsigned int e0 = (koff[2*jj]   >= 0) ? xsu[koff[2*jj]   + baseA] : 0u;
          unsigned int e1 = (koff[2*jj+1] >= 0) ? xsu[koff[2*jj+1] + baseA] : 0u;
          bh_.u[jj] = __builtin_amdgcn_perm(e1, e0, 0x05040100u);
          bl_.u[jj] = __builtin_amdgcn_perm(e1, e0, 0x07060302u);
        }
        aA = __builtin_amdgcn_mfma_f32_16x16x32_bf16(a1h, bh_.v, aA, 0, 0, 0);
        aA = __builtin_amdgcn_mfma_f32_16x16x32_bf16(a1h, bl_.v, aA, 0, 0, 0);
        aA = __builtin_amdgcn_mfma_f32_16x16x32_bf16(a1l, bh_.v, aA, 0, 0, 0);
      }
      // row B
      {
        union { unsigned int u[4]; bf16x8 v; } bh_, bl_;
        #pragma unroll
        for (int jj = 0; jj < 4; ++jj) {
          unsigned int e0 = (koff[2*jj]   >= 0) ? xsu[koff[2*jj]   + baseA + 36] : 0u;
          unsigned int e1 = (koff[2*jj+1] >= 0) ? xsu[koff[2*jj+1] + baseA + 36] : 0u;
          bh_.u[jj] = __builtin_amdgcn_perm(e1, e0, 0x05040100u);
          bl_.u[jj] = __builtin_amdgcn_perm(e1, e0, 0x07060302u);
        }
        aB = __builtin_amdgcn_mfma_f32_16x16x32_bf16(a1h, bh_.v, aB, 0, 0, 0);
        aB = __builtin_amdgcn_mfma_f32_16x16x32_bf16(a1h, bl_.v, aB, 0, 0, 0);
        aB = __builtin_amdgcn_mfma_f32_16x16x32_bf16(a1l, bh_.v, aB, 0, 0, 0);
      }
      #pragma unroll
      for (int r = 0; r < 4; ++r) {
        float v = fmaxf(aA[r], aB[r]);             // y-pool (row pair in-registers)
        v = fmaxf(v, __shfl_xor(v, 1, 64));        // x-pool (col pair)
        if ((lr & 1) == 0) {
          int oc = oct1*16 + lq*4 + r;             // D row = (lane>>4)*4+reg
          int Xp = xh*8 + (lr >> 1);
          int Yp = ps*2 + (ly0 >> 1);
          float m = fmaxf(v + bs1[oc], 0.f);
          unsigned short h = f2bf(m);
          unsigned short l = f2bf(m - bf2f(h));
          int pl = (Yp+1)*18 + (Xp+1);
          int sl = pl*4 + ((oc >> 3) ^ ((pl >> 1) & 3));
          int us = (sl << 3) | (oc & 7);
          ishB[0][us] = h; ishB[1][us] = l;
        }
      }
    }
  }
  __syncthreads();
  // ---- conv2 bf16x2 MFMA (3-term) + fused pool + relu; A loaded directly per tap ----
  {
    const int mtp = (wvv & 1)*2;
    const int rq = wvv >> 1;
    f32x4 acc[2][4];
    #pragma unroll
    for (int i = 0; i < 2; ++i)
      #pragma unroll
      for (int j = 0; j < 4; ++j) acc[i][j] = (f32x4){0.f,0.f,0.f,0.f};
    #pragma unroll
    for (int tap = 0; tap < 9; ++tap) {
      const int off0 = ((tap*64 + mtp*16     + lr) << 5) + lq*8;
      const int off1 = ((tap*64 + (mtp+1)*16 + lr) << 5) + lq*8;
      bf16x8 ah0 = *(const bf16x8*)&wBh[off0];
      bf16x8 al0 = *(const bf16x8*)&wBl[off0];
      bf16x8 ah1 = *(const bf16x8*)&wBh[off1];
      bf16x8 al1 = *(const bf16x8*)&wBl[off1];
      const int dy = tap/3, dx = tap - dy*3;
      #pragma unroll
      for (int j = 0; j < 4; ++j) {
        int pl = (rq*4 + j + dy)*18 + lr + dx;
        int sl = pl*4 + (lq ^ ((pl >> 1) & 3));
        bf16x8 bh = *(const bf16x8*)&ishB[0][sl << 3];
        bf16x8 bl = *(const bf16x8*)&ishB[1][sl << 3];
        acc[0][j] = __builtin_amdgcn_mfma_f32_16x16x32_bf16(ah0, bh, acc[0][j], 0, 0, 0);
        acc[1][j] = __builtin_amdgcn_mfma_f32_16x16x32_bf16(ah1, bh, acc[1][j], 0, 0, 0);
        acc[0][j] = __builtin_amdgcn_mfma_f32_16x16x32_bf16(ah0, bl, acc[0][j], 0, 0, 0);
        acc[1][j] = __builtin_amdgcn_mfma_f32_16x16x32_bf16(ah1, bl, acc[1][j], 0, 0, 0);
        acc[0][j] = __builtin_amdgcn_mfma_f32_16x16x32_bf16(al0, bh, acc[0][j], 0, 0, 0);
        acc[1][j] = __builtin_amdgcn_mfma_f32_16x16x32_bf16(al1, bh, acc[1][j], 0, 0, 0);
      }
    }
    __syncthreads();
    float* ps2 = (float*)&ishB[0][0];
    #pragma unroll
    for (int m = 0; m < 2; ++m)
      #pragma unroll
      for (int k = 0; k < 2; ++k)
        #pragma unroll
        for (int r = 0; r < 4; ++r) {
          float v = fmaxf(acc[m][2*k][r], acc[m][2*k+1][r]);
          v = fmaxf(v, __shfl_xor(v, 1, 64));
          if ((lr & 1) == 0) {
            int oc = (mtp + m)*16 + lq*4 + r;
            int Y = rq*2 + k, X = lr >> 1;
            ps2[oc*65 + Y*8 + X] = fmaxf(v + bs2[oc], 0.f);
          }
        }
    __syncthreads();
    float* op = outB + (size_t)img*4096;
    #pragma unroll
    for (int jj = 0; jj < 8; ++jj) {
      int i = jj*512 + t;
      op[i] = ps2[(i >> 6)*65 + (i & 63)];
    }
  }
}

// ================= conv3 weight prep: c3w[oc][ic][tap] -> wAh/wAl[tap][oc][ic] bf16 hi/lo
__global__ __launch_bounds__(256) void k_wt3b(const float* __restrict__ w,
    unsigned short* __restrict__ wAh, unsigned short* __restrict__ wAl) {
  int i = blockIdx.x*256 + threadIdx.x;
  if (i >= 9*128*64) return;
  int ic = i & 63, rem = i >> 6;
  int oc = rem & 127, tap = rem >> 7;
  float v = w[(oc*64 + ic)*9 + tap];
  unsigned short h = f2bf(v);
  wAh[i] = h;
  wAl[i] = f2bf(v - bf2f(h));
}

// ================= conv3 v5: bf16x2 split MFMA (3-term); emits C as bf16 hi/lo ==========
__global__ __launch_bounds__(256) void k_conv3(const float* __restrict__ inB,
    const unsigned short* __restrict__ wAh, const unsigned short* __restrict__ wAl,
    const float* __restrict__ bias,
    unsigned short* __restrict__ Chh, unsigned short* __restrict__ Chl) {
  __shared__ unsigned short ish[2][6400];
  const int t = threadIdx.x;
  const int img = blockIdx.x;
  {
    unsigned int* z = (unsigned int*)&ish[0][0];
    #pragma unroll
    for (int j = 0; j < 25; ++j) z[t + 256*j] = 0u;
  }
  __syncthreads();
  {
    const float* src = inB + (size_t)img*4096;
    #pragma unroll
    for (int j = 0; j < 16; ++j) {
      int f = t + 256*j;
      int ic = f >> 6, p = f & 63;
      int pl = ((p >> 3) + 1)*10 + (p & 7) + 1;
      float v = src[f];
      unsigned short h = f2bf(v);
      unsigned short l = f2bf(v - bf2f(h));
      int u = pl*64 + ic;
      int us = (((u >> 3) ^ (pl & 7)) << 3) | (u & 7);
      ish[0][us] = h; ish[1][us] = l;
    }
  }
  __syncthreads();

  const int lane = t & 63, wid = t >> 6;
  const int lr = lane & 15, lq = lane >> 4;
  const int mt0 = wid*2;
  const int yb = lr >> 3, xb = lr & 7;

  f32x4 acc[2][4];
  #pragma unroll
  for (int i = 0; i < 2; ++i)
    #pragma unroll
    for (int j = 0; j < 4; ++j) acc[i][j] = (f32x4){0.f,0.f,0.f,0.f};

  for (int tap = 0; tap < 9; ++tap) {
    const int dy = tap/3, dx = tap - dy*3;
    #pragma unroll
    for (int kc = 0; kc < 2; ++kc) {
      const int kb = kc*32 + lq*8;
      const int wbase = ((tap << 7) << 6) + kb;
      bf16x8 a0h = *(const bf16x8*)&wAh[wbase + ((mt0*16 + lr) << 6)];
      bf16x8 a0l = *(const bf16x8*)&wAl[wbase + ((mt0*16 + lr) << 6)];
      bf16x8 a1h = *(const bf16x8*)&wAh[wbase + (((mt0+1)*16 + lr) << 6)];
      bf16x8 a1l = *(const bf16x8*)&wAl[wbase + (((mt0+1)*16 + lr) << 6)];
      #pragma unroll
      for (int nt = 0; nt < 4; ++nt) {
        const int pl = (2*nt + yb + dy)*10 + xb + dx;
        const int u = pl*64 + kb;
        const int us = (((u >> 3) ^ (pl & 7)) << 3);
        bf16x8 bh = *(const bf16x8*)&ish[0][us];
        bf16x8 bl = *(const bf16x8*)&ish[1][us];
        acc[0][nt] = __builtin_amdgcn_mfma_f32_16x16x32_bf16(a0h, bh, acc[0][nt], 0, 0, 0);
        acc[0][nt] = __builtin_amdgcn_mfma_f32_16x16x32_bf16(a0h, bl, acc[0][nt], 0, 0, 0);
        acc[0][nt] = __builtin_amdgcn_mfma_f32_16x16x32_bf16(a0l, bh, acc[0][nt], 0, 0, 0);
        acc[1][nt] = __builtin_amdgcn_mfma_f32_16x16x32_bf16(a1h, bh, acc[1][nt], 0, 0, 0);
        acc[1][nt] = __builtin_amdgcn_mfma_f32_16x16x32_bf16(a1h, bl, acc[1][nt], 0, 0, 0);
        acc[1][nt] = __builtin_amdgcn_mfma_f32_16x16x32_bf16(a1l, bh, acc[1][nt], 0, 0, 0);
      }
    }
  }
  __syncthreads();
  float* stg = (float*)&ish[0][0];   // [128 oc][17]
  #pragma unroll
  for (int mtl = 0; mtl < 2; ++mtl)
    #pragma unroll
    for (int nt = 0; nt < 4; ++nt)
      #pragma unroll
      for (int r = 0; r < 4; ++r) {
        float v = acc[mtl][nt][r];
        v = fmaxf(v, __shfl_xor(v, 1, 64));
        v = fmaxf(v, __shfl_xor(v, 8, 64));
        if ((lane & 9) == 0) {
          int oc = (mt0 + mtl)*16 + lq*4 + r;
          int pix = nt*4 + (xb >> 1);
          stg[oc*17 + pix] = fmaxf(v + bias[oc], 0.f);
        }
      }
  __syncthreads();
  #pragma unroll
  for (int j = 0; j < 8; ++j) {
    int i = t + 256*j;
    float v = stg[(i >> 4)*17 + (i & 15)];
    unsigned short h = f2bf(v);
    Chh[(size_t)img*2048 + i] = h;
    Chl[(size_t)img*2048 + i] = f2bf(v - bf2f(h));
  }
}

// ================= FC GEMM v2: bf16x2 3-term MFMA, no LDS, split-K=4 =================
__global__ __launch_bounds__(256) void k_fc(const unsigned short* __restrict__ Chh,
    const unsigned short* __restrict__ Chl,
    const unsigned short* __restrict__ wfh, const unsigned short* __restrict__ wfl,
    float* __restrict__ P0, float* __restrict__ P1,
    float* __restrict__ P2, float* __restrict__ P3) {
  const int t = threadIdx.x;
  const int r0 = blockIdx.x * 32;
  const int kq = blockIdx.z;
  float* __restrict__ P = (kq == 0) ? P0 : (kq == 1) ? P1 : (kq == 2) ? P2 : P3;
  const int lane = t & 63, wv = t >> 6;
  const int lr = lane & 15, lq = lane >> 4;
  f32x4 acc[2][4];
  #pragma unroll
  for (int i = 0; i < 2; ++i)
    #pragma unroll
    for (int j = 0; j < 4; ++j) acc[i][j] = (f32x4){0.f,0.f,0.f,0.f};
  #pragma unroll 4
  for (int ks = 0; ks < 16; ++ks) {
    bf16x8 ah[2], al[2];
    #pragma unroll
    for (int rt = 0; rt < 2; ++rt) {
      size_t ao = (size_t)(r0 + rt*16 + lr)*2048 + kq*512 + ks*32 + lq*8;
      ah[rt] = *(const bf16x8*)&Chh[ao];
      al[rt] = *(const bf16x8*)&Chl[ao];
    }
    #pragma unroll
    for (int nt = 0; nt < 4; ++nt) {
      size_t bo = ((size_t)((wv*4 + nt)*64 + kq*16 + ks)*64 + lane)*8;
      bf16x8 bh = *(const bf16x8*)&wfh[bo];
      bf16x8 bl = *(const bf16x8*)&wfl[bo];
      acc[0][nt] = __builtin_amdgcn_mfma_f32_16x16x32_bf16(ah[0], bh, acc[0][nt], 0, 0, 0);
      acc[1][nt] = __builtin_amdgcn_mfma_f32_16x16x32_bf16(ah[1], bh, acc[1][nt], 0, 0, 0);
      acc[0][nt] = __builtin_amdgcn_mfma_f32_16x16x32_bf16(ah[0], bl, acc[0][nt], 0, 0, 0);
      acc[1][nt] = __builtin_amdgcn_mfma_f32_16x16x32_bf16(ah[1], bl, acc[1][nt], 0, 0, 0);
      acc[0][nt] = __builtin_amdgcn_mfma_f32_16x16x32_bf16(al[0], bh, acc[0][nt], 0, 0, 0);
      acc[1][nt] = __builtin_amdgcn_mfma_f32_16x16x32_bf16(al[1], bh, acc[1][nt], 0, 0, 0);
    }
  }
  #pragma unroll
  for (int rt = 0; rt < 2; ++rt)
    #pragma unroll
    for (int nt = 0; nt < 4; ++nt)
      #pragma unroll
      for (int r = 0; r < 4; ++r)
        P[(size_t)(r0 + rt*16 + lq*4 + r)*256 + (wv*4 + nt)*16 + lr] = acc[rt][nt][r];
}

// ================= gate: feat = P0+P1+P2+P3+fcb; logits; top-2 softmax; expert lists
__global__ __launch_bounds__(256) void k_gate(const float* __restrict__ P0,
    const float* __restrict__ P1, const float* __restrict__ P2, const float* __restrict__ P3,
    const float* __restrict__ fcb,
    const float* __restrict__ gw, const float* __restrict__ gb,
    float* __restrict__ feat, int* __restrict__ cnt, float* __restrict__ gsum,
    int* __restrict__ lrow, float* __restrict__ lg) {
  __shared__ float ft[16][256];
  __shared__ float lgs[16][16];
  __shared__ float gwl[4096];
  const int t = threadIdx.x;
  const int r0 = blockIdx.x * 16;
  for (int i = t; i < 4096; i += 256) gwl[i] = gw[i];
  float bb = fcb[t];
  #pragma unroll
  for (int r = 0; r < 16; ++r) {
    size_t off = (size_t)(r0+r)*256 + t;
    float v = P0[off] + P1[off] + P2[off] + P3[off] + bb;
    ft[r][t] = v;
    feat[off] = v;
  }
  __syncthreads();
  {
    int r = t >> 4, e = t & 15;
    float s = gb[e];
    for (int k = 0; k < 256; ++k) s = fmaf(ft[r][k], gwl[k*16 + e], s);
    lgs[r][e] = s;
  }
  __syncthreads();
  if (t < 16) {
    int r = t;
    float v1 = -3.402823e38f, v2 = -3.402823e38f;
    int i1 = 0, i2 = 0;
    for (int e = 0; e < 16; ++e) {
      float v = lgs[r][e];
      if (v > v1)      { v2 = v1; i2 = i1; v1 = v; i1 = e; }
      else if (v > v2) { v2 = v;  i2 = e; }
    }
    float ex = __expf(v2 - v1);
    float g1 = 1.f / (1.f + ex);
    float g2 = ex  / (1.f + ex);
    int row = r0 + r;
    int p1 = atomicAdd(&cnt[i1], 1); lrow[i1*4096 + p1] = row; lg[i1*4096 + p1] = g1;
    int p2 = atomicAdd(&cnt[i2], 1); lrow[i2*4096 + p2] = row; lg[i2*4096 + p2] = g2;
    atomicAdd(&gsum[i1], g1);
    atomicAdd(&gsum[i2], g2);
  }
}

// ================= MoE v4: 32-row tiles x split-K(8), bf16x2 MFMA 3-term, packed weights
__global__ __launch_bounds__(256) void k_moe(const float* __restrict__ feat,
    const unsigned short* __restrict__ w1th, const unsigned short* __restrict__ w1tl,
    const unsigned short* __restrict__ w2th, const unsigned short* __restrict__ w2tl,
    const float* __restrict__ eb1, const float* __restrict__ eb2,
    const int* __restrict__ cnt, const int* __restrict__ lrow, const float* __restrict__ lgw,
    float* __restrict__ moe) {
  const int e = blockIdx.y;
  const int n_e = cnt[e];
  const int start = blockIdx.x * 32;
  if (start >= n_e) return;
  const int c = blockIdx.z;
  const int n = min(32, n_e - start);
  __shared__ unsigned short fh[8192], fl[8192];
  __shared__ unsigned short h1h[4096], h1l[4096];
  __shared__ int   rws[32];
  __shared__ float gws[32];
  const int t = threadIdx.x;
  if (t < 32) {
    rws[t] = (t < n) ? lrow[e*4096 + start + t] : 0;
    gws[t] = (t < n) ? lgw[e*4096 + start + t] : 0.f;
  }
  __syncthreads();
  for (int j = 0; j < 32; ++j) {
    float v = (j < n) ? feat[(size_t)rws[j]*256 + t] : 0.f;
    unsigned short h = f2bf(v);
    int us = (j*32 + ((t >> 3) ^ (j & 7)))*8 + (t & 7);
    fh[us] = h; fl[us] = f2bf(v - bf2f(h));
  }
  const int lane = t & 63, wv = t >> 6;
  const int lr = lane & 15, lq = lane >> 4;
  const int rh = wv & 1, qh = wv >> 1;
  const int arow = rh*16 + lr;
  const int rsw = arow & 7;
  const size_t ewb = (size_t)e << 18;

  f32x4 acc2[8];
  #pragma unroll
  for (int i = 0; i < 8; ++i) acc2[i] = (f32x4){0.f,0.f,0.f,0.f};

  __syncthreads();

  {
    f32x4 acc1[4];
    #pragma unroll
    for (int i = 0; i < 4; ++i) acc1[i] = (f32x4){0.f,0.f,0.f,0.f};
    #pragma unroll
    for (int ks = 0; ks < 8; ++ks) {
      int aoff = (arow*32 + ((ks*4 + lq) ^ rsw))*8;
      bf16x8 ah = *(const bf16x8*)&fh[aoff];
      bf16x8 al = *(const bf16x8*)&fl[aoff];
      #pragma unroll
      for (int ht = 0; ht < 4; ++ht) {
        int htile = c*8 + qh*4 + ht;
        size_t bo = ewb + ((size_t)(htile*8 + ks)*64 + lane)*8;
        bf16x8 bh = *(const bf16x8*)&w1th[bo];
        bf16x8 bl = *(const bf16x8*)&w1tl[bo];
        acc1[ht] = __builtin_amdgcn_mfma_f32_16x16x32_bf16(ah, bh, acc1[ht], 0, 0, 0);
        acc1[ht] = __builtin_amdgcn_mfma_f32_16x16x32_bf16(ah, bl, acc1[ht], 0, 0, 0);
        acc1[ht] = __builtin_amdgcn_mfma_f32_16x16x32_bf16(al, bh, acc1[ht], 0, 0, 0);
      }
    }
    __syncthreads();
    #pragma unroll
    for (int ht = 0; ht < 4; ++ht) {
      int hloc = qh*64 + ht*16 + lr;
      float bb = eb1[e*1024 + c*128 + hloc];
      #pragma unroll
      for (int r = 0; r < 4; ++r) {
        int orow = rh*16 + lq*4 + r;
        float v = fmaxf(acc1[ht][r] + bb, 0.f);
        unsigned short hh = f2bf(v);
        int us = (orow*16 + ((hloc >> 3) ^ (orow & 7)))*8 + (hloc & 7);
        h1h[us] = hh; h1l[us] = f2bf(v - bf2f(hh));
      }
    }
    __syncthreads();
    #pragma unroll
    for (int ks = 0; ks < 4; ++ks) {
      int aoff = (arow*16 + ((ks*4 + lq) ^ rsw))*8;
      bf16x8 ah = *(const bf16x8*)&h1h[aoff];
      bf16x8 al = *(const bf16x8*)&h1l[aoff];
      #pragma unroll
      for (int dt = 0; dt < 8; ++dt) {
        int dtile = qh*8 + dt;
        size_t bo = ewb + ((size_t)(dtile*32 + c*4 + ks)*64 + lane)*8;
        bf16x8 bh = *(const bf16x8*)&w2th[bo];
        bf16x8 bl = *(const bf16x8*)&w2tl[bo];
        acc2[dt] = __builtin_amdgcn_mfma_f32_16x16x32_bf16(ah, bh, acc2[dt], 0, 0, 0);
        acc2[dt] = __builtin_amdgcn_mfma_f32_16x16x32_bf16(ah, bl, acc2[dt], 0, 0, 0);
        acc2[dt] = __builtin_amdgcn_mfma_f32_16x16x32_bf16(al, bh, acc2[dt], 0, 0, 0);
      }
    }
  }
  #pragma unroll
  for (int dt = 0; dt < 8; ++dt) {
    int d = qh*128 + dt*16 + lr;
    float b2 = (c == 0) ? eb2[e*256 + d] : 0.f;
    #pragma unroll
    for (int r = 0; r < 4; ++r) {
      int orow = rh*16 + lq*4 + r;
      if (orow < n)
        atomicAdd(&moe[(size_t)rws[orow]*256 + d], gws[orow]*(acc2[dt][r] + b2));
    }
  }
}

// ================= load-balance loss
__global__ void k_lb(const float* __restrict__ gsum, float* __restrict__ out_lb) {
  int t = threadIdx.x;
  float term = 0.f;
  if (t < 16) {
    float D = gsum[t] * (1.f/4096.f);
    term = D * logf(D + 1e-8f);
  }
  #pragma unroll
  for (int o = 8; o > 0; o >>= 1) term += __shfl_down(term, o, 64);
  if (t == 0) *out_lb = term;
}

// ================= LayerNorm(moe + feat) -> y bf16 hi/lo =================
__global__ __launch_bounds__(256) void k_ln(const float* __restrict__ feat,
    const float* __restrict__ moe, const float* __restrict__ g, const float* __restrict__ bp,
    unsigned short* __restrict__ yh, unsigned short* __restrict__ yl) {
  const int r = blockIdx.x, t = threadIdx.x;
  float v = moe[(size_t)r*256 + t] + feat[(size_t)r*256 + t];
  float s = v, q = v * v;
  #pragma unroll
  for (int o = 32; o > 0; o >>= 1) {
    s += __shfl_down(s, o, 64);
    q += __shfl_down(q, o, 64);
  }
  __shared__ float ss[4], qq[4];
  int wv = t >> 6;
  if ((t & 63) == 0) { ss[wv] = s; qq[wv] = q; }
  __syncthreads();
  float S = ss[0]+ss[1]+ss[2]+ss[3];
  float Q = qq[0]+qq[1]+qq[2]+qq[3];
  float mu  = S * (1.f/256.f);
  float var = Q * (1.f/256.f) - mu*mu;
  float inv = rsqrtf(var + 1e-5f);
  float y = (v - mu) * inv * g[t] + bp[t];
  unsigned short h = f2bf(y);
  yh[(size_t)r*256 + t] = h;
  yl[(size_t)r*256 + t] = f2bf(y - bf2f(h));
}

// ================= output GEMM v2: bf16x2 3-term MFMA, no LDS =================
__global__ __launch_bounds__(256) void k_out(const unsigned short* __restrict__ yh,
    const unsigned short* __restrict__ yl,
    const unsigned short* __restrict__ owh, const unsigned short* __restrict__ owl,
    const float* __restrict__ ob, float* __restrict__ out) {
  const int t = threadIdx.x;
  const int r0 = blockIdx.x * 32;
  const int lane = t & 63, wv = t >> 6;
  const int lr = lane & 15, lq = lane >> 4;
  const int ntile = blockIdx.y*4 + wv;
  f32x4 acc[2];
  acc[0] = (f32x4){0.f,0.f,0.f,0.f};
  acc[1] = (f32x4){0.f,0.f,0.f,0.f};
  #pragma unroll
  for (int ks = 0; ks < 8; ++ks) {
    bf16x8 bh = *(const bf16x8*)&owh[((size_t)(ntile*8 + ks)*64 + lane)*8];
    bf16x8 bl = *(const bf16x8*)&owl[((size_t)(ntile*8 + ks)*64 + lane)*8];
    #pragma unroll
    for (int rt = 0; rt < 2; ++rt) {
      size_t ao = (size_t)(r0 + rt*16 + lr)*256 + ks*32 + lq*8;
      bf16x8 ah = *(const bf16x8*)&yh[ao];
      bf16x8 al = *(const bf16x8*)&yl[ao];
      acc[rt] = __builtin_amdgcn_mfma_f32_16x16x32_bf16(ah, bh, acc[rt], 0, 0, 0);
      acc[rt] = __builtin_amdgcn_mfma_f32_16x16x32_bf16(ah, bl, acc[rt], 0, 0, 0);
      acc[rt] = __builtin_amdgcn_mfma_f32_16x16x32_bf16(al, bh, acc[rt], 0, 0, 0);
    }
  }
  const int col = ntile*16 + lr;
  if (col < NCLS) {
    float bb = ob[col];
    #pragma unroll
    for (int rt = 0; rt < 2; ++rt)
      #pragma unroll
      for (int r = 0; r < 4; ++r)
        out[(size_t)(r0 + rt*16 + lq*4 + r)*NCLS + col] = acc[rt][r] + bb;
  }
}

// ================= launch =================
extern "C" void kernel_launch(void* const* d_in, const int* in_sizes, int n_in,
                              void* d_out, int out_size, void* d_ws, size_t ws_size,
                              hipStream_t stream) {
  const float* x   = (const float*)d_in[0];
  const float* c1w = (const float*)d_in[1];
  const float* c1b = (const float*)d_in[2];
  const float* c2w = (const float*)d_in[3];
  const float* c2b = (const float*)d_in[4];
  const float* c3w = (const float*)d_in[5];
  const float* c3b = (const float*)d_in[6];
  const float* fcw = (const float*)d_in[7];
  const float* fcb = (const float*)d_in[8];
  const float* gw  = (const float*)d_in[9];
  const float* gb  = (const float*)d_in[10];
  const float* ew1 = (const float*)d_in[11];
  const float* eb1 = (const float*)d_in[12];
  const float* ew2 = (const float*)d_in[13];
  const float* eb2 = (const float*)d_in[14];
  const float* lng = (const float*)d_in[15];
  const float* lnb = (const float*)d_in[16];
  const float* ow  = (const float*)d_in[17];
  const float* ob  = (const float*)d_in[18];
  char* ws = (char*)d_ws;
  float* Bb   = (float*)(ws + OFF_B);
  float* P0   = (float*)(ws + OFF_P0);
  float* P1   = (float*)(ws + OFF_P1);
  float* P2   = (float*)(ws + OFF_P2);
  float* P3   = (float*)(ws + OFF_P3);
  unsigned short* Chh = (unsigned short*)(ws + OFF_CHH);
  unsigned short* Chl = (unsigned short*)(ws + OFF_CHL);
  unsigned short* wBh = (unsigned short*)(ws + OFF_CHH);   // aliases Chh (written after conv12)
  unsigned short* wBl = (unsigned short*)(ws + OFF_WBL);
  unsigned short* wA1h = (unsigned short*)(ws + OFF_WA1H);
  unsigned short* wA1l = (unsigned short*)(ws + OFF_WA1L);
  unsigned short* wAh = (unsigned short*)(ws + OFF_FEAT);  // aliases feat (written later)
  unsigned short* wAl = (unsigned short*)(ws + OFF_WAL);
  unsigned short* w1th = (unsigned short*)(ws + OFF_W1TH);
  unsigned short* w1tl = (unsigned short*)(ws + OFF_W1TL);
  unsigned short* w2th = (unsigned short*)(ws + OFF_W2TH);
  unsigned short* w2tl = (unsigned short*)(ws + OFF_W2TL);
  unsigned short* wfh = (unsigned short*)(ws + OFF_WFCH);
  unsigned short* wfl = (unsigned short*)(ws + OFF_WFCL);
  unsigned short* owph = (unsigned short*)(ws + OFF_OWH);
  unsigned short* owpl = (unsigned short*)(ws + OFF_OWL);
  unsigned short* yh = (unsigned short*)(ws + OFF_P0);     // aliases P0 (dead after gate)
  unsigned short* yl = (unsigned short*)(ws + OFF_P1);     // aliases P1
  float* feat = (float*)(ws + OFF_FEAT);
  float* moe  = (float*)(ws + OFF_MOE);
  int*   cnt  = (int*)(ws + OFF_CNT);
  float* gsum = (float*)(ws + OFF_GSUM);
  int*   lrow = (int*)(ws + OFF_LROW);
  float* lgv  = (float*)(ws + OFF_LG);
  float* outp = (float*)d_out;

  hipMemsetAsync(ws + OFF_MOE, 0, 4194304 + 128, stream);

  hipLaunchKernelGGL(k_wt1b,   dim3(4),       dim3(256), 0, stream, c1w, wA1h, wA1l);
  hipLaunchKernelGGL(k_wt2b,   dim3(72),      dim3(256), 0, stream, c2w, wBh, wBl);
  hipLaunchKernelGGL(k_wt3b,   dim3(288),     dim3(256), 0, stream, c3w, wAh, wAl);
  hipLaunchKernelGGL(k_conv12, dim3(4096),    dim3(512), 0, stream, x, wA1h, wA1l, c1b, wBh, wBl, c2b, Bb);
  hipLaunchKernelGGL(k_conv3,  dim3(4096),    dim3(256), 0, stream, Bb, wAh, wAl, c3b, Chh, Chl);
  // Bb dead now -> build ALL packed weights that live in its region
  hipLaunchKernelGGL(k_pack,   dim3(16, 4, 16), dim3(256), 0, stream, ew1, w1th, w1tl, 256, 1024);
  hipLaunchKernelGGL(k_pack,   dim3(4, 16, 16), dim3(256), 0, stream, ew2, w2th, w2tl, 1024, 256);
  hipLaunchKernelGGL(k_pack,   dim3(4, 32, 1),  dim3(256), 0, stream, fcw, wfh, wfl, 2048, 256);
  hipLaunchKernelGGL(k_packo,  dim3(1024),    dim3(256), 0, stream, ow, owph, owpl);
  hipLaunchKernelGGL(k_fc,     dim3(128, 1, 4), dim3(256), 0, stream, Chh, Chl, wfh, wfl, P0, P1, P2, P3);
  hipLaunchKernelGGL(k_gate,   dim3(256),     dim3(256), 0, stream, P0, P1, P2, P3, fcb, gw, gb,
                     feat, cnt, gsum, lrow, lgv);
  hipLaunchKernelGGL(k_moe,    dim3(128, 16, 8), dim3(256), 0, stream, feat, w1th, w1tl, w2th, w2tl,
                     eb1, eb2, cnt, lrow, lgv, moe);
  hipLaunchKernelGGL(k_lb,     dim3(1),       dim3(64),  0, stream, gsum, outp + (size_t)NB*NCLS);
  hipLaunchKernelGGL(k_ln,     dim3(4096),    dim3(256), 0, stream, feat, moe, lng, lnb, yh, yl);
  hipLaunchKernelGGL(k_out,    dim3(128, 16), dim3(256), 0, stream, yh, yl, owph, owpl, ob, outp);
}

// Round 23
// 799.664 us; speedup vs baseline: 1.0176x; 1.0176x over previous
//
#include <hip/hip_runtime.h>
#include <hip/hip_bf16.h>

typedef short bf16x8 __attribute__((ext_vector_type(8)));
typedef float f32x4 __attribute__((ext_vector_type(4)));

// ---------------- problem sizes ----------------
#define NB   4096
#define NEXP 16
#define DDIM 256
#define HDIM 1024
#define NCLS 1000

// ---------------- workspace layout (bytes) ----------------
// NOTE: Bb (conv2 out, 67 MB at offset 0) is live from conv12 until conv3 completes.
// ALL packed-weight regions below OFF_CHH alias Bb -> their pack kernels MUST run after conv3.
#define OFF_B    ((size_t)0)
#define OFF_P0   ((size_t)0)           // f32 [4096][256] FC partial (kq 0); ALSO yh after gate
#define OFF_P1   ((size_t)4194304)     // f32 [4096][256] FC partial (kq 1); ALSO yl after gate
#define OFF_W1TH ((size_t)8388608)     // bf16 packed [16][64 ht][8 ks][64 lane][8]  8 MB
#define OFF_W1TL ((size_t)16777216)
#define OFF_W2TH ((size_t)25165824)    // bf16 packed [16][16 dt][32 ks][64 lane][8] 8 MB
#define OFF_W2TL ((size_t)33554432)
#define OFF_WFCH ((size_t)41943040)    // fcw packed hi (1 MB)
#define OFF_WFCL ((size_t)42991616)    // fcw packed lo (1 MB)
#define OFF_P2   ((size_t)44040192)    // f32 [4096][256] FC partial (kq 2)
#define OFF_P3   ((size_t)48234496)    // f32 [4096][256] FC partial (kq 3)
#define OFF_OWH  ((size_t)52428800)    // ow packed hi [64 nt][8 ks][64][8] (512 KB)
#define OFF_OWL  ((size_t)53477376)
#define OFF_CHH  ((size_t)67108864)    // conv3 out hi bf16 [4096][2048]; ALSO wBh/wBl/wA1 before conv12
#define OFF_CHL  ((size_t)83886080)    // conv3 out lo bf16
#define OFF_WBL  ((size_t)67145728)
#define OFF_WA1H ((size_t)67182592)
#define OFF_WA1L ((size_t)67184640)
#define OFF_FEAT ((size_t)100663296)   // f32 [4096][256]; ALSO wAh/wAl (288 KB) before k_gate
#define OFF_WAL  ((size_t)100810752)
#define OFF_MOE  ((size_t)104857600)   // f32 [4096][256]
#define OFF_CNT  ((size_t)109051904)   // int [16]
#define OFF_GSUM ((size_t)109051968)   // f32 [16]
#define OFF_LROW ((size_t)109052032)   // int [16][4096]
#define OFF_LG   ((size_t)109314176)   // f32 [16][4096]

__device__ inline unsigned short f2bf(float v) {
  __hip_bfloat16 h = __float2bfloat16(v);
  return *(unsigned short*)&h;
}
__device__ inline float bf2f(unsigned short u) {
  union { unsigned int i; float f; } c; c.i = ((unsigned int)u) << 16; return c.f;
}

// ====== merged weight prep: conv1(1024) + conv2(18432) + conv3(73728) elems, range-split
__global__ __launch_bounds__(256) void k_wprep(
    const float* __restrict__ c1w, unsigned short* __restrict__ a1h, unsigned short* __restrict__ a1l,
    const float* __restrict__ c2w, unsigned short* __restrict__ b2h, unsigned short* __restrict__ b2l,
    const float* __restrict__ c3w, unsigned short* __restrict__ a3h, unsigned short* __restrict__ a3l) {
  int i = blockIdx.x*256 + threadIdx.x;   // over 93184
  if (i < 1024) {
    int k = i & 31, oc = i >> 5;
    float v = (k < 27) ? c1w[oc*27 + k] : 0.f;
    unsigned short h = f2bf(v);
    a1h[i] = h; a1l[i] = f2bf(v - bf2f(h));
  } else if (i < 19456) {
    int j = i - 1024;
    int ic = j & 31, rem = j >> 5;
    int oc = rem & 63, tap = rem >> 6;
    float v = c2w[(oc*32 + ic)*9 + tap];
    unsigned short h = f2bf(v);
    b2h[j] = h; b2l[j] = f2bf(v - bf2f(h));
  } else if (i < 93184) {
    int j = i - 19456;
    int ic = j & 63, rem = j >> 6;
    int oc = rem & 127, tap = rem >> 7;
    float v = c3w[(oc*64 + ic)*9 + tap];
    unsigned short h = f2bf(v);
    a3h[j] = h; a3l[j] = f2bf(v - bf2f(h));
  }
}

// ====== generic pack body (verbatim from k_pack): in[e][R][C] -> packed hi/lo
__device__ inline void pack_body(const float* __restrict__ in,
    unsigned short* __restrict__ oh, unsigned short* __restrict__ ol,
    int R, int C, int bx, int by, int e, int t, float (*tile)[65]) {
  const size_t eb = (size_t)e * R * C;
  const int c0 = bx*64, r0 = by*64;
  const int cc = t & 63, r4 = t >> 6;
  #pragma unroll
  for (int j = 0; j < 16; ++j) {
    int rr = r4 + j*4;
    tile[rr][cc] = in[eb + (size_t)(r0+rr)*C + c0 + cc];
  }
  __syncthreads();
  const int K32 = R >> 5;
  #pragma unroll
  for (int j = 0; j < 16; ++j) {
    int idx = t + j*256;
    int jin = idx & 7, lane = (idx >> 3) & 63, ksl = (idx >> 9) & 1, ntl = idx >> 10;
    int kl = ksl*32 + ((lane >> 4) << 3) + jin;
    int nl = ntl*16 + (lane & 15);
    float v = tile[kl][nl];
    unsigned short h = f2bf(v);
    size_t o = eb + ((size_t)(((c0 >> 4) + ntl)*K32 + (r0 >> 5) + ksl)*64 + lane)*8 + jin;
    oh[o] = h;
    ol[o] = f2bf(v - bf2f(h));
  }
}

// ====== merged packs: ew1(1024 blk) + ew2(1024) + fcw(128) + ow(1024) = 3200 blocks
__global__ __launch_bounds__(256) void k_packall(
    const float* __restrict__ ew1, unsigned short* __restrict__ w1th, unsigned short* __restrict__ w1tl,
    const float* __restrict__ ew2, unsigned short* __restrict__ w2th, unsigned short* __restrict__ w2tl,
    const float* __restrict__ fcw, unsigned short* __restrict__ wfh,  unsigned short* __restrict__ wfl,
    const float* __restrict__ ow,  unsigned short* __restrict__ owh,  unsigned short* __restrict__ owl) {
  __shared__ float tile[64][65];
  const int b = blockIdx.x;
  const int t = threadIdx.x;
  if (b < 1024) {                       // ew1: R=256, C=1024, grid (16,4,16)
    int bx = b & 15, by = (b >> 4) & 3, e = b >> 6;
    pack_body(ew1, w1th, w1tl, 256, 1024, bx, by, e, t, tile);
  } else if (b < 2048) {                // ew2: R=1024, C=256, grid (4,16,16)
    int lb = b - 1024;
    int bx = lb & 3, by = (lb >> 2) & 15, e = lb >> 6;
    pack_body(ew2, w2th, w2tl, 1024, 256, bx, by, e, t, tile);
  } else if (b < 2176) {                // fcw: R=2048, C=256, grid (4,32,1)
    int lb = b - 2048;
    int bx = lb & 3, by = lb >> 2;
    pack_body(fcw, wfh, wfl, 2048, 256, bx, by, 0, t, tile);
  } else {                              // ow pack (elementwise, 1024 blocks)
    int lb = b - 2176;
    int i = lb*256 + t;                 // over 262144
    int j = i & 7, lane = (i >> 3) & 63, ks = (i >> 9) & 7, nt = i >> 12;
    int k = ks*32 + ((lane >> 4) << 3) + j;
    int n = nt*16 + (lane & 15);
    float v = (n < NCLS) ? ow[(size_t)k*NCLS + n] : 0.f;
    unsigned short h = f2bf(v);
    owh[i] = h;
    owl[i] = f2bf(v - bf2f(h));
  }
}

// ============ fused conv1(reg-im2col bf16x2 MFMA) + conv2(bf16x2 MFMA, 3-term) per image ====
// Register-trimmed (R22). launch_bounds(512,4): 2 blocks/CU (R20 lesson).
__global__ __launch_bounds__(512, 4) void k_conv12(const float* __restrict__ x,
    const unsigned short* __restrict__ wA1h, const unsigned short* __restrict__ wA1l,
    const float* __restrict__ b1,
    const unsigned short* __restrict__ wBh, const unsigned short* __restrict__ wBl,
    const float* __restrict__ b2, float* __restrict__ outB) {
  __shared__ unsigned int xsu[3*34*36];     // packed bf16 hi/lo image (14.7 KB)
  __shared__ unsigned short ishB[2][10368]; // conv1-out hi/lo swizzled (41.5 KB); reused for store
  __shared__ float bs1[32];
  __shared__ float bs2[64];
  const int t = threadIdx.x;
  const int img = blockIdx.x;
  for (int i = t; i < 3*34*36; i += 512) xsu[i] = 0u;
  {
    unsigned int* z = (unsigned int*)&ishB[0][0];
    for (int i = t; i < 10368; i += 512) z[i] = 0u;
  }
  __syncthreads();
  for (int i = t; i < 3072; i += 512) {
    int ic = i >> 10, rem = i & 1023, y = rem >> 5, xx = rem & 31;
    float v = x[(size_t)img*3072 + i];
    unsigned short h = f2bf(v);
    unsigned short l = f2bf(v - bf2f(h));
    xsu[ic*34*36 + (y+1)*36 + (xx+1)] = ((unsigned int)l << 16) | (unsigned int)h;
  }
  if (t < 32) bs1[t] = b1[t];
  else if (t >= 64 && t < 128) bs2[t-64] = b2[t-64];

  const int lane = t & 63, wvv = t >> 6;
  const int lr = lane & 15, lq = lane >> 4;

  const int oct1 = wvv & 1;
  const bf16x8 a1h = *(const bf16x8*)&wA1h[((oct1*16 + lr) << 5) + lq*8];
  const bf16x8 a1l = *(const bf16x8*)&wA1l[((oct1*16 + lr) << 5) + lq*8];

  int koff[8];
  #pragma unroll
  for (int j = 0; j < 8; ++j) {
    int k = lq*8 + j;
    if (k < 27) {
      int ic = k/9, tap = k - ic*9, dy = tap/3, dx = tap - dy*3;
      koff[j] = ic*34*36 + dy*36 + dx;
    } else koff[j] = -1;
  }
  __syncthreads();

  // ---- conv1 via MFMA, barrier-free: 8 passes of 4 pre-pool rows ----
  {
    const int rp  = wvv >> 1;
    const int ly0 = (rp >> 1) << 1;      // 0 or 2
    const int xh  = rp & 1;
    const int X   = xh*16 + lr;
    for (int ps = 0; ps < 8; ++ps) {
      const int baseA = (ps*4 + ly0)*36 + X;
      f32x4 aA = (f32x4){0.f,0.f,0.f,0.f}, aB = (f32x4){0.f,0.f,0.f,0.f};
      {
        union { unsigned int u[4]; bf16x8 v; } bh_, bl_;
        #pragma unroll
        for (int jj = 0; jj < 4; ++jj) {
          unsigned int e0 = (koff[2*jj]   >= 0) ? xsu[koff[2*jj]   + baseA] : 0u;
          unsigned int e1 = (koff[2*jj+1] >= 0) ? xsu[koff[2*jj+1] + baseA] : 0u;
          bh_.u[jj] = __builtin_amdgcn_perm(e1, e0, 0x05040100u);
          bl_.u[jj] = __builtin_amdgcn_perm(e1, e0, 0x07060302u);
        }
        aA = __builtin_amdgcn_mfma_f32_16x16x32_bf16(a1h, bh_.v, aA, 0, 0, 0);
        aA = __builtin_amdgcn_mfma_f32_16x16x32_bf16(a1h, bl_.v, aA, 0, 0, 0);
        aA = __builtin_amdgcn_mfma_f32_16x16x32_bf16(a1l, bh_.v, aA, 0, 0, 0);
      }
      {
        union { unsigned int u[4]; bf16x8 v; } bh_, bl_;
        #pragma unroll
        for (int jj = 0; jj < 4; ++jj) {
          unsigned int e0 = (koff[2*jj]   >= 0) ? xsu[koff[2*jj]   + baseA + 36] : 0u;
          unsigned int e1 = (koff[2*jj+1] >= 0) ? xsu[koff[2*jj+1] + baseA + 36] : 0u;
          bh_.u[jj] = __builtin_amdgcn_perm(e1, e0, 0x05040100u);
          bl_.u[jj] = __builtin_amdgcn_perm(e1, e0, 0x07060302u);
        }
        aB = __builtin_amdgcn_mfma_f32_16x16x32_bf16(a1h, bh_.v, aB, 0, 0, 0);
        aB = __builtin_amdgcn_mfma_f32_16x16x32_bf16(a1h, bl_.v, aB, 0, 0, 0);
        aB = __builtin_amdgcn_mfma_f32_16x16x32_bf16(a1l, bh_.v, aB, 0, 0, 0);
      }
      #pragma unroll
      for (int r = 0; r < 4; ++r) {
        float v = fmaxf(aA[r], aB[r]);
        v = fmaxf(v, __shfl_xor(v, 1, 64));
        if ((lr & 1) == 0) {
          int oc = oct1*16 + lq*4 + r;
          int Xp = xh*8 + (lr >> 1);
          int Yp = ps*2 + (ly0 >> 1);
          float m = fmaxf(v + bs1[oc], 0.f);
          unsigned short h = f2bf(m);
          unsigned short l = f2bf(m - bf2f(h));
          int pl = (Yp+1)*18 + (Xp+1);
          int sl = pl*4 + ((oc >> 3) ^ ((pl >> 1) & 3));
          int us = (sl << 3) | (oc & 7);
          ishB[0][us] = h; ishB[1][us] = l;
        }
      }
    }
  }
  __syncthreads();
  // ---- conv2 bf16x2 MFMA (3-term) + fused pool + relu; A loaded directly per tap ----
  {
    const int mtp = (wvv & 1)*2;
    const int rq = wvv >> 1;
    f32x4 acc[2][4];
    #pragma unroll
    for (int i = 0; i < 2; ++i)
      #pragma unroll
      for (int j = 0; j < 4; ++j) acc[i][j] = (f32x4){0.f,0.f,0.f,0.f};
    #pragma unroll
    for (int tap = 0; tap < 9; ++tap) {
      const int off0 = ((tap*64 + mtp*16     + lr) << 5) + lq*8;
      const int off1 = ((tap*64 + (mtp+1)*16 + lr) << 5) + lq*8;
      bf16x8 ah0 = *(const bf16x8*)&wBh[off0];
      bf16x8 al0 = *(const bf16x8*)&wBl[off0];
      bf16x8 ah1 = *(const bf16x8*)&wBh[off1];
      bf16x8 al1 = *(const bf16x8*)&wBl[off1];
      const int dy = tap/3, dx = tap - dy*3;
      #pragma unroll
      for (int j = 0; j < 4; ++j) {
        int pl = (rq*4 + j + dy)*18 + lr + dx;
        int sl = pl*4 + (lq ^ ((pl >> 1) & 3));
        bf16x8 bh = *(const bf16x8*)&ishB[0][sl << 3];
        bf16x8 bl = *(const bf16x8*)&ishB[1][sl << 3];
        acc[0][j] = __builtin_amdgcn_mfma_f32_16x16x32_bf16(ah0, bh, acc[0][j], 0, 0, 0);
        acc[1][j] = __builtin_amdgcn_mfma_f32_16x16x32_bf16(ah1, bh, acc[1][j], 0, 0, 0);
        acc[0][j] = __builtin_amdgcn_mfma_f32_16x16x32_bf16(ah0, bl, acc[0][j], 0, 0, 0);
        acc[1][j] = __builtin_amdgcn_mfma_f32_16x16x32_bf16(ah1, bl, acc[1][j], 0, 0, 0);
        acc[0][j] = __builtin_amdgcn_mfma_f32_16x16x32_bf16(al0, bh, acc[0][j], 0, 0, 0);
        acc[1][j] = __builtin_amdgcn_mfma_f32_16x16x32_bf16(al1, bh, acc[1][j], 0, 0, 0);
      }
    }
    __syncthreads();
    float* ps2 = (float*)&ishB[0][0];
    #pragma unroll
    for (int m = 0; m < 2; ++m)
      #pragma unroll
      for (int k = 0; k < 2; ++k)
        #pragma unroll
        for (int r = 0; r < 4; ++r) {
          float v = fmaxf(acc[m][2*k][r], acc[m][2*k+1][r]);
          v = fmaxf(v, __shfl_xor(v, 1, 64));
          if ((lr & 1) == 0) {
            int oc = (mtp + m)*16 + lq*4 + r;
            int Y = rq*2 + k, X = lr >> 1;
            ps2[oc*65 + Y*8 + X] = fmaxf(v + bs2[oc], 0.f);
          }
        }
    __syncthreads();
    float* op = outB + (size_t)img*4096;
    #pragma unroll
    for (int jj = 0; jj < 8; ++jj) {
      int i = jj*512 + t;
      op[i] = ps2[(i >> 6)*65 + (i & 63)];
    }
  }
}

// ================= conv3 v5: bf16x2 split MFMA (3-term); emits C as bf16 hi/lo ==========
__global__ __launch_bounds__(256) void k_conv3(const float* __restrict__ inB,
    const unsigned short* __restrict__ wAh, const unsigned short* __restrict__ wAl,
    const float* __restrict__ bias,
    unsigned short* __restrict__ Chh, unsigned short* __restrict__ Chl) {
  __shared__ unsigned short ish[2][6400];
  const int t = threadIdx.x;
  const int img = blockIdx.x;
  {
    unsigned int* z = (unsigned int*)&ish[0][0];
    #pragma unroll
    for (int j = 0; j < 25; ++j) z[t + 256*j] = 0u;
  }
  __syncthreads();
  {
    const float* src = inB + (size_t)img*4096;
    #pragma unroll
    for (int j = 0; j < 16; ++j) {
      int f = t + 256*j;
      int ic = f >> 6, p = f & 63;
      int pl = ((p >> 3) + 1)*10 + (p & 7) + 1;
      float v = src[f];
      unsigned short h = f2bf(v);
      unsigned short l = f2bf(v - bf2f(h));
      int u = pl*64 + ic;
      int us = (((u >> 3) ^ (pl & 7)) << 3) | (u & 7);
      ish[0][us] = h; ish[1][us] = l;
    }
  }
  __syncthreads();

  const int lane = t & 63, wid = t >> 6;
  const int lr = lane & 15, lq = lane >> 4;
  const int mt0 = wid*2;
  const int yb = lr >> 3, xb = lr & 7;

  f32x4 acc[2][4];
  #pragma unroll
  for (int i = 0; i < 2; ++i)
    #pragma unroll
    for (int j = 0; j < 4; ++j) acc[i][j] = (f32x4){0.f,0.f,0.f,0.f};

  for (int tap = 0; tap < 9; ++tap) {
    const int dy = tap/3, dx = tap - dy*3;
    #pragma unroll
    for (int kc = 0; kc < 2; ++kc) {
      const int kb = kc*32 + lq*8;
      const int wbase = ((tap << 7) << 6) + kb;
      bf16x8 a0h = *(const bf16x8*)&wAh[wbase + ((mt0*16 + lr) << 6)];
      bf16x8 a0l = *(const bf16x8*)&wAl[wbase + ((mt0*16 + lr) << 6)];
      bf16x8 a1h = *(const bf16x8*)&wAh[wbase + (((mt0+1)*16 + lr) << 6)];
      bf16x8 a1l = *(const bf16x8*)&wAl[wbase + (((mt0+1)*16 + lr) << 6)];
      #pragma unroll
      for (int nt = 0; nt < 4; ++nt) {
        const int pl = (2*nt + yb + dy)*10 + xb + dx;
        const int u = pl*64 + kb;
        const int us = (((u >> 3) ^ (pl & 7)) << 3);
        bf16x8 bh = *(const bf16x8*)&ish[0][us];
        bf16x8 bl = *(const bf16x8*)&ish[1][us];
        acc[0][nt] = __builtin_amdgcn_mfma_f32_16x16x32_bf16(a0h, bh, acc[0][nt], 0, 0, 0);
        acc[0][nt] = __builtin_amdgcn_mfma_f32_16x16x32_bf16(a0h, bl, acc[0][nt], 0, 0, 0);
        acc[0][nt] = __builtin_amdgcn_mfma_f32_16x16x32_bf16(a0l, bh, acc[0][nt], 0, 0, 0);
        acc[1][nt] = __builtin_amdgcn_mfma_f32_16x16x32_bf16(a1h, bh, acc[1][nt], 0, 0, 0);
        acc[1][nt] = __builtin_amdgcn_mfma_f32_16x16x32_bf16(a1h, bl, acc[1][nt], 0, 0, 0);
        acc[1][nt] = __builtin_amdgcn_mfma_f32_16x16x32_bf16(a1l, bh, acc[1][nt], 0, 0, 0);
      }
    }
  }
  __syncthreads();
  float* stg = (float*)&ish[0][0];   // [128 oc][17]
  #pragma unroll
  for (int mtl = 0; mtl < 2; ++mtl)
    #pragma unroll
    for (int nt = 0; nt < 4; ++nt)
      #pragma unroll
      for (int r = 0; r < 4; ++r) {
        float v = acc[mtl][nt][r];
        v = fmaxf(v, __shfl_xor(v, 1, 64));
        v = fmaxf(v, __shfl_xor(v, 8, 64));
        if ((lane & 9) == 0) {
          int oc = (mt0 + mtl)*16 + lq*4 + r;
          int pix = nt*4 + (xb >> 1);
          stg[oc*17 + pix] = fmaxf(v + bias[oc], 0.f);
        }
      }
  __syncthreads();
  #pragma unroll
  for (int j = 0; j < 8; ++j) {
    int i = t + 256*j;
    float v = stg[(i >> 4)*17 + (i & 15)];
    unsigned short h = f2bf(v);
    Chh[(size_t)img*2048 + i] = h;
    Chl[(size_t)img*2048 + i] = f2bf(v - bf2f(h));
  }
}

// ================= FC GEMM v2: bf16x2 3-term MFMA, no LDS, split-K=4 =================
__global__ __launch_bounds__(256) void k_fc(const unsigned short* __restrict__ Chh,
    const unsigned short* __restrict__ Chl,
    const unsigned short* __restrict__ wfh, const unsigned short* __restrict__ wfl,
    float* __restrict__ P0, float* __restrict__ P1,
    float* __restrict__ P2, float* __restrict__ P3) {
  const int t = threadIdx.x;
  const int r0 = blockIdx.x * 32;
  const int kq = blockIdx.z;
  float* __restrict__ P = (kq == 0) ? P0 : (kq == 1) ? P1 : (kq == 2) ? P2 : P3;
  const int lane = t & 63, wv = t >> 6;
  const int lr = lane & 15, lq = lane >> 4;
  f32x4 acc[2][4];
  #pragma unroll
  for (int i = 0; i < 2; ++i)
    #pragma unroll
    for (int j = 0; j < 4; ++j) acc[i][j] = (f32x4){0.f,0.f,0.f,0.f};
  #pragma unroll 4
  for (int ks = 0; ks < 16; ++ks) {
    bf16x8 ah[2], al[2];
    #pragma unroll
    for (int rt = 0; rt < 2; ++rt) {
      size_t ao = (size_t)(r0 + rt*16 + lr)*2048 + kq*512 + ks*32 + lq*8;
      ah[rt] = *(const bf16x8*)&Chh[ao];
      al[rt] = *(const bf16x8*)&Chl[ao];
    }
    #pragma unroll
    for (int nt = 0; nt < 4; ++nt) {
      size_t bo = ((size_t)((wv*4 + nt)*64 + kq*16 + ks)*64 + lane)*8;
      bf16x8 bh = *(const bf16x8*)&wfh[bo];
      bf16x8 bl = *(const bf16x8*)&wfl[bo];
      acc[0][nt] = __builtin_amdgcn_mfma_f32_16x16x32_bf16(ah[0], bh, acc[0][nt], 0, 0, 0);
      acc[1][nt] = __builtin_amdgcn_mfma_f32_16x16x32_bf16(ah[1], bh, acc[1][nt], 0, 0, 0);
      acc[0][nt] = __builtin_amdgcn_mfma_f32_16x16x32_bf16(ah[0], bl, acc[0][nt], 0, 0, 0);
      acc[1][nt] = __builtin_amdgcn_mfma_f32_16x16x32_bf16(ah[1], bl, acc[1][nt], 0, 0, 0);
      acc[0][nt] = __builtin_amdgcn_mfma_f32_16x16x32_bf16(al[0], bh, acc[0][nt], 0, 0, 0);
      acc[1][nt] = __builtin_amdgcn_mfma_f32_16x16x32_bf16(al[1], bh, acc[1][nt], 0, 0, 0);
    }
  }
  #pragma unroll
  for (int rt = 0; rt < 2; ++rt)
    #pragma unroll
    for (int nt = 0; nt < 4; ++nt)
      #pragma unroll
      for (int r = 0; r < 4; ++r)
        P[(size_t)(r0 + rt*16 + lq*4 + r)*256 + (wv*4 + nt)*16 + lr] = acc[rt][nt][r];
}

// ================= gate: feat = P0+P1+P2+P3+fcb; logits; top-2 softmax; expert lists
__global__ __launch_bounds__(256) void k_gate(const float* __restrict__ P0,
    const float* __restrict__ P1, const float* __restrict__ P2, const float* __restrict__ P3,
    const float* __restrict__ fcb,
    const float* __restrict__ gw, const float* __restrict__ gb,
    float* __restrict__ feat, int* __restrict__ cnt, float* __restrict__ gsum,
    int* __restrict__ lrow, float* __restrict__ lg) {
  __shared__ float ft[16][256];
  __shared__ float lgs[16][16];
  __shared__ float gwl[4096];
  const int t = threadIdx.x;
  const int r0 = blockIdx.x * 16;
  for (int i = t; i < 4096; i += 256) gwl[i] = gw[i];
  float bb = fcb[t];
  #pragma unroll
  for (int r = 0; r < 16; ++r) {
    size_t off = (size_t)(r0+r)*256 + t;
    float v = P0[off] + P1[off] + P2[off] + P3[off] + bb;
    ft[r][t] = v;
    feat[off] = v;
  }
  __syncthreads();
  {
    int r = t >> 4, e = t & 15;
    float s = gb[e];
    for (int k = 0; k < 256; ++k) s = fmaf(ft[r][k], gwl[k*16 + e], s);
    lgs[r][e] = s;
  }
  __syncthreads();
  if (t < 16) {
    int r = t;
    float v1 = -3.402823e38f, v2 = -3.402823e38f;
    int i1 = 0, i2 = 0;
    for (int e = 0; e < 16; ++e) {
      float v = lgs[r][e];
      if (v > v1)      { v2 = v1; i2 = i1; v1 = v; i1 = e; }
      else if (v > v2) { v2 = v;  i2 = e; }
    }
    float ex = __expf(v2 - v1);
    float g1 = 1.f / (1.f + ex);
    float g2 = ex  / (1.f + ex);
    int row = r0 + r;
    int p1 = atomicAdd(&cnt[i1], 1); lrow[i1*4096 + p1] = row; lg[i1*4096 + p1] = g1;
    int p2 = atomicAdd(&cnt[i2], 1); lrow[i2*4096 + p2] = row; lg[i2*4096 + p2] = g2;
    atomicAdd(&gsum[i1], g1);
    atomicAdd(&gsum[i2], g2);
  }
}

// ================= MoE v4: 32-row tiles x split-K(8), bf16x2 MFMA 3-term, packed weights
__global__ __launch_bounds__(256) void k_moe(const float* __restrict__ feat,
    const unsigned short* __restrict__ w1th, const unsigned short* __restrict__ w1tl,
    const unsigned short* __restrict__ w2th, const unsigned short* __restrict__ w2tl,
    const float* __restrict__ eb1, const float* __restrict__ eb2,
    const int* __restrict__ cnt, const int* __restrict__ lrow, const float* __restrict__ lgw,
    float* __restrict__ moe) {
  const int e = blockIdx.y;
  const int n_e = cnt[e];
  const int start = blockIdx.x * 32;
  if (start >= n_e) return;
  const int c = blockIdx.z;
  const int n = min(32, n_e - start);
  __shared__ unsigned short fh[8192], fl[8192];
  __shared__ unsigned short h1h[4096], h1l[4096];
  __shared__ int   rws[32];
  __shared__ float gws[32];
  const int t = threadIdx.x;
  if (t < 32) {
    rws[t] = (t < n) ? lrow[e*4096 + start + t] : 0;
    gws[t] = (t < n) ? lgw[e*4096 + start + t] : 0.f;
  }
  __syncthreads();
  for (int j = 0; j < 32; ++j) {
    float v = (j < n) ? feat[(size_t)rws[j]*256 + t] : 0.f;
    unsigned short h = f2bf(v);
    int us = (j*32 + ((t >> 3) ^ (j & 7)))*8 + (t & 7);
    fh[us] = h; fl[us] = f2bf(v - bf2f(h));
  }
  const int lane = t & 63, wv = t >> 6;
  const int lr = lane & 15, lq = lane >> 4;
  const int rh = wv & 1, qh = wv >> 1;
  const int arow = rh*16 + lr;
  const int rsw = arow & 7;
  const size_t ewb = (size_t)e << 18;

  f32x4 acc2[8];
  #pragma unroll
  for (int i = 0; i < 8; ++i) acc2[i] = (f32x4){0.f,0.f,0.f,0.f};

  __syncthreads();

  {
    f32x4 acc1[4];
    #pragma unroll
    for (int i = 0; i < 4; ++i) acc1[i] = (f32x4){0.f,0.f,0.f,0.f};
    #pragma unroll
    for (int ks = 0; ks < 8; ++ks) {
      int aoff = (arow*32 + ((ks*4 + lq) ^ rsw))*8;
      bf16x8 ah = *(const bf16x8*)&fh[aoff];
      bf16x8 al = *(const bf16x8*)&fl[aoff];
      #pragma unroll
      for (int ht = 0; ht < 4; ++ht) {
        int htile = c*8 + qh*4 + ht;
        size_t bo = ewb + ((size_t)(htile*8 + ks)*64 + lane)*8;
        bf16x8 bh = *(const bf16x8*)&w1th[bo];
        bf16x8 bl = *(const bf16x8*)&w1tl[bo];
        acc1[ht] = __builtin_amdgcn_mfma_f32_16x16x32_bf16(ah, bh, acc1[ht], 0, 0, 0);
        acc1[ht] = __builtin_amdgcn_mfma_f32_16x16x32_bf16(ah, bl, acc1[ht], 0, 0, 0);
        acc1[ht] = __builtin_amdgcn_mfma_f32_16x16x32_bf16(al, bh, acc1[ht], 0, 0, 0);
      }
    }
    __syncthreads();
    #pragma unroll
    for (int ht = 0; ht < 4; ++ht) {
      int hloc = qh*64 + ht*16 + lr;
      float bb = eb1[e*1024 + c*128 + hloc];
      #pragma unroll
      for (int r = 0; r < 4; ++r) {
        int orow = rh*16 + lq*4 + r;
        float v = fmaxf(acc1[ht][r] + bb, 0.f);
        unsigned short hh = f2bf(v);
        int us = (orow*16 + ((hloc >> 3) ^ (orow & 7)))*8 + (hloc & 7);
        h1h[us] = hh; h1l[us] = f2bf(v - bf2f(hh));
      }
    }
    __syncthreads();
    #pragma unroll
    for (int ks = 0; ks < 4; ++ks) {
      int aoff = (arow*16 + ((ks*4 + lq) ^ rsw))*8;
      bf16x8 ah = *(const bf16x8*)&h1h[aoff];
      bf16x8 al = *(const bf16x8*)&h1l[aoff];
      #pragma unroll
      for (int dt = 0; dt < 8; ++dt) {
        int dtile = qh*8 + dt;
        size_t bo = ewb + ((size_t)(dtile*32 + c*4 + ks)*64 + lane)*8;
        bf16x8 bh = *(const bf16x8*)&w2th[bo];
        bf16x8 bl = *(const bf16x8*)&w2tl[bo];
        acc2[dt] = __builtin_amdgcn_mfma_f32_16x16x32_bf16(ah, bh, acc2[dt], 0, 0, 0);
        acc2[dt] = __builtin_amdgcn_mfma_f32_16x16x32_bf16(ah, bl, acc2[dt], 0, 0, 0);
        acc2[dt] = __builtin_amdgcn_mfma_f32_16x16x32_bf16(al, bh, acc2[dt], 0, 0, 0);
      }
    }
  }
  #pragma unroll
  for (int dt = 0; dt < 8; ++dt) {
    int d = qh*128 + dt*16 + lr;
    float b2 = (c == 0) ? eb2[e*256 + d] : 0.f;
    #pragma unroll
    for (int r = 0; r < 4; ++r) {
      int orow = rh*16 + lq*4 + r;
      if (orow < n)
        atomicAdd(&moe[(size_t)rws[orow]*256 + d], gws[orow]*(acc2[dt][r] + b2));
    }
  }
}

// ================= LayerNorm(moe + feat) -> y bf16 hi/lo; block 4096 computes lb_loss ======
__global__ __launch_bounds__(256) void k_ln(const float* __restrict__ feat,
    const float* __restrict__ moe, const float* __restrict__ g, const float* __restrict__ bp,
    unsigned short* __restrict__ yh, unsigned short* __restrict__ yl,
    const float* __restrict__ gsum, float* __restrict__ out_lb) {
  const int r = blockIdx.x, t = threadIdx.x;
  if (r == NB) {            // lb block: wave 0 only, no barriers on this path
    if (t < 64) {
      float term = 0.f;
      if (t < 16) {
        float D = gsum[t] * (1.f/4096.f);
        term = D * logf(D + 1e-8f);
      }
      #pragma unroll
      for (int o = 8; o > 0; o >>= 1) term += __shfl_down(term, o, 64);
      if (t == 0) *out_lb = term;
    }
    return;
  }
  float v = moe[(size_t)r*256 + t] + feat[(size_t)r*256 + t];
  float s = v, q = v * v;
  #pragma unroll
  for (int o = 32; o > 0; o >>= 1) {
    s += __shfl_down(s, o, 64);
    q += __shfl_down(q, o, 64);
  }
  __shared__ float ss[4], qq[4];
  int wv = t >> 6;
  if ((t & 63) == 0) { ss[wv] = s; qq[wv] = q; }
  __syncthreads();
  float S = ss[0]+ss[1]+ss[2]+ss[3];
  float Q = qq[0]+qq[1]+qq[2]+qq[3];
  float mu  = S * (1.f/256.f);
  float var = Q * (1.f/256.f) - mu*mu;
  float inv = rsqrtf(var + 1e-5f);
  float y = (v - mu) * inv * g[t] + bp[t];
  unsigned short h = f2bf(y);
  yh[(size_t)r*256 + t] = h;
  yl[(size_t)r*256 + t] = f2bf(y - bf2f(h));
}

// ================= output GEMM v2: bf16x2 3-term MFMA, no LDS =================
__global__ __launch_bounds__(256) void k_out(const unsigned short* __restrict__ yh,
    const unsigned short* __restrict__ yl,
    const unsigned short* __restrict__ owh, const unsigned short* __restrict__ owl,
    const float* __restrict__ ob, float* __restrict__ out) {
  const int t = threadIdx.x;
  const int r0 = blockIdx.x * 32;
  const int lane = t & 63, wv = t >> 6;
  const int lr = lane & 15, lq = lane >> 4;
  const int ntile = blockIdx.y*4 + wv;
  f32x4 acc[2];
  acc[0] = (f32x4){0.f,0.f,0.f,0.f};
  acc[1] = (f32x4){0.f,0.f,0.f,0.f};
  #pragma unroll
  for (int ks = 0; ks < 8; ++ks) {
    bf16x8 bh = *(const bf16x8*)&owh[((size_t)(ntile*8 + ks)*64 + lane)*8];
    bf16x8 bl = *(const bf16x8*)&owl[((size_t)(ntile*8 + ks)*64 + lane)*8];
    #pragma unroll
    for (int rt = 0; rt < 2; ++rt) {
      size_t ao = (size_t)(r0 + rt*16 + lr)*256 + ks*32 + lq*8;
      bf16x8 ah = *(const bf16x8*)&yh[ao];
      bf16x8 al = *(const bf16x8*)&yl[ao];
      acc[rt] = __builtin_amdgcn_mfma_f32_16x16x32_bf16(ah, bh, acc[rt], 0, 0, 0);
      acc[rt] = __builtin_amdgcn_mfma_f32_16x16x32_bf16(ah, bl, acc[rt], 0, 0, 0);
      acc[rt] = __builtin_amdgcn_mfma_f32_16x16x32_bf16(al, bh, acc[rt], 0, 0, 0);
    }
  }
  const int col = ntile*16 + lr;
  if (col < NCLS) {
    float bb = ob[col];
    #pragma unroll
    for (int rt = 0; rt < 2; ++rt)
      #pragma unroll
      for (int r = 0; r < 4; ++r)
        out[(size_t)(r0 + rt*16 + lq*4 + r)*NCLS + col] = acc[rt][r] + bb;
  }
}

// ================= launch =================
extern "C" void kernel_launch(void* const* d_in, const int* in_sizes, int n_in,
                              void* d_out, int out_size, void* d_ws, size_t ws_size,
                              hipStream_t stream) {
  const float* x   = (const float*)d_in[0];
  const float* c1w = (const float*)d_in[1];
  const float* c1b = (const float*)d_in[2];
  const float* c2w = (const float*)d_in[3];
  const float* c2b = (const float*)d_in[4];
  const float* c3w = (const float*)d_in[5];
  const float* c3b = (const float*)d_in[6];
  const float* fcw = (const float*)d_in[7];
  const float* fcb = (const float*)d_in[8];
  const float* gw  = (const float*)d_in[9];
  const float* gb  = (const float*)d_in[10];
  const float* ew1 = (const float*)d_in[11];
  const float* eb1 = (const float*)d_in[12];
  const float* ew2 = (const float*)d_in[13];
  const float* eb2 = (const float*)d_in[14];
  const float* lng = (const float*)d_in[15];
  const float* lnb = (const float*)d_in[16];
  const float* ow  = (const float*)d_in[17];
  const float* ob  = (const float*)d_in[18];
  char* ws = (char*)d_ws;
  float* Bb   = (float*)(ws + OFF_B);
  float* P0   = (float*)(ws + OFF_P0);
  float* P1   = (float*)(ws + OFF_P1);
  float* P2   = (float*)(ws + OFF_P2);
  float* P3   = (float*)(ws + OFF_P3);
  unsigned short* Chh = (unsigned short*)(ws + OFF_CHH);
  unsigned short* Chl = (unsigned short*)(ws + OFF_CHL);
  unsigned short* wBh = (unsigned short*)(ws + OFF_CHH);   // aliases Chh (written after conv12)
  unsigned short* wBl = (unsigned short*)(ws + OFF_WBL);
  unsigned short* wA1h = (unsigned short*)(ws + OFF_WA1H);
  unsigned short* wA1l = (unsigned short*)(ws + OFF_WA1L);
  unsigned short* wAh = (unsigned short*)(ws + OFF_FEAT);  // aliases feat (written later)
  unsigned short* wAl = (unsigned short*)(ws + OFF_WAL);
  unsigned short* w1th = (unsigned short*)(ws + OFF_W1TH);
  unsigned short* w1tl = (unsigned short*)(ws + OFF_W1TL);
  unsigned short* w2th = (unsigned short*)(ws + OFF_W2TH);
  unsigned short* w2tl = (unsigned short*)(ws + OFF_W2TL);
  unsigned short* wfh = (unsigned short*)(ws + OFF_WFCH);
  unsigned short* wfl = (unsigned short*)(ws + OFF_WFCL);
  unsigned short* owph = (unsigned short*)(ws + OFF_OWH);
  unsigned short* owpl = (unsigned short*)(ws + OFF_OWL);
  unsigned short* yh = (unsigned short*)(ws + OFF_P0);     // aliases P0 (dead after gate)
  unsigned short* yl = (unsigned short*)(ws + OFF_P1);     // aliases P1
  float* feat = (float*)(ws + OFF_FEAT);
  float* moe  = (float*)(ws + OFF_MOE);
  int*   cnt  = (int*)(ws + OFF_CNT);
  float* gsum = (float*)(ws + OFF_GSUM);
  int*   lrow = (int*)(ws + OFF_LROW);
  float* lgv  = (float*)(ws + OFF_LG);
  float* outp = (float*)d_out;

  hipMemsetAsync(ws + OFF_MOE, 0, 4194304 + 128, stream);

  hipLaunchKernelGGL(k_wprep,  dim3(364),     dim3(256), 0, stream,
                     c1w, wA1h, wA1l, c2w, wBh, wBl, c3w, wAh, wAl);
  hipLaunchKernelGGL(k_conv12, dim3(4096),    dim3(512), 0, stream, x, wA1h, wA1l, c1b, wBh, wBl, c2b, Bb);
  hipLaunchKernelGGL(k_conv3,  dim3(4096),    dim3(256), 0, stream, Bb, wAh, wAl, c3b, Chh, Chl);
  // Bb dead now -> build ALL packed weights that live in its region (one kernel)
  hipLaunchKernelGGL(k_packall, dim3(3200),   dim3(256), 0, stream,
                     ew1, w1th, w1tl, ew2, w2th, w2tl, fcw, wfh, wfl, ow, owph, owpl);
  hipLaunchKernelGGL(k_fc,     dim3(128, 1, 4), dim3(256), 0, stream, Chh, Chl, wfh, wfl, P0, P1, P2, P3);
  hipLaunchKernelGGL(k_gate,   dim3(256),     dim3(256), 0, stream, P0, P1, P2, P3, fcb, gw, gb,
                     feat, cnt, gsum, lrow, lgv);
  hipLaunchKernelGGL(k_moe,    dim3(128, 16, 8), dim3(256), 0, stream, feat, w1th, w1tl, w2th, w2tl,
                     eb1, eb2, cnt, lrow, lgv, moe);
  hipLaunchKernelGGL(k_ln,     dim3(4097),    dim3(256), 0, stream, feat, moe, lng, lnb, yh, yl,
                     gsum, outp + (size_t)NB*NCLS);
  hipLaunchKernelGGL(k_out,    dim3(128, 16), dim3(256), 0, stream, yh, yl, owph, owpl, ob, outp);
}

// Round 24
// 787.910 us; speedup vs baseline: 1.0328x; 1.0149x over previous
//
#include <hip/hip_runtime.h>
#include <hip/hip_bf16.h>

typedef short bf16x8 __attribute__((ext_vector_type(8)));
typedef float f32x4 __attribute__((ext_vector_type(4)));

// ---------------- problem sizes ----------------
#define NB   4096
#define NEXP 16
#define DDIM 256
#define HDIM 1024
#define NCLS 1000

// ---------------- workspace layout (bytes) ----------------
// NOTE: Bb (conv2 out, 67 MB at offset 0) is live from conv12 until conv3 completes.
// ALL packed-weight regions below OFF_CHH alias Bb -> their pack kernels MUST run after conv3.
#define OFF_B    ((size_t)0)
#define OFF_P0   ((size_t)0)           // f32 [4096][256] FC partial (kq 0); ALSO yh after gate
#define OFF_P1   ((size_t)4194304)     // f32 [4096][256] FC partial (kq 1); ALSO yl after gate
#define OFF_W1TH ((size_t)8388608)     // bf16 packed [16][64 ht][8 ks][64 lane][8]  8 MB
#define OFF_W1TL ((size_t)16777216)
#define OFF_W2TH ((size_t)25165824)    // bf16 packed [16][16 dt][32 ks][64 lane][8] 8 MB
#define OFF_W2TL ((size_t)33554432)
#define OFF_WFCH ((size_t)41943040)    // fcw packed hi (1 MB)
#define OFF_WFCL ((size_t)42991616)    // fcw packed lo (1 MB)
#define OFF_P2   ((size_t)44040192)    // f32 [4096][256] FC partial (kq 2)
#define OFF_P3   ((size_t)48234496)    // f32 [4096][256] FC partial (kq 3)
#define OFF_OWH  ((size_t)52428800)    // ow packed hi [64 nt][8 ks][64][8] (512 KB)
#define OFF_OWL  ((size_t)53477376)
#define OFF_CHH  ((size_t)67108864)    // conv3 out hi bf16 [4096][2048]; ALSO wBh/wBl/wA1 before conv12
#define OFF_CHL  ((size_t)83886080)    // conv3 out lo bf16
#define OFF_WBL  ((size_t)67145728)
#define OFF_WA1H ((size_t)67182592)
#define OFF_WA1L ((size_t)67184640)
#define OFF_FEAT ((size_t)100663296)   // f32 [4096][256]; ALSO wAh/wAl (288 KB) before k_gate
#define OFF_WAL  ((size_t)100810752)
#define OFF_MOE  ((size_t)104857600)   // f32 [4096][256]
#define OFF_CNT  ((size_t)109051904)   // int [16]
#define OFF_GSUM ((size_t)109051968)   // f32 [16]
#define OFF_LROW ((size_t)109052032)   // int [16][4096]
#define OFF_LG   ((size_t)109314176)   // f32 [16][4096]

__device__ inline unsigned short f2bf(float v) {
  __hip_bfloat16 h = __float2bfloat16(v);
  return *(unsigned short*)&h;
}
__device__ inline float bf2f(unsigned short u) {
  union { unsigned int i; float f; } c; c.i = ((unsigned int)u) << 16; return c.f;
}

// ====== merged weight prep: conv1(1024) + conv2(18432) + conv3(73728) elems, range-split
__global__ __launch_bounds__(256) void k_wprep(
    const float* __restrict__ c1w, unsigned short* __restrict__ a1h, unsigned short* __restrict__ a1l,
    const float* __restrict__ c2w, unsigned short* __restrict__ b2h, unsigned short* __restrict__ b2l,
    const float* __restrict__ c3w, unsigned short* __restrict__ a3h, unsigned short* __restrict__ a3l) {
  int i = blockIdx.x*256 + threadIdx.x;   // over 93184
  if (i < 1024) {
    int k = i & 31, oc = i >> 5;
    float v = (k < 27) ? c1w[oc*27 + k] : 0.f;
    unsigned short h = f2bf(v);
    a1h[i] = h; a1l[i] = f2bf(v - bf2f(h));
  } else if (i < 19456) {
    int j = i - 1024;
    int ic = j & 31, rem = j >> 5;
    int oc = rem & 63, tap = rem >> 6;
    float v = c2w[(oc*32 + ic)*9 + tap];
    unsigned short h = f2bf(v);
    b2h[j] = h; b2l[j] = f2bf(v - bf2f(h));
  } else if (i < 93184) {
    int j = i - 19456;
    int ic = j & 63, rem = j >> 6;
    int oc = rem & 127, tap = rem >> 7;
    float v = c3w[(oc*64 + ic)*9 + tap];
    unsigned short h = f2bf(v);
    a3h[j] = h; a3l[j] = f2bf(v - bf2f(h));
  }
}

// ====== generic pack body (verbatim from k_pack): in[e][R][C] -> packed hi/lo
__device__ inline void pack_body(const float* __restrict__ in,
    unsigned short* __restrict__ oh, unsigned short* __restrict__ ol,
    int R, int C, int bx, int by, int e, int t, float (*tile)[65]) {
  const size_t eb = (size_t)e * R * C;
  const int c0 = bx*64, r0 = by*64;
  const int cc = t & 63, r4 = t >> 6;
  #pragma unroll
  for (int j = 0; j < 16; ++j) {
    int rr = r4 + j*4;
    tile[rr][cc] = in[eb + (size_t)(r0+rr)*C + c0 + cc];
  }
  __syncthreads();
  const int K32 = R >> 5;
  #pragma unroll
  for (int j = 0; j < 16; ++j) {
    int idx = t + j*256;
    int jin = idx & 7, lane = (idx >> 3) & 63, ksl = (idx >> 9) & 1, ntl = idx >> 10;
    int kl = ksl*32 + ((lane >> 4) << 3) + jin;
    int nl = ntl*16 + (lane & 15);
    float v = tile[kl][nl];
    unsigned short h = f2bf(v);
    size_t o = eb + ((size_t)(((c0 >> 4) + ntl)*K32 + (r0 >> 5) + ksl)*64 + lane)*8 + jin;
    oh[o] = h;
    ol[o] = f2bf(v - bf2f(h));
  }
}

// ====== merged packs: ew1(1024 blk) + ew2(1024) + fcw(128) + ow(1024) = 3200 blocks
__global__ __launch_bounds__(256) void k_packall(
    const float* __restrict__ ew1, unsigned short* __restrict__ w1th, unsigned short* __restrict__ w1tl,
    const float* __restrict__ ew2, unsigned short* __restrict__ w2th, unsigned short* __restrict__ w2tl,
    const float* __restrict__ fcw, unsigned short* __restrict__ wfh,  unsigned short* __restrict__ wfl,
    const float* __restrict__ ow,  unsigned short* __restrict__ owh,  unsigned short* __restrict__ owl) {
  __shared__ float tile[64][65];
  const int b = blockIdx.x;
  const int t = threadIdx.x;
  if (b < 1024) {                       // ew1: R=256, C=1024, grid (16,4,16)
    int bx = b & 15, by = (b >> 4) & 3, e = b >> 6;
    pack_body(ew1, w1th, w1tl, 256, 1024, bx, by, e, t, tile);
  } else if (b < 2048) {                // ew2: R=1024, C=256, grid (4,16,16)
    int lb = b - 1024;
    int bx = lb & 3, by = (lb >> 2) & 15, e = lb >> 6;
    pack_body(ew2, w2th, w2tl, 1024, 256, bx, by, e, t, tile);
  } else if (b < 2176) {                // fcw: R=2048, C=256, grid (4,32,1)
    int lb = b - 2048;
    int bx = lb & 3, by = lb >> 2;
    pack_body(fcw, wfh, wfl, 2048, 256, bx, by, 0, t, tile);
  } else {                              // ow pack (elementwise, 1024 blocks)
    int lb = b - 2176;
    int i = lb*256 + t;                 // over 262144
    int j = i & 7, lane = (i >> 3) & 63, ks = (i >> 9) & 7, nt = i >> 12;
    int k = ks*32 + ((lane >> 4) << 3) + j;
    int n = nt*16 + (lane & 15);
    float v = (n < NCLS) ? ow[(size_t)k*NCLS + n] : 0.f;
    unsigned short h = f2bf(v);
    owh[i] = h;
    owl[i] = f2bf(v - bf2f(h));
  }
}

// ============ fused conv1(reg-im2col bf16x2 MFMA) + conv2(bf16x2 MFMA, 3-term) per image ====
// R24: ishB pl-stride padded 4->5 slots (80B) so bank = (20*pl + 4*slot) % 32 spreads over
// 8 positions; conv2 B-reads drop from ~4-way to ~2-way conflicts. Values bit-exact.
__global__ __launch_bounds__(512, 4) void k_conv12(const float* __restrict__ x,
    const unsigned short* __restrict__ wA1h, const unsigned short* __restrict__ wA1l,
    const float* __restrict__ b1,
    const unsigned short* __restrict__ wBh, const unsigned short* __restrict__ wBl,
    const float* __restrict__ b2, float* __restrict__ outB) {
  __shared__ unsigned int xsu[3*34*36];     // packed bf16 hi/lo image (14.7 KB)
  __shared__ __align__(16) unsigned short ishB[2][12960]; // [pl][5 slots][8] padded (51.8 KB); reused for store
  __shared__ float bs1[32];
  __shared__ float bs2[64];
  const int t = threadIdx.x;
  const int img = blockIdx.x;
  for (int i = t; i < 3*34*36; i += 512) xsu[i] = 0u;
  {
    unsigned int* z = (unsigned int*)&ishB[0][0];
    for (int i = t; i < 12960; i += 512) z[i] = 0u;   // 2 planes x 12960 shorts = 12960 u32
  }
  __syncthreads();
  for (int i = t; i < 3072; i += 512) {
    int ic = i >> 10, rem = i & 1023, y = rem >> 5, xx = rem & 31;
    float v = x[(size_t)img*3072 + i];
    unsigned short h = f2bf(v);
    unsigned short l = f2bf(v - bf2f(h));
    xsu[ic*34*36 + (y+1)*36 + (xx+1)] = ((unsigned int)l << 16) | (unsigned int)h;
  }
  if (t < 32) bs1[t] = b1[t];
  else if (t >= 64 && t < 128) bs2[t-64] = b2[t-64];

  const int lane = t & 63, wvv = t >> 6;
  const int lr = lane & 15, lq = lane >> 4;

  const int oct1 = wvv & 1;
  const bf16x8 a1h = *(const bf16x8*)&wA1h[((oct1*16 + lr) << 5) + lq*8];
  const bf16x8 a1l = *(const bf16x8*)&wA1l[((oct1*16 + lr) << 5) + lq*8];

  int koff[8];
  #pragma unroll
  for (int j = 0; j < 8; ++j) {
    int k = lq*8 + j;
    if (k < 27) {
      int ic = k/9, tap = k - ic*9, dy = tap/3, dx = tap - dy*3;
      koff[j] = ic*34*36 + dy*36 + dx;
    } else koff[j] = -1;
  }
  __syncthreads();

  // ---- conv1 via MFMA, barrier-free: 8 passes of 4 pre-pool rows ----
  {
    const int rp  = wvv >> 1;
    const int ly0 = (rp >> 1) << 1;      // 0 or 2
    const int xh  = rp & 1;
    const int X   = xh*16 + lr;
    for (int ps = 0; ps < 8; ++ps) {
      const int baseA = (ps*4 + ly0)*36 + X;
      f32x4 aA = (f32x4){0.f,0.f,0.f,0.f}, aB = (f32x4){0.f,0.f,0.f,0.f};
      {
        union { unsigned int u[4]; bf16x8 v; } bh_, bl_;
        #pragma unroll
        for (int jj = 0; jj < 4; ++jj) {
          unsigned int e0 = (koff[2*jj]   >= 0) ? xsu[koff[2*jj]   + baseA] : 0u;
          unsigned int e1 = (koff[2*jj+1] >= 0) ? xsu[koff[2*jj+1] + baseA] : 0u;
          bh_.u[jj] = __builtin_amdgcn_perm(e1, e0, 0x05040100u);
          bl_.u[jj] = __builtin_amdgcn_perm(e1, e0, 0x07060302u);
        }
        aA = __builtin_amdgcn_mfma_f32_16x16x32_bf16(a1h, bh_.v, aA, 0, 0, 0);
        aA = __builtin_amdgcn_mfma_f32_16x16x32_bf16(a1h, bl_.v, aA, 0, 0, 0);
        aA = __builtin_amdgcn_mfma_f32_16x16x32_bf16(a1l, bh_.v, aA, 0, 0, 0);
      }
      {
        union { unsigned int u[4]; bf16x8 v; } bh_, bl_;
        #pragma unroll
        for (int jj = 0; jj < 4; ++jj) {
          unsigned int e0 = (koff[2*jj]   >= 0) ? xsu[koff[2*jj]   + baseA + 36] : 0u;
          unsigned int e1 = (koff[2*jj+1] >= 0) ? xsu[koff[2*jj+1] + baseA + 36] : 0u;
          bh_.u[jj] = __builtin_amdgcn_perm(e1, e0, 0x05040100u);
          bl_.u[jj] = __builtin_amdgcn_perm(e1, e0, 0x07060302u);
        }
        aB = __builtin_amdgcn_mfma_f32_16x16x32_bf16(a1h, bh_.v, aB, 0, 0, 0);
        aB = __builtin_amdgcn_mfma_f32_16x16x32_bf16(a1h, bl_.v, aB, 0, 0, 0);
        aB = __builtin_amdgcn_mfma_f32_16x16x32_bf16(a1l, bh_.v, aB, 0, 0, 0);
      }
      #pragma unroll
      for (int r = 0; r < 4; ++r) {
        float v = fmaxf(aA[r], aB[r]);
        v = fmaxf(v, __shfl_xor(v, 1, 64));
        if ((lr & 1) == 0) {
          int oc = oct1*16 + lq*4 + r;
          int Xp = xh*8 + (lr >> 1);
          int Yp = ps*2 + (ly0 >> 1);
          float m = fmaxf(v + bs1[oc], 0.f);
          unsigned short h = f2bf(m);
          unsigned short l = f2bf(m - bf2f(h));
          int pl = (Yp+1)*18 + (Xp+1);
          int us = (pl*5 + (oc >> 3))*8 + (oc & 7);   // padded layout, slot = oc>>3
          ishB[0][us] = h; ishB[1][us] = l;
        }
      }
    }
  }
  __syncthreads();
  // ---- conv2 bf16x2 MFMA (3-term) + fused pool + relu; A loaded directly per tap ----
  {
    const int mtp = (wvv & 1)*2;
    const int rq = wvv >> 1;
    f32x4 acc[2][4];
    #pragma unroll
    for (int i = 0; i < 2; ++i)
      #pragma unroll
      for (int j = 0; j < 4; ++j) acc[i][j] = (f32x4){0.f,0.f,0.f,0.f};
    #pragma unroll
    for (int tap = 0; tap < 9; ++tap) {
      const int off0 = ((tap*64 + mtp*16     + lr) << 5) + lq*8;
      const int off1 = ((tap*64 + (mtp+1)*16 + lr) << 5) + lq*8;
      bf16x8 ah0 = *(const bf16x8*)&wBh[off0];
      bf16x8 al0 = *(const bf16x8*)&wBl[off0];
      bf16x8 ah1 = *(const bf16x8*)&wBh[off1];
      bf16x8 al1 = *(const bf16x8*)&wBl[off1];
      const int dy = tap/3, dx = tap - dy*3;
      #pragma unroll
      for (int j = 0; j < 4; ++j) {
        int pl = (rq*4 + j + dy)*18 + lr + dx;
        int slot = pl*5 + lq;                        // padded layout, slot = lq
        bf16x8 bh = *(const bf16x8*)&ishB[0][slot << 3];
        bf16x8 bl = *(const bf16x8*)&ishB[1][slot << 3];
        acc[0][j] = __builtin_amdgcn_mfma_f32_16x16x32_bf16(ah0, bh, acc[0][j], 0, 0, 0);
        acc[1][j] = __builtin_amdgcn_mfma_f32_16x16x32_bf16(ah1, bh, acc[1][j], 0, 0, 0);
        acc[0][j] = __builtin_amdgcn_mfma_f32_16x16x32_bf16(ah0, bl, acc[0][j], 0, 0, 0);
        acc[1][j] = __builtin_amdgcn_mfma_f32_16x16x32_bf16(ah1, bl, acc[1][j], 0, 0, 0);
        acc[0][j] = __builtin_amdgcn_mfma_f32_16x16x32_bf16(al0, bh, acc[0][j], 0, 0, 0);
        acc[1][j] = __builtin_amdgcn_mfma_f32_16x16x32_bf16(al1, bh, acc[1][j], 0, 0, 0);
      }
    }
    __syncthreads();
    float* ps2 = (float*)&ishB[0][0];
    #pragma unroll
    for (int m = 0; m < 2; ++m)
      #pragma unroll
      for (int k = 0; k < 2; ++k)
        #pragma unroll
        for (int r = 0; r < 4; ++r) {
          float v = fmaxf(acc[m][2*k][r], acc[m][2*k+1][r]);
          v = fmaxf(v, __shfl_xor(v, 1, 64));
          if ((lr & 1) == 0) {
            int oc = (mtp + m)*16 + lq*4 + r;
            int Y = rq*2 + k, X = lr >> 1;
            ps2[oc*65 + Y*8 + X] = fmaxf(v + bs2[oc], 0.f);
          }
        }
    __syncthreads();
    float* op = outB + (size_t)img*4096;
    #pragma unroll
    for (int jj = 0; jj < 8; ++jj) {
      int i = jj*512 + t;
      op[i] = ps2[(i >> 6)*65 + (i & 63)];
    }
  }
}

// ================= conv3 v5: bf16x2 split MFMA (3-term); emits C as bf16 hi/lo ==========
__global__ __launch_bounds__(256) void k_conv3(const float* __restrict__ inB,
    const unsigned short* __restrict__ wAh, const unsigned short* __restrict__ wAl,
    const float* __restrict__ bias,
    unsigned short* __restrict__ Chh, unsigned short* __restrict__ Chl) {
  __shared__ unsigned short ish[2][6400];
  const int t = threadIdx.x;
  const int img = blockIdx.x;
  {
    unsigned int* z = (unsigned int*)&ish[0][0];
    #pragma unroll
    for (int j = 0; j < 25; ++j) z[t + 256*j] = 0u;
  }
  __syncthreads();
  {
    const float* src = inB + (size_t)img*4096;
    #pragma unroll
    for (int j = 0; j < 16; ++j) {
      int f = t + 256*j;
      int ic = f >> 6, p = f & 63;
      int pl = ((p >> 3) + 1)*10 + (p & 7) + 1;
      float v = src[f];
      unsigned short h = f2bf(v);
      unsigned short l = f2bf(v - bf2f(h));
      int u = pl*64 + ic;
      int us = (((u >> 3) ^ (pl & 7)) << 3) | (u & 7);
      ish[0][us] = h; ish[1][us] = l;
    }
  }
  __syncthreads();

  const int lane = t & 63, wid = t >> 6;
  const int lr = lane & 15, lq = lane >> 4;
  const int mt0 = wid*2;
  const int yb = lr >> 3, xb = lr & 7;

  f32x4 acc[2][4];
  #pragma unroll
  for (int i = 0; i < 2; ++i)
    #pragma unroll
    for (int j = 0; j < 4; ++j) acc[i][j] = (f32x4){0.f,0.f,0.f,0.f};

  for (int tap = 0; tap < 9; ++tap) {
    const int dy = tap/3, dx = tap - dy*3;
    #pragma unroll
    for (int kc = 0; kc < 2; ++kc) {
      const int kb = kc*32 + lq*8;
      const int wbase = ((tap << 7) << 6) + kb;
      bf16x8 a0h = *(const bf16x8*)&wAh[wbase + ((mt0*16 + lr) << 6)];
      bf16x8 a0l = *(const bf16x8*)&wAl[wbase + ((mt0*16 + lr) << 6)];
      bf16x8 a1h = *(const bf16x8*)&wAh[wbase + (((mt0+1)*16 + lr) << 6)];
      bf16x8 a1l = *(const bf16x8*)&wAl[wbase + (((mt0+1)*16 + lr) << 6)];
      #pragma unroll
      for (int nt = 0; nt < 4; ++nt) {
        const int pl = (2*nt + yb + dy)*10 + xb + dx;
        const int u = pl*64 + kb;
        const int us = (((u >> 3) ^ (pl & 7)) << 3);
        bf16x8 bh = *(const bf16x8*)&ish[0][us];
        bf16x8 bl = *(const bf16x8*)&ish[1][us];
        acc[0][nt] = __builtin_amdgcn_mfma_f32_16x16x32_bf16(a0h, bh, acc[0][nt], 0, 0, 0);
        acc[0][nt] = __builtin_amdgcn_mfma_f32_16x16x32_bf16(a0h, bl, acc[0][nt], 0, 0, 0);
        acc[0][nt] = __builtin_amdgcn_mfma_f32_16x16x32_bf16(a0l, bh, acc[0][nt], 0, 0, 0);
        acc[1][nt] = __builtin_amdgcn_mfma_f32_16x16x32_bf16(a1h, bh, acc[1][nt], 0, 0, 0);
        acc[1][nt] = __builtin_amdgcn_mfma_f32_16x16x32_bf16(a1h, bl, acc[1][nt], 0, 0, 0);
        acc[1][nt] = __builtin_amdgcn_mfma_f32_16x16x32_bf16(a1l, bh, acc[1][nt], 0, 0, 0);
      }
    }
  }
  __syncthreads();
  float* stg = (float*)&ish[0][0];   // [128 oc][17]
  #pragma unroll
  for (int mtl = 0; mtl < 2; ++mtl)
    #pragma unroll
    for (int nt = 0; nt < 4; ++nt)
      #pragma unroll
      for (int r = 0; r < 4; ++r) {
        float v = acc[mtl][nt][r];
        v = fmaxf(v, __shfl_xor(v, 1, 64));
        v = fmaxf(v, __shfl_xor(v, 8, 64));
        if ((lane & 9) == 0) {
          int oc = (mt0 + mtl)*16 + lq*4 + r;
          int pix = nt*4 + (xb >> 1);
          stg[oc*17 + pix] = fmaxf(v + bias[oc], 0.f);
        }
      }
  __syncthreads();
  #pragma unroll
  for (int j = 0; j < 8; ++j) {
    int i = t + 256*j;
    float v = stg[(i >> 4)*17 + (i & 15)];
    unsigned short h = f2bf(v);
    Chh[(size_t)img*2048 + i] = h;
    Chl[(size_t)img*2048 + i] = f2bf(v - bf2f(h));
  }
}

// ================= FC GEMM v2: bf16x2 3-term MFMA, no LDS, split-K=4 =================
__global__ __launch_bounds__(256) void k_fc(const unsigned short* __restrict__ Chh,
    const unsigned short* __restrict__ Chl,
    const unsigned short* __restrict__ wfh, const unsigned short* __restrict__ wfl,
    float* __restrict__ P0, float* __restrict__ P1,
    float* __restrict__ P2, float* __restrict__ P3) {
  const int t = threadIdx.x;
  const int r0 = blockIdx.x * 32;
  const int kq = blockIdx.z;
  float* __restrict__ P = (kq == 0) ? P0 : (kq == 1) ? P1 : (kq == 2) ? P2 : P3;
  const int lane = t & 63, wv = t >> 6;
  const int lr = lane & 15, lq = lane >> 4;
  f32x4 acc[2][4];
  #pragma unroll
  for (int i = 0; i < 2; ++i)
    #pragma unroll
    for (int j = 0; j < 4; ++j) acc[i][j] = (f32x4){0.f,0.f,0.f,0.f};
  #pragma unroll 4
  for (int ks = 0; ks < 16; ++ks) {
    bf16x8 ah[2], al[2];
    #pragma unroll
    for (int rt = 0; rt < 2; ++rt) {
      size_t ao = (size_t)(r0 + rt*16 + lr)*2048 + kq*512 + ks*32 + lq*8;
      ah[rt] = *(const bf16x8*)&Chh[ao];
      al[rt] = *(const bf16x8*)&Chl[ao];
    }
    #pragma unroll
    for (int nt = 0; nt < 4; ++nt) {
      size_t bo = ((size_t)((wv*4 + nt)*64 + kq*16 + ks)*64 + lane)*8;
      bf16x8 bh = *(const bf16x8*)&wfh[bo];
      bf16x8 bl = *(const bf16x8*)&wfl[bo];
      acc[0][nt] = __builtin_amdgcn_mfma_f32_16x16x32_bf16(ah[0], bh, acc[0][nt], 0, 0, 0);
      acc[1][nt] = __builtin_amdgcn_mfma_f32_16x16x32_bf16(ah[1], bh, acc[1][nt], 0, 0, 0);
      acc[0][nt] = __builtin_amdgcn_mfma_f32_16x16x32_bf16(ah[0], bl, acc[0][nt], 0, 0, 0);
      acc[1][nt] = __builtin_amdgcn_mfma_f32_16x16x32_bf16(ah[1], bl, acc[1][nt], 0, 0, 0);
      acc[0][nt] = __builtin_amdgcn_mfma_f32_16x16x32_bf16(al[0], bh, acc[0][nt], 0, 0, 0);
      acc[1][nt] = __builtin_amdgcn_mfma_f32_16x16x32_bf16(al[1], bh, acc[1][nt], 0, 0, 0);
    }
  }
  #pragma unroll
  for (int rt = 0; rt < 2; ++rt)
    #pragma unroll
    for (int nt = 0; nt < 4; ++nt)
      #pragma unroll
      for (int r = 0; r < 4; ++r)
        P[(size_t)(r0 + rt*16 + lq*4 + r)*256 + (wv*4 + nt)*16 + lr] = acc[rt][nt][r];
}

// ================= gate: feat = P0+P1+P2+P3+fcb; logits; top-2 softmax; expert lists
__global__ __launch_bounds__(256) void k_gate(const float* __restrict__ P0,
    const float* __restrict__ P1, const float* __restrict__ P2, const float* __restrict__ P3,
    const float* __restrict__ fcb,
    const float* __restrict__ gw, const float* __restrict__ gb,
    float* __restrict__ feat, int* __restrict__ cnt, float* __restrict__ gsum,
    int* __restrict__ lrow, float* __restrict__ lg) {
  __shared__ float ft[16][256];
  __shared__ float lgs[16][16];
  __shared__ float gwl[4096];
  const int t = threadIdx.x;
  const int r0 = blockIdx.x * 16;
  for (int i = t; i < 4096; i += 256) gwl[i] = gw[i];
  float bb = fcb[t];
  #pragma unroll
  for (int r = 0; r < 16; ++r) {
    size_t off = (size_t)(r0+r)*256 + t;
    float v = P0[off] + P1[off] + P2[off] + P3[off] + bb;
    ft[r][t] = v;
    feat[off] = v;
  }
  __syncthreads();
  {
    int r = t >> 4, e = t & 15;
    float s = gb[e];
    for (int k = 0; k < 256; ++k) s = fmaf(ft[r][k], gwl[k*16 + e], s);
    lgs[r][e] = s;
  }
  __syncthreads();
  if (t < 16) {
    int r = t;
    float v1 = -3.402823e38f, v2 = -3.402823e38f;
    int i1 = 0, i2 = 0;
    for (int e = 0; e < 16; ++e) {
      float v = lgs[r][e];
      if (v > v1)      { v2 = v1; i2 = i1; v1 = v; i1 = e; }
      else if (v > v2) { v2 = v;  i2 = e; }
    }
    float ex = __expf(v2 - v1);
    float g1 = 1.f / (1.f + ex);
    float g2 = ex  / (1.f + ex);
    int row = r0 + r;
    int p1 = atomicAdd(&cnt[i1], 1); lrow[i1*4096 + p1] = row; lg[i1*4096 + p1] = g1;
    int p2 = atomicAdd(&cnt[i2], 1); lrow[i2*4096 + p2] = row; lg[i2*4096 + p2] = g2;
    atomicAdd(&gsum[i1], g1);
    atomicAdd(&gsum[i2], g2);
  }
}

// ================= MoE v4: 32-row tiles x split-K(8), bf16x2 MFMA 3-term, packed weights
__global__ __launch_bounds__(256) void k_moe(const float* __restrict__ feat,
    const unsigned short* __restrict__ w1th, const unsigned short* __restrict__ w1tl,
    const unsigned short* __restrict__ w2th, const unsigned short* __restrict__ w2tl,
    const float* __restrict__ eb1, const float* __restrict__ eb2,
    const int* __restrict__ cnt, const int* __restrict__ lrow, const float* __restrict__ lgw,
    float* __restrict__ moe) {
  const int e = blockIdx.y;
  const int n_e = cnt[e];
  const int start = blockIdx.x * 32;
  if (start >= n_e) return;
  const int c = blockIdx.z;
  const int n = min(32, n_e - start);
  __shared__ unsigned short fh[8192], fl[8192];
  __shared__ unsigned short h1h[4096], h1l[4096];
  __shared__ int   rws[32];
  __shared__ float gws[32];
  const int t = threadIdx.x;
  if (t < 32) {
    rws[t] = (t < n) ? lrow[e*4096 + start + t] : 0;
    gws[t] = (t < n) ? lgw[e*4096 + start + t] : 0.f;
  }
  __syncthreads();
  for (int j = 0; j < 32; ++j) {
    float v = (j < n) ? feat[(size_t)rws[j]*256 + t] : 0.f;
    unsigned short h = f2bf(v);
    int us = (j*32 + ((t >> 3) ^ (j & 7)))*8 + (t & 7);
    fh[us] = h; fl[us] = f2bf(v - bf2f(h));
  }
  const int lane = t & 63, wv = t >> 6;
  const int lr = lane & 15, lq = lane >> 4;
  const int rh = wv & 1, qh = wv >> 1;
  const int arow = rh*16 + lr;
  const int rsw = arow & 7;
  const size_t ewb = (size_t)e << 18;

  f32x4 acc2[8];
  #pragma unroll
  for (int i = 0; i < 8; ++i) acc2[i] = (f32x4){0.f,0.f,0.f,0.f};

  __syncthreads();

  {
    f32x4 acc1[4];
    #pragma unroll
    for (int i = 0; i < 4; ++i) acc1[i] = (f32x4){0.f,0.f,0.f,0.f};
    #pragma unroll
    for (int ks = 0; ks < 8; ++ks) {
      int aoff = (arow*32 + ((ks*4 + lq) ^ rsw))*8;
      bf16x8 ah = *(const bf16x8*)&fh[aoff];
      bf16x8 al = *(const bf16x8*)&fl[aoff];
      #pragma unroll
      for (int ht = 0; ht < 4; ++ht) {
        int htile = c*8 + qh*4 + ht;
        size_t bo = ewb + ((size_t)(htile*8 + ks)*64 + lane)*8;
        bf16x8 bh = *(const bf16x8*)&w1th[bo];
        bf16x8 bl = *(const bf16x8*)&w1tl[bo];
        acc1[ht] = __builtin_amdgcn_mfma_f32_16x16x32_bf16(ah, bh, acc1[ht], 0, 0, 0);
        acc1[ht] = __builtin_amdgcn_mfma_f32_16x16x32_bf16(ah, bl, acc1[ht], 0, 0, 0);
        acc1[ht] = __builtin_amdgcn_mfma_f32_16x16x32_bf16(al, bh, acc1[ht], 0, 0, 0);
      }
    }
    __syncthreads();
    #pragma unroll
    for (int ht = 0; ht < 4; ++ht) {
      int hloc = qh*64 + ht*16 + lr;
      float bb = eb1[e*1024 + c*128 + hloc];
      #pragma unroll
      for (int r = 0; r < 4; ++r) {
        int orow = rh*16 + lq*4 + r;
        float v = fmaxf(acc1[ht][r] + bb, 0.f);
        unsigned short hh = f2bf(v);
        int us = (orow*16 + ((hloc >> 3) ^ (orow & 7)))*8 + (hloc & 7);
        h1h[us] = hh; h1l[us] = f2bf(v - bf2f(hh));
      }
    }
    __syncthreads();
    #pragma unroll
    for (int ks = 0; ks < 4; ++ks) {
      int aoff = (arow*16 + ((ks*4 + lq) ^ rsw))*8;
      bf16x8 ah = *(const bf16x8*)&h1h[aoff];
      bf16x8 al = *(const bf16x8*)&h1l[aoff];
      #pragma unroll
      for (int dt = 0; dt < 8; ++dt) {
        int dtile = qh*8 + dt;
        size_t bo = ewb + ((size_t)(dtile*32 + c*4 + ks)*64 + lane)*8;
        bf16x8 bh = *(const bf16x8*)&w2th[bo];
        bf16x8 bl = *(const bf16x8*)&w2tl[bo];
        acc2[dt] = __builtin_amdgcn_mfma_f32_16x16x32_bf16(ah, bh, acc2[dt], 0, 0, 0);
        acc2[dt] = __builtin_amdgcn_mfma_f32_16x16x32_bf16(ah, bl, acc2[dt], 0, 0, 0);
        acc2[dt] = __builtin_amdgcn_mfma_f32_16x16x32_bf16(al, bh, acc2[dt], 0, 0, 0);
      }
    }
  }
  #pragma unroll
  for (int dt = 0; dt < 8; ++dt) {
    int d = qh*128 + dt*16 + lr;
    float b2 = (c == 0) ? eb2[e*256 + d] : 0.f;
    #pragma unroll
    for (int r = 0; r < 4; ++r) {
      int orow = rh*16 + lq*4 + r;
      if (orow < n)
        atomicAdd(&moe[(size_t)rws[orow]*256 + d], gws[orow]*(acc2[dt][r] + b2));
    }
  }
}

// ================= LayerNorm(moe + feat) -> y bf16 hi/lo; block 4096 computes lb_loss ======
__global__ __launch_bounds__(256) void k_ln(const float* __restrict__ feat,
    const float* __restrict__ moe, const float* __restrict__ g, const float* __restrict__ bp,
    unsigned short* __restrict__ yh, unsigned short* __restrict__ yl,
    const float* __restrict__ gsum, float* __restrict__ out_lb) {
  const int r = blockIdx.x, t = threadIdx.x;
  if (r == NB) {            // lb block: wave 0 only, no barriers on this path
    if (t < 64) {
      float term = 0.f;
      if (t < 16) {
        float D = gsum[t] * (1.f/4096.f);
        term = D * logf(D + 1e-8f);
      }
      #pragma unroll
      for (int o = 8; o > 0; o >>= 1) term += __shfl_down(term, o, 64);
      if (t == 0) *out_lb = term;
    }
    return;
  }
  float v = moe[(size_t)r*256 + t] + feat[(size_t)r*256 + t];
  float s = v, q = v * v;
  #pragma unroll
  for (int o = 32; o > 0; o >>= 1) {
    s += __shfl_down(s, o, 64);
    q += __shfl_down(q, o, 64);
  }
  __shared__ float ss[4], qq[4];
  int wv = t >> 6;
  if ((t & 63) == 0) { ss[wv] = s; qq[wv] = q; }
  __syncthreads();
  float S = ss[0]+ss[1]+ss[2]+ss[3];
  float Q = qq[0]+qq[1]+qq[2]+qq[3];
  float mu  = S * (1.f/256.f);
  float var = Q * (1.f/256.f) - mu*mu;
  float inv = rsqrtf(var + 1e-5f);
  float y = (v - mu) * inv * g[t] + bp[t];
  unsigned short h = f2bf(y);
  yh[(size_t)r*256 + t] = h;
  yl[(size_t)r*256 + t] = f2bf(y - bf2f(h));
}

// ================= output GEMM v2: bf16x2 3-term MFMA, no LDS =================
__global__ __launch_bounds__(256) void k_out(const unsigned short* __restrict__ yh,
    const unsigned short* __restrict__ yl,
    const unsigned short* __restrict__ owh, const unsigned short* __restrict__ owl,
    const float* __restrict__ ob, float* __restrict__ out) {
  const int t = threadIdx.x;
  const int r0 = blockIdx.x * 32;
  const int lane = t & 63, wv = t >> 6;
  const int lr = lane & 15, lq = lane >> 4;
  const int ntile = blockIdx.y*4 + wv;
  f32x4 acc[2];
  acc[0] = (f32x4){0.f,0.f,0.f,0.f};
  acc[1] = (f32x4){0.f,0.f,0.f,0.f};
  #pragma unroll
  for (int ks = 0; ks < 8; ++ks) {
    bf16x8 bh = *(const bf16x8*)&owh[((size_t)(ntile*8 + ks)*64 + lane)*8];
    bf16x8 bl = *(const bf16x8*)&owl[((size_t)(ntile*8 + ks)*64 + lane)*8];
    #pragma unroll
    for (int rt = 0; rt < 2; ++rt) {
      size_t ao = (size_t)(r0 + rt*16 + lr)*256 + ks*32 + lq*8;
      bf16x8 ah = *(const bf16x8*)&yh[ao];
      bf16x8 al = *(const bf16x8*)&yl[ao];
      acc[rt] = __builtin_amdgcn_mfma_f32_16x16x32_bf16(ah, bh, acc[rt], 0, 0, 0);
      acc[rt] = __builtin_amdgcn_mfma_f32_16x16x32_bf16(ah, bl, acc[rt], 0, 0, 0);
      acc[rt] = __builtin_amdgcn_mfma_f32_16x16x32_bf16(al, bh, acc[rt], 0, 0, 0);
    }
  }
  const int col = ntile*16 + lr;
  if (col < NCLS) {
    float bb = ob[col];
    #pragma unroll
    for (int rt = 0; rt < 2; ++rt)
      #pragma unroll
      for (int r = 0; r < 4; ++r)
        out[(size_t)(r0 + rt*16 + lq*4 + r)*NCLS + col] = acc[rt][r] + bb;
  }
}

// ================= launch =================
extern "C" void kernel_launch(void* const* d_in, const int* in_sizes, int n_in,
                              void* d_out, int out_size, void* d_ws, size_t ws_size,
                              hipStream_t stream) {
  const float* x   = (const float*)d_in[0];
  const float* c1w = (const float*)d_in[1];
  const float* c1b = (const float*)d_in[2];
  const float* c2w = (const float*)d_in[3];
  const float* c2b = (const float*)d_in[4];
  const float* c3w = (const float*)d_in[5];
  const float* c3b = (const float*)d_in[6];
  const float* fcw = (const float*)d_in[7];
  const float* fcb = (const float*)d_in[8];
  const float* gw  = (const float*)d_in[9];
  const float* gb  = (const float*)d_in[10];
  const float* ew1 = (const float*)d_in[11];
  const float* eb1 = (const float*)d_in[12];
  const float* ew2 = (const float*)d_in[13];
  const float* eb2 = (const float*)d_in[14];
  const float* lng = (const float*)d_in[15];
  const float* lnb = (const float*)d_in[16];
  const float* ow  = (const float*)d_in[17];
  const float* ob  = (const float*)d_in[18];
  char* ws = (char*)d_ws;
  float* Bb   = (float*)(ws + OFF_B);
  float* P0   = (float*)(ws + OFF_P0);
  float* P1   = (float*)(ws + OFF_P1);
  float* P2   = (float*)(ws + OFF_P2);
  float* P3   = (float*)(ws + OFF_P3);
  unsigned short* Chh = (unsigned short*)(ws + OFF_CHH);
  unsigned short* Chl = (unsigned short*)(ws + OFF_CHL);
  unsigned short* wBh = (unsigned short*)(ws + OFF_CHH);   // aliases Chh (written after conv12)
  unsigned short* wBl = (unsigned short*)(ws + OFF_WBL);
  unsigned short* wA1h = (unsigned short*)(ws + OFF_WA1H);
  unsigned short* wA1l = (unsigned short*)(ws + OFF_WA1L);
  unsigned short* wAh = (unsigned short*)(ws + OFF_FEAT);  // aliases feat (written later)
  unsigned short* wAl = (unsigned short*)(ws + OFF_WAL);
  unsigned short* w1th = (unsigned short*)(ws + OFF_W1TH);
  unsigned short* w1tl = (unsigned short*)(ws + OFF_W1TL);
  unsigned short* w2th = (unsigned short*)(ws + OFF_W2TH);
  unsigned short* w2tl = (unsigned short*)(ws + OFF_W2TL);
  unsigned short* wfh = (unsigned short*)(ws + OFF_WFCH);
  unsigned short* wfl = (unsigned short*)(ws + OFF_WFCL);
  unsigned short* owph = (unsigned short*)(ws + OFF_OWH);
  unsigned short* owpl = (unsigned short*)(ws + OFF_OWL);
  unsigned short* yh = (unsigned short*)(ws + OFF_P0);     // aliases P0 (dead after gate)
  unsigned short* yl = (unsigned short*)(ws + OFF_P1);     // aliases P1
  float* feat = (float*)(ws + OFF_FEAT);
  float* moe  = (float*)(ws + OFF_MOE);
  int*   cnt  = (int*)(ws + OFF_CNT);
  float* gsum = (float*)(ws + OFF_GSUM);
  int*   lrow = (int*)(ws + OFF_LROW);
  float* lgv  = (float*)(ws + OFF_LG);
  float* outp = (float*)d_out;

  hipMemsetAsync(ws + OFF_MOE, 0, 4194304 + 128, stream);

  hipLaunchKernelGGL(k_wprep,  dim3(364),     dim3(256), 0, stream,
                     c1w, wA1h, wA1l, c2w, wBh, wBl, c3w, wAh, wAl);
  hipLaunchKernelGGL(k_conv12, dim3(4096),    dim3(512), 0, stream, x, wA1h, wA1l, c1b, wBh, wBl, c2b, Bb);
  hipLaunchKernelGGL(k_conv3,  dim3(4096),    dim3(256), 0, stream, Bb, wAh, wAl, c3b, Chh, Chl);
  // Bb dead now -> build ALL packed weights that live in its region (one kernel)
  hipLaunchKernelGGL(k_packall, dim3(3200),   dim3(256), 0, stream,
                     ew1, w1th, w1tl, ew2, w2th, w2tl, fcw, wfh, wfl, ow, owph, owpl);
  hipLaunchKernelGGL(k_fc,     dim3(128, 1, 4), dim3(256), 0, stream, Chh, Chl, wfh, wfl, P0, P1, P2, P3);
  hipLaunchKernelGGL(k_gate,   dim3(256),     dim3(256), 0, stream, P0, P1, P2, P3, fcb, gw, gb,
                     feat, cnt, gsum, lrow, lgv);
  hipLaunchKernelGGL(k_moe,    dim3(128, 16, 8), dim3(256), 0, stream, feat, w1th, w1tl, w2th, w2tl,
                     eb1, eb2, cnt, lrow, lgv, moe);
  hipLaunchKernelGGL(k_ln,     dim3(4097),    dim3(256), 0, stream, feat, moe, lng, lnb, yh, yl,
                     gsum, outp + (size_t)NB*NCLS);
  hipLaunchKernelGGL(k_out,    dim3(128, 16), dim3(256), 0, stream, yh, yl, owph, owpl, ob, outp);
}

// Round 25
// 749.198 us; speedup vs baseline: 1.0862x; 1.0517x over previous
//
#include <hip/hip_runtime.h>
#include <hip/hip_bf16.h>

typedef short bf16x8 __attribute__((ext_vector_type(8)));
typedef float f32x4 __attribute__((ext_vector_type(4)));

// ---------------- problem sizes ----------------
#define NB   4096
#define NEXP 16
#define DDIM 256
#define HDIM 1024
#define NCLS 1000

// ---------------- workspace layout (bytes) ----------------
// NOTE: Bb (conv2 out, 67 MB at offset 0) is live from conv12 until conv3 completes.
// ALL packed-weight regions below OFF_CHH alias Bb -> their pack kernels MUST run after conv3.
#define OFF_B    ((size_t)0)
#define OFF_P0   ((size_t)0)           // f32 [4096][256] FC partial (kq 0); ALSO yh after gate
#define OFF_P1   ((size_t)4194304)     // f32 [4096][256] FC partial (kq 1); ALSO yl after gate
#define OFF_W1TH ((size_t)8388608)     // bf16 packed [16][64 ht][8 ks][64 lane][8]  8 MB
#define OFF_W1TL ((size_t)16777216)
#define OFF_W2TH ((size_t)25165824)    // bf16 packed [16][16 dt][32 ks][64 lane][8] 8 MB
#define OFF_W2TL ((size_t)33554432)
#define OFF_WFCH ((size_t)41943040)    // fcw packed hi (1 MB)
#define OFF_WFCL ((size_t)42991616)    // fcw packed lo (1 MB)
#define OFF_P2   ((size_t)44040192)    // f32 [4096][256] FC partial (kq 2)
#define OFF_P3   ((size_t)48234496)    // f32 [4096][256] FC partial (kq 3)
#define OFF_OWH  ((size_t)52428800)    // ow packed hi [64 nt][8 ks][64][8] (512 KB)
#define OFF_OWL  ((size_t)53477376)
#define OFF_CHH  ((size_t)67108864)    // conv3 out hi bf16 [4096][2048]; ALSO wBh/wBl/wA1 before conv12
#define OFF_CHL  ((size_t)83886080)    // conv3 out lo bf16
#define OFF_WBL  ((size_t)67145728)
#define OFF_WA1H ((size_t)67182592)
#define OFF_WA1L ((size_t)67184640)
#define OFF_FEAT ((size_t)100663296)   // f32 [4096][256]; ALSO wAh/wAl (288 KB) before k_gate
#define OFF_WAL  ((size_t)100810752)
#define OFF_MOE  ((size_t)104857600)   // f32 [4096][256]
#define OFF_CNT  ((size_t)109051904)   // int [16]
#define OFF_GSUM ((size_t)109051968)   // f32 [16]
#define OFF_LROW ((size_t)109052032)   // int [16][4096]
#define OFF_LG   ((size_t)109314176)   // f32 [16][4096]

__device__ inline unsigned short f2bf(float v) {
  __hip_bfloat16 h = __float2bfloat16(v);
  return *(unsigned short*)&h;
}
__device__ inline float bf2f(unsigned short u) {
  union { unsigned int i; float f; } c; c.i = ((unsigned int)u) << 16; return c.f;
}

// ====== merged weight prep: conv1(1024) + conv2(18432) + conv3(73728) elems, range-split
__global__ __launch_bounds__(256) void k_wprep(
    const float* __restrict__ c1w, unsigned short* __restrict__ a1h, unsigned short* __restrict__ a1l,
    const float* __restrict__ c2w, unsigned short* __restrict__ b2h, unsigned short* __restrict__ b2l,
    const float* __restrict__ c3w, unsigned short* __restrict__ a3h, unsigned short* __restrict__ a3l) {
  int i = blockIdx.x*256 + threadIdx.x;   // over 93184
  if (i < 1024) {
    int k = i & 31, oc = i >> 5;
    float v = (k < 27) ? c1w[oc*27 + k] : 0.f;
    unsigned short h = f2bf(v);
    a1h[i] = h; a1l[i] = f2bf(v - bf2f(h));
  } else if (i < 19456) {
    int j = i - 1024;
    int ic = j & 31, rem = j >> 5;
    int oc = rem & 63, tap = rem >> 6;
    float v = c2w[(oc*32 + ic)*9 + tap];
    unsigned short h = f2bf(v);
    b2h[j] = h; b2l[j] = f2bf(v - bf2f(h));
  } else if (i < 93184) {
    int j = i - 19456;
    int ic = j & 63, rem = j >> 6;
    int oc = rem & 127, tap = rem >> 7;
    float v = c3w[(oc*64 + ic)*9 + tap];
    unsigned short h = f2bf(v);
    a3h[j] = h; a3l[j] = f2bf(v - bf2f(h));
  }
}

// ====== generic pack body (verbatim from k_pack): in[e][R][C] -> packed hi/lo
__device__ inline void pack_body(const float* __restrict__ in,
    unsigned short* __restrict__ oh, unsigned short* __restrict__ ol,
    int R, int C, int bx, int by, int e, int t, float (*tile)[65]) {
  const size_t eb = (size_t)e * R * C;
  const int c0 = bx*64, r0 = by*64;
  const int cc = t & 63, r4 = t >> 6;
  #pragma unroll
  for (int j = 0; j < 16; ++j) {
    int rr = r4 + j*4;
    tile[rr][cc] = in[eb + (size_t)(r0+rr)*C + c0 + cc];
  }
  __syncthreads();
  const int K32 = R >> 5;
  #pragma unroll
  for (int j = 0; j < 16; ++j) {
    int idx = t + j*256;
    int jin = idx & 7, lane = (idx >> 3) & 63, ksl = (idx >> 9) & 1, ntl = idx >> 10;
    int kl = ksl*32 + ((lane >> 4) << 3) + jin;
    int nl = ntl*16 + (lane & 15);
    float v = tile[kl][nl];
    unsigned short h = f2bf(v);
    size_t o = eb + ((size_t)(((c0 >> 4) + ntl)*K32 + (r0 >> 5) + ksl)*64 + lane)*8 + jin;
    oh[o] = h;
    ol[o] = f2bf(v - bf2f(h));
  }
}

// ====== merged packs: ew1(1024 blk) + ew2(1024) + fcw(128) + ow(1024) = 3200 blocks
__global__ __launch_bounds__(256) void k_packall(
    const float* __restrict__ ew1, unsigned short* __restrict__ w1th, unsigned short* __restrict__ w1tl,
    const float* __restrict__ ew2, unsigned short* __restrict__ w2th, unsigned short* __restrict__ w2tl,
    const float* __restrict__ fcw, unsigned short* __restrict__ wfh,  unsigned short* __restrict__ wfl,
    const float* __restrict__ ow,  unsigned short* __restrict__ owh,  unsigned short* __restrict__ owl) {
  __shared__ float tile[64][65];
  const int b = blockIdx.x;
  const int t = threadIdx.x;
  if (b < 1024) {                       // ew1: R=256, C=1024, grid (16,4,16)
    int bx = b & 15, by = (b >> 4) & 3, e = b >> 6;
    pack_body(ew1, w1th, w1tl, 256, 1024, bx, by, e, t, tile);
  } else if (b < 2048) {                // ew2: R=1024, C=256, grid (4,16,16)
    int lb = b - 1024;
    int bx = lb & 3, by = (lb >> 2) & 15, e = lb >> 6;
    pack_body(ew2, w2th, w2tl, 1024, 256, bx, by, e, t, tile);
  } else if (b < 2176) {                // fcw: R=2048, C=256, grid (4,32,1)
    int lb = b - 2048;
    int bx = lb & 3, by = lb >> 2;
    pack_body(fcw, wfh, wfl, 2048, 256, bx, by, 0, t, tile);
  } else {                              // ow pack (elementwise, 1024 blocks)
    int lb = b - 2176;
    int i = lb*256 + t;                 // over 262144
    int j = i & 7, lane = (i >> 3) & 63, ks = (i >> 9) & 7, nt = i >> 12;
    int k = ks*32 + ((lane >> 4) << 3) + j;
    int n = nt*16 + (lane & 15);
    float v = (n < NCLS) ? ow[(size_t)k*NCLS + n] : 0.f;
    unsigned short h = f2bf(v);
    owh[i] = h;
    owl[i] = f2bf(v - bf2f(h));
  }
}

// ============ fused conv1(reg-im2col bf16x2 MFMA) + conv2(bf16x2 MFMA, 3-term) per image ====
// R24: ishB pl-stride padded 4->5 slots (80B) so bank = (20*pl + 4*slot) % 32 spreads over
// 8 positions; conv2 B-reads drop from ~4-way to ~2-way conflicts. Values bit-exact.
__global__ __launch_bounds__(512, 4) void k_conv12(const float* __restrict__ x,
    const unsigned short* __restrict__ wA1h, const unsigned short* __restrict__ wA1l,
    const float* __restrict__ b1,
    const unsigned short* __restrict__ wBh, const unsigned short* __restrict__ wBl,
    const float* __restrict__ b2, float* __restrict__ outB) {
  __shared__ unsigned int xsu[3*34*36];     // packed bf16 hi/lo image (14.7 KB)
  __shared__ __align__(16) unsigned short ishB[2][12960]; // [pl][5 slots][8] padded (51.8 KB); reused for store
  __shared__ float bs1[32];
  __shared__ float bs2[64];
  const int t = threadIdx.x;
  const int img = blockIdx.x;
  for (int i = t; i < 3*34*36; i += 512) xsu[i] = 0u;
  {
    unsigned int* z = (unsigned int*)&ishB[0][0];
    for (int i = t; i < 12960; i += 512) z[i] = 0u;   // 2 planes x 12960 shorts = 12960 u32
  }
  __syncthreads();
  for (int i = t; i < 3072; i += 512) {
    int ic = i >> 10, rem = i & 1023, y = rem >> 5, xx = rem & 31;
    float v = x[(size_t)img*3072 + i];
    unsigned short h = f2bf(v);
    unsigned short l = f2bf(v - bf2f(h));
    xsu[ic*34*36 + (y+1)*36 + (xx+1)] = ((unsigned int)l << 16) | (unsigned int)h;
  }
  if (t < 32) bs1[t] = b1[t];
  else if (t >= 64 && t < 128) bs2[t-64] = b2[t-64];

  const int lane = t & 63, wvv = t >> 6;
  const int lr = lane & 15, lq = lane >> 4;

  const int oct1 = wvv & 1;
  const bf16x8 a1h = *(const bf16x8*)&wA1h[((oct1*16 + lr) << 5) + lq*8];
  const bf16x8 a1l = *(const bf16x8*)&wA1l[((oct1*16 + lr) << 5) + lq*8];

  int koff[8];
  #pragma unroll
  for (int j = 0; j < 8; ++j) {
    int k = lq*8 + j;
    if (k < 27) {
      int ic = k/9, tap = k - ic*9, dy = tap/3, dx = tap - dy*3;
      koff[j] = ic*34*36 + dy*36 + dx;
    } else koff[j] = -1;
  }
  __syncthreads();

  // ---- conv1 via MFMA, barrier-free: 8 passes of 4 pre-pool rows ----
  {
    const int rp  = wvv >> 1;
    const int ly0 = (rp >> 1) << 1;      // 0 or 2
    const int xh  = rp & 1;
    const int X   = xh*16 + lr;
    for (int ps = 0; ps < 8; ++ps) {
      const int baseA = (ps*4 + ly0)*36 + X;
      f32x4 aA = (f32x4){0.f,0.f,0.f,0.f}, aB = (f32x4){0.f,0.f,0.f,0.f};
      {
        union { unsigned int u[4]; bf16x8 v; } bh_, bl_;
        #pragma unroll
        for (int jj = 0; jj < 4; ++jj) {
          unsigned int e0 = (koff[2*jj]   >= 0) ? xsu[koff[2*jj]   + baseA] : 0u;
          unsigned int e1 = (koff[2*jj+1] >= 0) ? xsu[koff[2*jj+1] + baseA] : 0u;
          bh_.u[jj] = __builtin_amdgcn_perm(e1, e0, 0x05040100u);
          bl_.u[jj] = __builtin_amdgcn_perm(e1, e0, 0x07060302u);
        }
        aA = __builtin_amdgcn_mfma_f32_16x16x32_bf16(a1h, bh_.v, aA, 0, 0, 0);
        aA = __builtin_amdgcn_mfma_f32_16x16x32_bf16(a1h, bl_.v, aA, 0, 0, 0);
        aA = __builtin_amdgcn_mfma_f32_16x16x32_bf16(a1l, bh_.v, aA, 0, 0, 0);
      }
      {
        union { unsigned int u[4]; bf16x8 v; } bh_, bl_;
        #pragma unroll
        for (int jj = 0; jj < 4; ++jj) {
          unsigned int e0 = (koff[2*jj]   >= 0) ? xsu[koff[2*jj]   + baseA + 36] : 0u;
          unsigned int e1 = (koff[2*jj+1] >= 0) ? xsu[koff[2*jj+1] + baseA + 36] : 0u;
          bh_.u[jj] = __builtin_amdgcn_perm(e1, e0, 0x05040100u);
          bl_.u[jj] = __builtin_amdgcn_perm(e1, e0, 0x07060302u);
        }
        aB = __builtin_amdgcn_mfma_f32_16x16x32_bf16(a1h, bh_.v, aB, 0, 0, 0);
        aB = __builtin_amdgcn_mfma_f32_16x16x32_bf16(a1h, bl_.v, aB, 0, 0, 0);
        aB = __builtin_amdgcn_mfma_f32_16x16x32_bf16(a1l, bh_.v, aB, 0, 0, 0);
      }
      #pragma unroll
      for (int r = 0; r < 4; ++r) {
        float v = fmaxf(aA[r], aB[r]);
        v = fmaxf(v, __shfl_xor(v, 1, 64));
        if ((lr & 1) == 0) {
          int oc = oct1*16 + lq*4 + r;
          int Xp = xh*8 + (lr >> 1);
          int Yp = ps*2 + (ly0 >> 1);
          float m = fmaxf(v + bs1[oc], 0.f);
          unsigned short h = f2bf(m);
          unsigned short l = f2bf(m - bf2f(h));
          int pl = (Yp+1)*18 + (Xp+1);
          int us = (pl*5 + (oc >> 3))*8 + (oc & 7);   // padded layout, slot = oc>>3
          ishB[0][us] = h; ishB[1][us] = l;
        }
      }
    }
  }
  __syncthreads();
  // ---- conv2 bf16x2 MFMA (3-term) + fused pool + relu; A loaded directly per tap ----
  {
    const int mtp = (wvv & 1)*2;
    const int rq = wvv >> 1;
    f32x4 acc[2][4];
    #pragma unroll
    for (int i = 0; i < 2; ++i)
      #pragma unroll
      for (int j = 0; j < 4; ++j) acc[i][j] = (f32x4){0.f,0.f,0.f,0.f};
    #pragma unroll
    for (int tap = 0; tap < 9; ++tap) {
      const int off0 = ((tap*64 + mtp*16     + lr) << 5) + lq*8;
      const int off1 = ((tap*64 + (mtp+1)*16 + lr) << 5) + lq*8;
      bf16x8 ah0 = *(const bf16x8*)&wBh[off0];
      bf16x8 al0 = *(const bf16x8*)&wBl[off0];
      bf16x8 ah1 = *(const bf16x8*)&wBh[off1];
      bf16x8 al1 = *(const bf16x8*)&wBl[off1];
      const int dy = tap/3, dx = tap - dy*3;
      #pragma unroll
      for (int j = 0; j < 4; ++j) {
        int pl = (rq*4 + j + dy)*18 + lr + dx;
        int slot = pl*5 + lq;                        // padded layout, slot = lq
        bf16x8 bh = *(const bf16x8*)&ishB[0][slot << 3];
        bf16x8 bl = *(const bf16x8*)&ishB[1][slot << 3];
        acc[0][j] = __builtin_amdgcn_mfma_f32_16x16x32_bf16(ah0, bh, acc[0][j], 0, 0, 0);
        acc[1][j] = __builtin_amdgcn_mfma_f32_16x16x32_bf16(ah1, bh, acc[1][j], 0, 0, 0);
        acc[0][j] = __builtin_amdgcn_mfma_f32_16x16x32_bf16(ah0, bl, acc[0][j], 0, 0, 0);
        acc[1][j] = __builtin_amdgcn_mfma_f32_16x16x32_bf16(ah1, bl, acc[1][j], 0, 0, 0);
        acc[0][j] = __builtin_amdgcn_mfma_f32_16x16x32_bf16(al0, bh, acc[0][j], 0, 0, 0);
        acc[1][j] = __builtin_amdgcn_mfma_f32_16x16x32_bf16(al1, bh, acc[1][j], 0, 0, 0);
      }
    }
    __syncthreads();
    float* ps2 = (float*)&ishB[0][0];
    #pragma unroll
    for (int m = 0; m < 2; ++m)
      #pragma unroll
      for (int k = 0; k < 2; ++k)
        #pragma unroll
        for (int r = 0; r < 4; ++r) {
          float v = fmaxf(acc[m][2*k][r], acc[m][2*k+1][r]);
          v = fmaxf(v, __shfl_xor(v, 1, 64));
          if ((lr & 1) == 0) {
            int oc = (mtp + m)*16 + lq*4 + r;
            int Y = rq*2 + k, X = lr >> 1;
            ps2[oc*65 + Y*8 + X] = fmaxf(v + bs2[oc], 0.f);
          }
        }
    __syncthreads();
    float* op = outB + (size_t)img*4096;
    #pragma unroll
    for (int jj = 0; jj < 8; ++jj) {
      int i = jj*512 + t;
      op[i] = ps2[(i >> 6)*65 + (i & 63)];
    }
  }
}

// ================= conv3 v5: bf16x2 split MFMA (3-term); emits C as bf16 hi/lo ==========
__global__ __launch_bounds__(256) void k_conv3(const float* __restrict__ inB,
    const unsigned short* __restrict__ wAh, const unsigned short* __restrict__ wAl,
    const float* __restrict__ bias,
    unsigned short* __restrict__ Chh, unsigned short* __restrict__ Chl) {
  __shared__ unsigned short ish[2][6400];
  const int t = threadIdx.x;
  const int img = blockIdx.x;
  {
    unsigned int* z = (unsigned int*)&ish[0][0];
    #pragma unroll
    for (int j = 0; j < 25; ++j) z[t + 256*j] = 0u;
  }
  __syncthreads();
  {
    const float* src = inB + (size_t)img*4096;
    #pragma unroll
    for (int j = 0; j < 16; ++j) {
      int f = t + 256*j;
      int ic = f >> 6, p = f & 63;
      int pl = ((p >> 3) + 1)*10 + (p & 7) + 1;
      float v = src[f];
      unsigned short h = f2bf(v);
      unsigned short l = f2bf(v - bf2f(h));
      int u = pl*64 + ic;
      int us = (((u >> 3) ^ (pl & 7)) << 3) | (u & 7);
      ish[0][us] = h; ish[1][us] = l;
    }
  }
  __syncthreads();

  const int lane = t & 63, wid = t >> 6;
  const int lr = lane & 15, lq = lane >> 4;
  const int mt0 = wid*2;
  const int yb = lr >> 3, xb = lr & 7;

  f32x4 acc[2][4];
  #pragma unroll
  for (int i = 0; i < 2; ++i)
    #pragma unroll
    for (int j = 0; j < 4; ++j) acc[i][j] = (f32x4){0.f,0.f,0.f,0.f};

  for (int tap = 0; tap < 9; ++tap) {
    const int dy = tap/3, dx = tap - dy*3;
    #pragma unroll
    for (int kc = 0; kc < 2; ++kc) {
      const int kb = kc*32 + lq*8;
      const int wbase = ((tap << 7) << 6) + kb;
      bf16x8 a0h = *(const bf16x8*)&wAh[wbase + ((mt0*16 + lr) << 6)];
      bf16x8 a0l = *(const bf16x8*)&wAl[wbase + ((mt0*16 + lr) << 6)];
      bf16x8 a1h = *(const bf16x8*)&wAh[wbase + (((mt0+1)*16 + lr) << 6)];
      bf16x8 a1l = *(const bf16x8*)&wAl[wbase + (((mt0+1)*16 + lr) << 6)];
      #pragma unroll
      for (int nt = 0; nt < 4; ++nt) {
        const int pl = (2*nt + yb + dy)*10 + xb + dx;
        const int u = pl*64 + kb;
        const int us = (((u >> 3) ^ (pl & 7)) << 3);
        bf16x8 bh = *(const bf16x8*)&ish[0][us];
        bf16x8 bl = *(const bf16x8*)&ish[1][us];
        acc[0][nt] = __builtin_amdgcn_mfma_f32_16x16x32_bf16(a0h, bh, acc[0][nt], 0, 0, 0);
        acc[0][nt] = __builtin_amdgcn_mfma_f32_16x16x32_bf16(a0h, bl, acc[0][nt], 0, 0, 0);
        acc[0][nt] = __builtin_amdgcn_mfma_f32_16x16x32_bf16(a0l, bh, acc[0][nt], 0, 0, 0);
        acc[1][nt] = __builtin_amdgcn_mfma_f32_16x16x32_bf16(a1h, bh, acc[1][nt], 0, 0, 0);
        acc[1][nt] = __builtin_amdgcn_mfma_f32_16x16x32_bf16(a1h, bl, acc[1][nt], 0, 0, 0);
        acc[1][nt] = __builtin_amdgcn_mfma_f32_16x16x32_bf16(a1l, bh, acc[1][nt], 0, 0, 0);
      }
    }
  }
  __syncthreads();
  float* stg = (float*)&ish[0][0];   // [128 oc][17]
  #pragma unroll
  for (int mtl = 0; mtl < 2; ++mtl)
    #pragma unroll
    for (int nt = 0; nt < 4; ++nt)
      #pragma unroll
      for (int r = 0; r < 4; ++r) {
        float v = acc[mtl][nt][r];
        v = fmaxf(v, __shfl_xor(v, 1, 64));
        v = fmaxf(v, __shfl_xor(v, 8, 64));
        if ((lane & 9) == 0) {
          int oc = (mt0 + mtl)*16 + lq*4 + r;
          int pix = nt*4 + (xb >> 1);
          stg[oc*17 + pix] = fmaxf(v + bias[oc], 0.f);
        }
      }
  __syncthreads();
  #pragma unroll
  for (int j = 0; j < 8; ++j) {
    int i = t + 256*j;
    float v = stg[(i >> 4)*17 + (i & 15)];
    unsigned short h = f2bf(v);
    Chh[(size_t)img*2048 + i] = h;
    Chl[(size_t)img*2048 + i] = f2bf(v - bf2f(h));
  }
}

// ================= FC GEMM v2: bf16x2 3-term MFMA, no LDS, split-K=4 =================
__global__ __launch_bounds__(256) void k_fc(const unsigned short* __restrict__ Chh,
    const unsigned short* __restrict__ Chl,
    const unsigned short* __restrict__ wfh, const unsigned short* __restrict__ wfl,
    float* __restrict__ P0, float* __restrict__ P1,
    float* __restrict__ P2, float* __restrict__ P3) {
  const int t = threadIdx.x;
  const int r0 = blockIdx.x * 32;
  const int kq = blockIdx.z;
  float* __restrict__ P = (kq == 0) ? P0 : (kq == 1) ? P1 : (kq == 2) ? P2 : P3;
  const int lane = t & 63, wv = t >> 6;
  const int lr = lane & 15, lq = lane >> 4;
  f32x4 acc[2][4];
  #pragma unroll
  for (int i = 0; i < 2; ++i)
    #pragma unroll
    for (int j = 0; j < 4; ++j) acc[i][j] = (f32x4){0.f,0.f,0.f,0.f};
  #pragma unroll 4
  for (int ks = 0; ks < 16; ++ks) {
    bf16x8 ah[2], al[2];
    #pragma unroll
    for (int rt = 0; rt < 2; ++rt) {
      size_t ao = (size_t)(r0 + rt*16 + lr)*2048 + kq*512 + ks*32 + lq*8;
      ah[rt] = *(const bf16x8*)&Chh[ao];
      al[rt] = *(const bf16x8*)&Chl[ao];
    }
    #pragma unroll
    for (int nt = 0; nt < 4; ++nt) {
      size_t bo = ((size_t)((wv*4 + nt)*64 + kq*16 + ks)*64 + lane)*8;
      bf16x8 bh = *(const bf16x8*)&wfh[bo];
      bf16x8 bl = *(const bf16x8*)&wfl[bo];
      acc[0][nt] = __builtin_amdgcn_mfma_f32_16x16x32_bf16(ah[0], bh, acc[0][nt], 0, 0, 0);
      acc[1][nt] = __builtin_amdgcn_mfma_f32_16x16x32_bf16(ah[1], bh, acc[1][nt], 0, 0, 0);
      acc[0][nt] = __builtin_amdgcn_mfma_f32_16x16x32_bf16(ah[0], bl, acc[0][nt], 0, 0, 0);
      acc[1][nt] = __builtin_amdgcn_mfma_f32_16x16x32_bf16(ah[1], bl, acc[1][nt], 0, 0, 0);
      acc[0][nt] = __builtin_amdgcn_mfma_f32_16x16x32_bf16(al[0], bh, acc[0][nt], 0, 0, 0);
      acc[1][nt] = __builtin_amdgcn_mfma_f32_16x16x32_bf16(al[1], bh, acc[1][nt], 0, 0, 0);
    }
  }
  #pragma unroll
  for (int rt = 0; rt < 2; ++rt)
    #pragma unroll
    for (int nt = 0; nt < 4; ++nt)
      #pragma unroll
      for (int r = 0; r < 4; ++r)
        P[(size_t)(r0 + rt*16 + lq*4 + r)*256 + (wv*4 + nt)*16 + lr] = acc[rt][nt][r];
}

// ================= gate: feat = P0+P1+P2+P3+fcb; logits; top-2 softmax; expert lists
__global__ __launch_bounds__(256) void k_gate(const float* __restrict__ P0,
    const float* __restrict__ P1, const float* __restrict__ P2, const float* __restrict__ P3,
    const float* __restrict__ fcb,
    const float* __restrict__ gw, const float* __restrict__ gb,
    float* __restrict__ feat, int* __restrict__ cnt, float* __restrict__ gsum,
    int* __restrict__ lrow, float* __restrict__ lg) {
  __shared__ float ft[16][256];
  __shared__ float lgs[16][16];
  __shared__ float gwl[4096];
  const int t = threadIdx.x;
  const int r0 = blockIdx.x * 16;
  for (int i = t; i < 4096; i += 256) gwl[i] = gw[i];
  float bb = fcb[t];
  #pragma unroll
  for (int r = 0; r < 16; ++r) {
    size_t off = (size_t)(r0+r)*256 + t;
    float v = P0[off] + P1[off] + P2[off] + P3[off] + bb;
    ft[r][t] = v;
    feat[off] = v;
  }
  __syncthreads();
  {
    int r = t >> 4, e = t & 15;
    float s = gb[e];
    for (int k = 0; k < 256; ++k) s = fmaf(ft[r][k], gwl[k*16 + e], s);
    lgs[r][e] = s;
  }
  __syncthreads();
  if (t < 16) {
    int r = t;
    float v1 = -3.402823e38f, v2 = -3.402823e38f;
    int i1 = 0, i2 = 0;
    for (int e = 0; e < 16; ++e) {
      float v = lgs[r][e];
      if (v > v1)      { v2 = v1; i2 = i1; v1 = v; i1 = e; }
      else if (v > v2) { v2 = v;  i2 = e; }
    }
    float ex = __expf(v2 - v1);
    float g1 = 1.f / (1.f + ex);
    float g2 = ex  / (1.f + ex);
    int row = r0 + r;
    int p1 = atomicAdd(&cnt[i1], 1); lrow[i1*4096 + p1] = row; lg[i1*4096 + p1] = g1;
    int p2 = atomicAdd(&cnt[i2], 1); lrow[i2*4096 + p2] = row; lg[i2*4096 + p2] = g2;
    atomicAdd(&gsum[i1], g1);
    atomicAdd(&gsum[i2], g2);
  }
}

// ================= MoE v5: R25 = v4 + software-pipelined weight prefetch ==============
// R24 PMC: MfmaUtil 5%, VALUBusy 9.6%, Occ 17.6%, VGPR 68 -> latency-bound, zero loads
// in flight. Prefetch next iteration's 8 weight loads (32 VGPR dbuf) before MFMAs;
// per-acc MFMA term/ks order unchanged -> bit-exact with v4.
__global__ __launch_bounds__(256) void k_moe(const float* __restrict__ feat,
    const unsigned short* __restrict__ w1th, const unsigned short* __restrict__ w1tl,
    const unsigned short* __restrict__ w2th, const unsigned short* __restrict__ w2tl,
    const float* __restrict__ eb1, const float* __restrict__ eb2,
    const int* __restrict__ cnt, const int* __restrict__ lrow, const float* __restrict__ lgw,
    float* __restrict__ moe) {
  const int e = blockIdx.y;
  const int n_e = cnt[e];
  const int start = blockIdx.x * 32;
  if (start >= n_e) return;
  const int c = blockIdx.z;
  const int n = min(32, n_e - start);
  __shared__ unsigned short fh[8192], fl[8192];
  __shared__ unsigned short h1h[4096], h1l[4096];
  __shared__ int   rws[32];
  __shared__ float gws[32];
  const int t = threadIdx.x;
  if (t < 32) {
    rws[t] = (t < n) ? lrow[e*4096 + start + t] : 0;
    gws[t] = (t < n) ? lgw[e*4096 + start + t] : 0.f;
  }
  __syncthreads();
  for (int j = 0; j < 32; ++j) {
    float v = (j < n) ? feat[(size_t)rws[j]*256 + t] : 0.f;
    unsigned short h = f2bf(v);
    int us = (j*32 + ((t >> 3) ^ (j & 7)))*8 + (t & 7);
    fh[us] = h; fl[us] = f2bf(v - bf2f(h));
  }
  const int lane = t & 63, wv = t >> 6;
  const int lr = lane & 15, lq = lane >> 4;
  const int rh = wv & 1, qh = wv >> 1;
  const int arow = rh*16 + lr;
  const int rsw = arow & 7;
  const size_t ewb = (size_t)e << 18;

  f32x4 acc2[8];
  #pragma unroll
  for (int i = 0; i < 8; ++i) acc2[i] = (f32x4){0.f,0.f,0.f,0.f};

  __syncthreads();

  {
    // -------- GEMM1: K=256 (8 ks), 4 htiles/wave; prefetch ks+1 weights --------
    f32x4 acc1[4];
    #pragma unroll
    for (int i = 0; i < 4; ++i) acc1[i] = (f32x4){0.f,0.f,0.f,0.f};
    bf16x8 wbh[4], wbl[4];
    #pragma unroll
    for (int ht = 0; ht < 4; ++ht) {
      size_t bo = ewb + ((size_t)((c*8 + qh*4 + ht)*8 + 0)*64 + lane)*8;
      wbh[ht] = *(const bf16x8*)&w1th[bo];
      wbl[ht] = *(const bf16x8*)&w1tl[bo];
    }
    #pragma unroll
    for (int ks = 0; ks < 8; ++ks) {
      bf16x8 nbh[4], nbl[4];
      if (ks < 7) {
        #pragma unroll
        for (int ht = 0; ht < 4; ++ht) {
          size_t bo = ewb + ((size_t)((c*8 + qh*4 + ht)*8 + ks + 1)*64 + lane)*8;
          nbh[ht] = *(const bf16x8*)&w1th[bo];
          nbl[ht] = *(const bf16x8*)&w1tl[bo];
        }
      }
      int aoff = (arow*32 + ((ks*4 + lq) ^ rsw))*8;
      bf16x8 ah = *(const bf16x8*)&fh[aoff];
      bf16x8 al = *(const bf16x8*)&fl[aoff];
      #pragma unroll
      for (int ht = 0; ht < 4; ++ht) {
        acc1[ht] = __builtin_amdgcn_mfma_f32_16x16x32_bf16(ah, wbh[ht], acc1[ht], 0, 0, 0);
        acc1[ht] = __builtin_amdgcn_mfma_f32_16x16x32_bf16(ah, wbl[ht], acc1[ht], 0, 0, 0);
        acc1[ht] = __builtin_amdgcn_mfma_f32_16x16x32_bf16(al, wbh[ht], acc1[ht], 0, 0, 0);
      }
      if (ks < 7) {
        #pragma unroll
        for (int ht = 0; ht < 4; ++ht) { wbh[ht] = nbh[ht]; wbl[ht] = nbl[ht]; }
      }
    }
    __syncthreads();
    #pragma unroll
    for (int ht = 0; ht < 4; ++ht) {
      int hloc = qh*64 + ht*16 + lr;
      float bb = eb1[e*1024 + c*128 + hloc];
      #pragma unroll
      for (int r = 0; r < 4; ++r) {
        int orow = rh*16 + lq*4 + r;
        float v = fmaxf(acc1[ht][r] + bb, 0.f);
        unsigned short hh = f2bf(v);
        int us = (orow*16 + ((hloc >> 3) ^ (orow & 7)))*8 + (hloc & 7);
        h1h[us] = hh; h1l[us] = f2bf(v - bf2f(hh));
      }
    }
    __syncthreads();
    // -------- GEMM2: K=128 local (4 ks), 8 dtiles/wave; prefetch per half-dt group ----
    // groups g: ks = g>>1, dth = (g&1)*4. Per-acc ks order 0..3 ascending = v4 order.
    bf16x8 w2h[4], w2l[4];
    #pragma unroll
    for (int dt = 0; dt < 4; ++dt) {
      size_t bo = ewb + ((size_t)((qh*8 + dt)*32 + c*4 + 0)*64 + lane)*8;
      w2h[dt] = *(const bf16x8*)&w2th[bo];
      w2l[dt] = *(const bf16x8*)&w2tl[bo];
    }
    #pragma unroll
    for (int g = 0; g < 8; ++g) {
      const int ks = g >> 1, dth = (g & 1)*4;
      bf16x8 nh[4], nl[4];
      if (g < 7) {
        const int ks2 = (g+1) >> 1, dth2 = ((g+1) & 1)*4;
        #pragma unroll
        for (int dt = 0; dt < 4; ++dt) {
          size_t bo = ewb + ((size_t)((qh*8 + dth2 + dt)*32 + c*4 + ks2)*64 + lane)*8;
          nh[dt] = *(const bf16x8*)&w2th[bo];
          nl[dt] = *(const bf16x8*)&w2tl[bo];
        }
      }
      int aoff = (arow*16 + ((ks*4 + lq) ^ rsw))*8;
      bf16x8 ah = *(const bf16x8*)&h1h[aoff];
      bf16x8 al = *(const bf16x8*)&h1l[aoff];
      #pragma unroll
      for (int dt = 0; dt < 4; ++dt) {
        acc2[dth+dt] = __builtin_amdgcn_mfma_f32_16x16x32_bf16(ah, w2h[dt], acc2[dth+dt], 0, 0, 0);
        acc2[dth+dt] = __builtin_amdgcn_mfma_f32_16x16x32_bf16(ah, w2l[dt], acc2[dth+dt], 0, 0, 0);
        acc2[dth+dt] = __builtin_amdgcn_mfma_f32_16x16x32_bf16(al, w2h[dt], acc2[dth+dt], 0, 0, 0);
      }
      if (g < 7) {
        #pragma unroll
        for (int dt = 0; dt < 4; ++dt) { w2h[dt] = nh[dt]; w2l[dt] = nl[dt]; }
      }
    }
  }
  #pragma unroll
  for (int dt = 0; dt < 8; ++dt) {
    int d = qh*128 + dt*16 + lr;
    float b2 = (c == 0) ? eb2[e*256 + d] : 0.f;
    #pragma unroll
    for (int r = 0; r < 4; ++r) {
      int orow = rh*16 + lq*4 + r;
      if (orow < n)
        atomicAdd(&moe[(size_t)rws[orow]*256 + d], gws[orow]*(acc2[dt][r] + b2));
    }
  }
}

// ================= LayerNorm(moe + feat) -> y bf16 hi/lo; block 4096 computes lb_loss ======
__global__ __launch_bounds__(256) void k_ln(const float* __restrict__ feat,
    const float* __restrict__ moe, const float* __restrict__ g, const float* __restrict__ bp,
    unsigned short* __restrict__ yh, unsigned short* __restrict__ yl,
    const float* __restrict__ gsum, float* __restrict__ out_lb) {
  const int r = blockIdx.x, t = threadIdx.x;
  if (r == NB) {            // lb block: wave 0 only, no barriers on this path
    if (t < 64) {
      float term = 0.f;
      if (t < 16) {
        float D = gsum[t] * (1.f/4096.f);
        term = D * logf(D + 1e-8f);
      }
      #pragma unroll
      for (int o = 8; o > 0; o >>= 1) term += __shfl_down(term, o, 64);
      if (t == 0) *out_lb = term;
    }
    return;
  }
  float v = moe[(size_t)r*256 + t] + feat[(size_t)r*256 + t];
  float s = v, q = v * v;
  #pragma unroll
  for (int o = 32; o > 0; o >>= 1) {
    s += __shfl_down(s, o, 64);
    q += __shfl_down(q, o, 64);
  }
  __shared__ float ss[4], qq[4];
  int wv = t >> 6;
  if ((t & 63) == 0) { ss[wv] = s; qq[wv] = q; }
  __syncthreads();
  float S = ss[0]+ss[1]+ss[2]+ss[3];
  float Q = qq[0]+qq[1]+qq[2]+qq[3];
  float mu  = S * (1.f/256.f);
  float var = Q * (1.f/256.f) - mu*mu;
  float inv = rsqrtf(var + 1e-5f);
  float y = (v - mu) * inv * g[t] + bp[t];
  unsigned short h = f2bf(y);
  yh[(size_t)r*256 + t] = h;
  yl[(size_t)r*256 + t] = f2bf(y - bf2f(h));
}

// ================= output GEMM v2: bf16x2 3-term MFMA, no LDS =================
__global__ __launch_bounds__(256) void k_out(const unsigned short* __restrict__ yh,
    const unsigned short* __restrict__ yl,
    const unsigned short* __restrict__ owh, const unsigned short* __restrict__ owl,
    const float* __restrict__ ob, float* __restrict__ out) {
  const int t = threadIdx.x;
  const int r0 = blockIdx.x * 32;
  const int lane = t & 63, wv = t >> 6;
  const int lr = lane & 15, lq = lane >> 4;
  const int ntile = blockIdx.y*4 + wv;
  f32x4 acc[2];
  acc[0] = (f32x4){0.f,0.f,0.f,0.f};
  acc[1] = (f32x4){0.f,0.f,0.f,0.f};
  #pragma unroll
  for (int ks = 0; ks < 8; ++ks) {
    bf16x8 bh = *(const bf16x8*)&owh[((size_t)(ntile*8 + ks)*64 + lane)*8];
    bf16x8 bl = *(const bf16x8*)&owl[((size_t)(ntile*8 + ks)*64 + lane)*8];
    #pragma unroll
    for (int rt = 0; rt < 2; ++rt) {
      size_t ao = (size_t)(r0 + rt*16 + lr)*256 + ks*32 + lq*8;
      bf16x8 ah = *(const bf16x8*)&yh[ao];
      bf16x8 al = *(const bf16x8*)&yl[ao];
      acc[rt] = __builtin_amdgcn_mfma_f32_16x16x32_bf16(ah, bh, acc[rt], 0, 0, 0);
      acc[rt] = __builtin_amdgcn_mfma_f32_16x16x32_bf16(ah, bl, acc[rt], 0, 0, 0);
      acc[rt] = __builtin_amdgcn_mfma_f32_16x16x32_bf16(al, bh, acc[rt], 0, 0, 0);
    }
  }
  const int col = ntile*16 + lr;
  if (col < NCLS) {
    float bb = ob[col];
    #pragma unroll
    for (int rt = 0; rt < 2; ++rt)
      #pragma unroll
      for (int r = 0; r < 4; ++r)
        out[(size_t)(r0 + rt*16 + lq*4 + r)*NCLS + col] = acc[rt][r] + bb;
  }
}

// ================= launch =================
extern "C" void kernel_launch(void* const* d_in, const int* in_sizes, int n_in,
                              void* d_out, int out_size, void* d_ws, size_t ws_size,
                              hipStream_t stream) {
  const float* x   = (const float*)d_in[0];
  const float* c1w = (const float*)d_in[1];
  const float* c1b = (const float*)d_in[2];
  const float* c2w = (const float*)d_in[3];
  const float* c2b = (const float*)d_in[4];
  const float* c3w = (const float*)d_in[5];
  const float* c3b = (const float*)d_in[6];
  const float* fcw = (const float*)d_in[7];
  const float* fcb = (const float*)d_in[8];
  const float* gw  = (const float*)d_in[9];
  const float* gb  = (const float*)d_in[10];
  const float* ew1 = (const float*)d_in[11];
  const float* eb1 = (const float*)d_in[12];
  const float* ew2 = (const float*)d_in[13];
  const float* eb2 = (const float*)d_in[14];
  const float* lng = (const float*)d_in[15];
  const float* lnb = (const float*)d_in[16];
  const float* ow  = (const float*)d_in[17];
  const float* ob  = (const float*)d_in[18];
  char* ws = (char*)d_ws;
  float* Bb   = (float*)(ws + OFF_B);
  float* P0   = (float*)(ws + OFF_P0);
  float* P1   = (float*)(ws + OFF_P1);
  float* P2   = (float*)(ws + OFF_P2);
  float* P3   = (float*)(ws + OFF_P3);
  unsigned short* Chh = (unsigned short*)(ws + OFF_CHH);
  unsigned short* Chl = (unsigned short*)(ws + OFF_CHL);
  unsigned short* wBh = (unsigned short*)(ws + OFF_CHH);   // aliases Chh (written after conv12)
  unsigned short* wBl = (unsigned short*)(ws + OFF_WBL);
  unsigned short* wA1h = (unsigned short*)(ws + OFF_WA1H);
  unsigned short* wA1l = (unsigned short*)(ws + OFF_WA1L);
  unsigned short* wAh = (unsigned short*)(ws + OFF_FEAT);  // aliases feat (written later)
  unsigned short* wAl = (unsigned short*)(ws + OFF_WAL);
  unsigned short* w1th = (unsigned short*)(ws + OFF_W1TH);
  unsigned short* w1tl = (unsigned short*)(ws + OFF_W1TL);
  unsigned short* w2th = (unsigned short*)(ws + OFF_W2TH);
  unsigned short* w2tl = (unsigned short*)(ws + OFF_W2TL);
  unsigned short* wfh = (unsigned short*)(ws + OFF_WFCH);
  unsigned short* wfl = (unsigned short*)(ws + OFF_WFCL);
  unsigned short* owph = (unsigned short*)(ws + OFF_OWH);
  unsigned short* owpl = (unsigned short*)(ws + OFF_OWL);
  unsigned short* yh = (unsigned short*)(ws + OFF_P0);     // aliases P0 (dead after gate)
  unsigned short* yl = (unsigned short*)(ws + OFF_P1);     // aliases P1
  float* feat = (float*)(ws + OFF_FEAT);
  float* moe  = (float*)(ws + OFF_MOE);
  int*   cnt  = (int*)(ws + OFF_CNT);
  float* gsum = (float*)(ws + OFF_GSUM);
  int*   lrow = (int*)(ws + OFF_LROW);
  float* lgv  = (float*)(ws + OFF_LG);
  float* outp = (float*)d_out;

  hipMemsetAsync(ws + OFF_MOE, 0, 4194304 + 128, stream);

  hipLaunchKernelGGL(k_wprep,  dim3(364),     dim3(256), 0, stream,
                     c1w, wA1h, wA1l, c2w, wBh, wBl, c3w, wAh, wAl);
  hipLaunchKernelGGL(k_conv12, dim3(4096),    dim3(512), 0, stream, x, wA1h, wA1l, c1b, wBh, wBl, c2b, Bb);
  hipLaunchKernelGGL(k_conv3,  dim3(4096),    dim3(256), 0, stream, Bb, wAh, wAl, c3b, Chh, Chl);
  // Bb dead now -> build ALL packed weights that live in its region (one kernel)
  hipLaunchKernelGGL(k_packall, dim3(3200),   dim3(256), 0, stream,
                     ew1, w1th, w1tl, ew2, w2th, w2tl, fcw, wfh, wfl, ow, owph, owpl);
  hipLaunchKernelGGL(k_fc,     dim3(128, 1, 4), dim3(256), 0, stream, Chh, Chl, wfh, wfl, P0, P1, P2, P3);
  hipLaunchKernelGGL(k_gate,   dim3(256),     dim3(256), 0, stream, P0, P1, P2, P3, fcb, gw, gb,
                     feat, cnt, gsum, lrow, lgv);
  hipLaunchKernelGGL(k_moe,    dim3(128, 16, 8), dim3(256), 0, stream, feat, w1th, w1tl, w2th, w2tl,
                     eb1, eb2, cnt, lrow, lgv, moe);
  hipLaunchKernelGGL(k_ln,     dim3(4097),    dim3(256), 0, stream, feat, moe, lng, lnb, yh, yl,
                     gsum, outp + (size_t)NB*NCLS);
  hipLaunchKernelGGL(k_out,    dim3(128, 16), dim3(256), 0, stream, yh, yl, owph, owpl, ob, outp);
}

// Round 26
// 744.151 us; speedup vs baseline: 1.0936x; 1.0068x over previous
//
#include <hip/hip_runtime.h>
#include <hip/hip_bf16.h>

typedef short bf16x8 __attribute__((ext_vector_type(8)));
typedef float f32x4 __attribute__((ext_vector_type(4)));

// ---------------- problem sizes ----------------
#define NB   4096
#define NEXP 16
#define DDIM 256
#define HDIM 1024
#define NCLS 1000

// ---------------- workspace layout (bytes) ----------------
// NOTE: Bb (conv2 out, 67 MB at offset 0) is live from conv12 until conv3 completes.
// ALL packed-weight regions below OFF_CHH alias Bb -> their pack kernels MUST run after conv3.
#define OFF_B    ((size_t)0)
#define OFF_P0   ((size_t)0)           // f32 [4096][256] FC partial (kq 0); ALSO yh after gate
#define OFF_P1   ((size_t)4194304)     // f32 [4096][256] FC partial (kq 1); ALSO yl after gate
#define OFF_W1TH ((size_t)8388608)     // bf16 packed [16][64 ht][8 ks][64 lane][8]  8 MB
#define OFF_W1TL ((size_t)16777216)
#define OFF_W2TH ((size_t)25165824)    // bf16 packed [16][16 dt][32 ks][64 lane][8] 8 MB
#define OFF_W2TL ((size_t)33554432)
#define OFF_WFCH ((size_t)41943040)    // fcw packed hi (1 MB)
#define OFF_WFCL ((size_t)42991616)    // fcw packed lo (1 MB)
#define OFF_P2   ((size_t)44040192)    // f32 [4096][256] FC partial (kq 2)
#define OFF_P3   ((size_t)48234496)    // f32 [4096][256] FC partial (kq 3)
#define OFF_OWH  ((size_t)52428800)    // ow packed hi [64 nt][8 ks][64][8] (512 KB)
#define OFF_OWL  ((size_t)53477376)
#define OFF_CHH  ((size_t)67108864)    // conv3 out hi bf16 [4096][2048]; ALSO wBh/wBl/wA1 before conv12
#define OFF_CHL  ((size_t)83886080)    // conv3 out lo bf16
#define OFF_WBL  ((size_t)67145728)
#define OFF_WA1H ((size_t)67182592)
#define OFF_WA1L ((size_t)67184640)
#define OFF_FEAT ((size_t)100663296)   // f32 [4096][256]; ALSO wAh/wAl (288 KB) before k_gate
#define OFF_WAL  ((size_t)100810752)
#define OFF_MOE  ((size_t)104857600)   // f32 [4096][256]
#define OFF_CNT  ((size_t)109051904)   // int [16]
#define OFF_GSUM ((size_t)109051968)   // f32 [16]
#define OFF_LROW ((size_t)109052032)   // int [16][4096]
#define OFF_LG   ((size_t)109314176)   // f32 [16][4096]

__device__ inline unsigned short f2bf(float v) {
  __hip_bfloat16 h = __float2bfloat16(v);
  return *(unsigned short*)&h;
}
__device__ inline float bf2f(unsigned short u) {
  union { unsigned int i; float f; } c; c.i = ((unsigned int)u) << 16; return c.f;
}

// ====== merged weight prep: conv1(1024) + conv2(18432) + conv3(73728) elems, range-split
__global__ __launch_bounds__(256) void k_wprep(
    const float* __restrict__ c1w, unsigned short* __restrict__ a1h, unsigned short* __restrict__ a1l,
    const float* __restrict__ c2w, unsigned short* __restrict__ b2h, unsigned short* __restrict__ b2l,
    const float* __restrict__ c3w, unsigned short* __restrict__ a3h, unsigned short* __restrict__ a3l) {
  int i = blockIdx.x*256 + threadIdx.x;   // over 93184
  if (i < 1024) {
    int k = i & 31, oc = i >> 5;
    float v = (k < 27) ? c1w[oc*27 + k] : 0.f;
    unsigned short h = f2bf(v);
    a1h[i] = h; a1l[i] = f2bf(v - bf2f(h));
  } else if (i < 19456) {
    int j = i - 1024;
    int ic = j & 31, rem = j >> 5;
    int oc = rem & 63, tap = rem >> 6;
    float v = c2w[(oc*32 + ic)*9 + tap];
    unsigned short h = f2bf(v);
    b2h[j] = h; b2l[j] = f2bf(v - bf2f(h));
  } else if (i < 93184) {
    int j = i - 19456;
    int ic = j & 63, rem = j >> 6;
    int oc = rem & 127, tap = rem >> 7;
    float v = c3w[(oc*64 + ic)*9 + tap];
    unsigned short h = f2bf(v);
    a3h[j] = h; a3l[j] = f2bf(v - bf2f(h));
  }
}

// ====== generic pack body (verbatim from k_pack): in[e][R][C] -> packed hi/lo
__device__ inline void pack_body(const float* __restrict__ in,
    unsigned short* __restrict__ oh, unsigned short* __restrict__ ol,
    int R, int C, int bx, int by, int e, int t, float (*tile)[65]) {
  const size_t eb = (size_t)e * R * C;
  const int c0 = bx*64, r0 = by*64;
  const int cc = t & 63, r4 = t >> 6;
  #pragma unroll
  for (int j = 0; j < 16; ++j) {
    int rr = r4 + j*4;
    tile[rr][cc] = in[eb + (size_t)(r0+rr)*C + c0 + cc];
  }
  __syncthreads();
  const int K32 = R >> 5;
  #pragma unroll
  for (int j = 0; j < 16; ++j) {
    int idx = t + j*256;
    int jin = idx & 7, lane = (idx >> 3) & 63, ksl = (idx >> 9) & 1, ntl = idx >> 10;
    int kl = ksl*32 + ((lane >> 4) << 3) + jin;
    int nl = ntl*16 + (lane & 15);
    float v = tile[kl][nl];
    unsigned short h = f2bf(v);
    size_t o = eb + ((size_t)(((c0 >> 4) + ntl)*K32 + (r0 >> 5) + ksl)*64 + lane)*8 + jin;
    oh[o] = h;
    ol[o] = f2bf(v - bf2f(h));
  }
}

// ====== merged packs: ew1(1024 blk) + ew2(1024) + fcw(128) + ow(1024) = 3200 blocks
__global__ __launch_bounds__(256) void k_packall(
    const float* __restrict__ ew1, unsigned short* __restrict__ w1th, unsigned short* __restrict__ w1tl,
    const float* __restrict__ ew2, unsigned short* __restrict__ w2th, unsigned short* __restrict__ w2tl,
    const float* __restrict__ fcw, unsigned short* __restrict__ wfh,  unsigned short* __restrict__ wfl,
    const float* __restrict__ ow,  unsigned short* __restrict__ owh,  unsigned short* __restrict__ owl) {
  __shared__ float tile[64][65];
  const int b = blockIdx.x;
  const int t = threadIdx.x;
  if (b < 1024) {                       // ew1: R=256, C=1024, grid (16,4,16)
    int bx = b & 15, by = (b >> 4) & 3, e = b >> 6;
    pack_body(ew1, w1th, w1tl, 256, 1024, bx, by, e, t, tile);
  } else if (b < 2048) {                // ew2: R=1024, C=256, grid (4,16,16)
    int lb = b - 1024;
    int bx = lb & 3, by = (lb >> 2) & 15, e = lb >> 6;
    pack_body(ew2, w2th, w2tl, 1024, 256, bx, by, e, t, tile);
  } else if (b < 2176) {                // fcw: R=2048, C=256, grid (4,32,1)
    int lb = b - 2048;
    int bx = lb & 3, by = lb >> 2;
    pack_body(fcw, wfh, wfl, 2048, 256, bx, by, 0, t, tile);
  } else {                              // ow pack (elementwise, 1024 blocks)
    int lb = b - 2176;
    int i = lb*256 + t;                 // over 262144
    int j = i & 7, lane = (i >> 3) & 63, ks = (i >> 9) & 7, nt = i >> 12;
    int k = ks*32 + ((lane >> 4) << 3) + j;
    int n = nt*16 + (lane & 15);
    float v = (n < NCLS) ? ow[(size_t)k*NCLS + n] : 0.f;
    unsigned short h = f2bf(v);
    owh[i] = h;
    owl[i] = f2bf(v - bf2f(h));
  }
}

// ============ fused conv1(reg-im2col bf16x2 MFMA) + conv2(bf16x2 MFMA, 3-term) per image ====
// R24: ishB pl-stride padded 4->5 slots. R26: zero-init only the 68 border pls of the
// 18x18 halo (conv1 writes the full interior before the barrier) -> 2720 u32 vs 12960.
__global__ __launch_bounds__(512, 4) void k_conv12(const float* __restrict__ x,
    const unsigned short* __restrict__ wA1h, const unsigned short* __restrict__ wA1l,
    const float* __restrict__ b1,
    const unsigned short* __restrict__ wBh, const unsigned short* __restrict__ wBl,
    const float* __restrict__ b2, float* __restrict__ outB) {
  __shared__ unsigned int xsu[3*34*36];     // packed bf16 hi/lo image (14.7 KB)
  __shared__ __align__(16) unsigned short ishB[2][12960]; // [pl][5 slots][8] padded (51.8 KB); reused for store
  __shared__ float bs1[32];
  __shared__ float bs2[64];
  const int t = threadIdx.x;
  const int img = blockIdx.x;
  for (int i = t; i < 3*34*36; i += 512) xsu[i] = 0u;
  {
    // border-only zero: pls with y==0, y==17, x==0 or x==17; 20 u32 per pl per plane
    unsigned int* z = (unsigned int*)&ishB[0][0];
    for (int i = t; i < 2720; i += 512) {
      int plane = i / 1360, rem = i - plane*1360;
      int b = rem / 20, o = rem - b*20;
      int pl;
      if (b < 18)      pl = b;                    // y = 0
      else if (b < 36) pl = 306 + (b - 18);       // y = 17
      else if (b < 52) pl = (b - 35) * 18;        // x = 0,  y = 1..16
      else             pl = (b - 51) * 18 + 17;   // x = 17, y = 1..16
      z[plane*6480 + pl*20 + o] = 0u;
    }
  }
  __syncthreads();
  for (int i = t; i < 3072; i += 512) {
    int ic = i >> 10, rem = i & 1023, y = rem >> 5, xx = rem & 31;
    float v = x[(size_t)img*3072 + i];
    unsigned short h = f2bf(v);
    unsigned short l = f2bf(v - bf2f(h));
    xsu[ic*34*36 + (y+1)*36 + (xx+1)] = ((unsigned int)l << 16) | (unsigned int)h;
  }
  if (t < 32) bs1[t] = b1[t];
  else if (t >= 64 && t < 128) bs2[t-64] = b2[t-64];

  const int lane = t & 63, wvv = t >> 6;
  const int lr = lane & 15, lq = lane >> 4;

  const int oct1 = wvv & 1;
  const bf16x8 a1h = *(const bf16x8*)&wA1h[((oct1*16 + lr) << 5) + lq*8];
  const bf16x8 a1l = *(const bf16x8*)&wA1l[((oct1*16 + lr) << 5) + lq*8];

  int koff[8];
  #pragma unroll
  for (int j = 0; j < 8; ++j) {
    int k = lq*8 + j;
    if (k < 27) {
      int ic = k/9, tap = k - ic*9, dy = tap/3, dx = tap - dy*3;
      koff[j] = ic*34*36 + dy*36 + dx;
    } else koff[j] = -1;
  }
  __syncthreads();

  // ---- conv1 via MFMA, barrier-free: 8 passes of 4 pre-pool rows ----
  {
    const int rp  = wvv >> 1;
    const int ly0 = (rp >> 1) << 1;      // 0 or 2
    const int xh  = rp & 1;
    const int X   = xh*16 + lr;
    for (int ps = 0; ps < 8; ++ps) {
      const int baseA = (ps*4 + ly0)*36 + X;
      f32x4 aA = (f32x4){0.f,0.f,0.f,0.f}, aB = (f32x4){0.f,0.f,0.f,0.f};
      {
        union { unsigned int u[4]; bf16x8 v; } bh_, bl_;
        #pragma unroll
        for (int jj = 0; jj < 4; ++jj) {
          unsigned int e0 = (koff[2*jj]   >= 0) ? xsu[koff[2*jj]   + baseA] : 0u;
          unsigned int e1 = (koff[2*jj+1] >= 0) ? xsu[koff[2*jj+1] + baseA] : 0u;
          bh_.u[jj] = __builtin_amdgcn_perm(e1, e0, 0x05040100u);
          bl_.u[jj] = __builtin_amdgcn_perm(e1, e0, 0x07060302u);
        }
        aA = __builtin_amdgcn_mfma_f32_16x16x32_bf16(a1h, bh_.v, aA, 0, 0, 0);
        aA = __builtin_amdgcn_mfma_f32_16x16x32_bf16(a1h, bl_.v, aA, 0, 0, 0);
        aA = __builtin_amdgcn_mfma_f32_16x16x32_bf16(a1l, bh_.v, aA, 0, 0, 0);
      }
      {
        union { unsigned int u[4]; bf16x8 v; } bh_, bl_;
        #pragma unroll
        for (int jj = 0; jj < 4; ++jj) {
          unsigned int e0 = (koff[2*jj]   >= 0) ? xsu[koff[2*jj]   + baseA + 36] : 0u;
          unsigned int e1 = (koff[2*jj+1] >= 0) ? xsu[koff[2*jj+1] + baseA + 36] : 0u;
          bh_.u[jj] = __builtin_amdgcn_perm(e1, e0, 0x05040100u);
          bl_.u[jj] = __builtin_amdgcn_perm(e1, e0, 0x07060302u);
        }
        aB = __builtin_amdgcn_mfma_f32_16x16x32_bf16(a1h, bh_.v, aB, 0, 0, 0);
        aB = __builtin_amdgcn_mfma_f32_16x16x32_bf16(a1h, bl_.v, aB, 0, 0, 0);
        aB = __builtin_amdgcn_mfma_f32_16x16x32_bf16(a1l, bh_.v, aB, 0, 0, 0);
      }
      #pragma unroll
      for (int r = 0; r < 4; ++r) {
        float v = fmaxf(aA[r], aB[r]);
        v = fmaxf(v, __shfl_xor(v, 1, 64));
        if ((lr & 1) == 0) {
          int oc = oct1*16 + lq*4 + r;
          int Xp = xh*8 + (lr >> 1);
          int Yp = ps*2 + (ly0 >> 1);
          float m = fmaxf(v + bs1[oc], 0.f);
          unsigned short h = f2bf(m);
          unsigned short l = f2bf(m - bf2f(h));
          int pl = (Yp+1)*18 + (Xp+1);
          int us = (pl*5 + (oc >> 3))*8 + (oc & 7);   // padded layout, slot = oc>>3
          ishB[0][us] = h; ishB[1][us] = l;
        }
      }
    }
  }
  __syncthreads();
  // ---- conv2 bf16x2 MFMA (3-term) + fused pool + relu; A loaded directly per tap ----
  {
    const int mtp = (wvv & 1)*2;
    const int rq = wvv >> 1;
    f32x4 acc[2][4];
    #pragma unroll
    for (int i = 0; i < 2; ++i)
      #pragma unroll
      for (int j = 0; j < 4; ++j) acc[i][j] = (f32x4){0.f,0.f,0.f,0.f};
    #pragma unroll
    for (int tap = 0; tap < 9; ++tap) {
      const int off0 = ((tap*64 + mtp*16     + lr) << 5) + lq*8;
      const int off1 = ((tap*64 + (mtp+1)*16 + lr) << 5) + lq*8;
      bf16x8 ah0 = *(const bf16x8*)&wBh[off0];
      bf16x8 al0 = *(const bf16x8*)&wBl[off0];
      bf16x8 ah1 = *(const bf16x8*)&wBh[off1];
      bf16x8 al1 = *(const bf16x8*)&wBl[off1];
      const int dy = tap/3, dx = tap - dy*3;
      #pragma unroll
      for (int j = 0; j < 4; ++j) {
        int pl = (rq*4 + j + dy)*18 + lr + dx;
        int slot = pl*5 + lq;                        // padded layout, slot = lq
        bf16x8 bh = *(const bf16x8*)&ishB[0][slot << 3];
        bf16x8 bl = *(const bf16x8*)&ishB[1][slot << 3];
        acc[0][j] = __builtin_amdgcn_mfma_f32_16x16x32_bf16(ah0, bh, acc[0][j], 0, 0, 0);
        acc[1][j] = __builtin_amdgcn_mfma_f32_16x16x32_bf16(ah1, bh, acc[1][j], 0, 0, 0);
        acc[0][j] = __builtin_amdgcn_mfma_f32_16x16x32_bf16(ah0, bl, acc[0][j], 0, 0, 0);
        acc[1][j] = __builtin_amdgcn_mfma_f32_16x16x32_bf16(ah1, bl, acc[1][j], 0, 0, 0);
        acc[0][j] = __builtin_amdgcn_mfma_f32_16x16x32_bf16(al0, bh, acc[0][j], 0, 0, 0);
        acc[1][j] = __builtin_amdgcn_mfma_f32_16x16x32_bf16(al1, bh, acc[1][j], 0, 0, 0);
      }
    }
    __syncthreads();
    float* ps2 = (float*)&ishB[0][0];
    #pragma unroll
    for (int m = 0; m < 2; ++m)
      #pragma unroll
      for (int k = 0; k < 2; ++k)
        #pragma unroll
        for (int r = 0; r < 4; ++r) {
          float v = fmaxf(acc[m][2*k][r], acc[m][2*k+1][r]);
          v = fmaxf(v, __shfl_xor(v, 1, 64));
          if ((lr & 1) == 0) {
            int oc = (mtp + m)*16 + lq*4 + r;
            int Y = rq*2 + k, X = lr >> 1;
            ps2[oc*65 + Y*8 + X] = fmaxf(v + bs2[oc], 0.f);
          }
        }
    __syncthreads();
    float* op = outB + (size_t)img*4096;
    #pragma unroll
    for (int jj = 0; jj < 8; ++jj) {
      int i = jj*512 + t;
      op[i] = ps2[(i >> 6)*65 + (i & 63)];
    }
  }
}

// ================= conv3 v5: bf16x2 split MFMA (3-term); emits C as bf16 hi/lo ==========
__global__ __launch_bounds__(256) void k_conv3(const float* __restrict__ inB,
    const unsigned short* __restrict__ wAh, const unsigned short* __restrict__ wAl,
    const float* __restrict__ bias,
    unsigned short* __restrict__ Chh, unsigned short* __restrict__ Chl) {
  __shared__ unsigned short ish[2][6400];
  const int t = threadIdx.x;
  const int img = blockIdx.x;
  {
    unsigned int* z = (unsigned int*)&ish[0][0];
    #pragma unroll
    for (int j = 0; j < 25; ++j) z[t + 256*j] = 0u;
  }
  __syncthreads();
  {
    const float* src = inB + (size_t)img*4096;
    #pragma unroll
    for (int j = 0; j < 16; ++j) {
      int f = t + 256*j;
      int ic = f >> 6, p = f & 63;
      int pl = ((p >> 3) + 1)*10 + (p & 7) + 1;
      float v = src[f];
      unsigned short h = f2bf(v);
      unsigned short l = f2bf(v - bf2f(h));
      int u = pl*64 + ic;
      int us = (((u >> 3) ^ (pl & 7)) << 3) | (u & 7);
      ish[0][us] = h; ish[1][us] = l;
    }
  }
  __syncthreads();

  const int lane = t & 63, wid = t >> 6;
  const int lr = lane & 15, lq = lane >> 4;
  const int mt0 = wid*2;
  const int yb = lr >> 3, xb = lr & 7;

  f32x4 acc[2][4];
  #pragma unroll
  for (int i = 0; i < 2; ++i)
    #pragma unroll
    for (int j = 0; j < 4; ++j) acc[i][j] = (f32x4){0.f,0.f,0.f,0.f};

  for (int tap = 0; tap < 9; ++tap) {
    const int dy = tap/3, dx = tap - dy*3;
    #pragma unroll
    for (int kc = 0; kc < 2; ++kc) {
      const int kb = kc*32 + lq*8;
      const int wbase = ((tap << 7) << 6) + kb;
      bf16x8 a0h = *(const bf16x8*)&wAh[wbase + ((mt0*16 + lr) << 6)];
      bf16x8 a0l = *(const bf16x8*)&wAl[wbase + ((mt0*16 + lr) << 6)];
      bf16x8 a1h = *(const bf16x8*)&wAh[wbase + (((mt0+1)*16 + lr) << 6)];
      bf16x8 a1l = *(const bf16x8*)&wAl[wbase + (((mt0+1)*16 + lr) << 6)];
      #pragma unroll
      for (int nt = 0; nt < 4; ++nt) {
        const int pl = (2*nt + yb + dy)*10 + xb + dx;
        const int u = pl*64 + kb;
        const int us = (((u >> 3) ^ (pl & 7)) << 3);
        bf16x8 bh = *(const bf16x8*)&ish[0][us];
        bf16x8 bl = *(const bf16x8*)&ish[1][us];
        acc[0][nt] = __builtin_amdgcn_mfma_f32_16x16x32_bf16(a0h, bh, acc[0][nt], 0, 0, 0);
        acc[0][nt] = __builtin_amdgcn_mfma_f32_16x16x32_bf16(a0h, bl, acc[0][nt], 0, 0, 0);
        acc[0][nt] = __builtin_amdgcn_mfma_f32_16x16x32_bf16(a0l, bh, acc[0][nt], 0, 0, 0);
        acc[1][nt] = __builtin_amdgcn_mfma_f32_16x16x32_bf16(a1h, bh, acc[1][nt], 0, 0, 0);
        acc[1][nt] = __builtin_amdgcn_mfma_f32_16x16x32_bf16(a1h, bl, acc[1][nt], 0, 0, 0);
        acc[1][nt] = __builtin_amdgcn_mfma_f32_16x16x32_bf16(a1l, bh, acc[1][nt], 0, 0, 0);
      }
    }
  }
  __syncthreads();
  float* stg = (float*)&ish[0][0];   // [128 oc][17]
  #pragma unroll
  for (int mtl = 0; mtl < 2; ++mtl)
    #pragma unroll
    for (int nt = 0; nt < 4; ++nt)
      #pragma unroll
      for (int r = 0; r < 4; ++r) {
        float v = acc[mtl][nt][r];
        v = fmaxf(v, __shfl_xor(v, 1, 64));
        v = fmaxf(v, __shfl_xor(v, 8, 64));
        if ((lane & 9) == 0) {
          int oc = (mt0 + mtl)*16 + lq*4 + r;
          int pix = nt*4 + (xb >> 1);
          stg[oc*17 + pix] = fmaxf(v + bias[oc], 0.f);
        }
      }
  __syncthreads();
  #pragma unroll
  for (int j = 0; j < 8; ++j) {
    int i = t + 256*j;
    float v = stg[(i >> 4)*17 + (i & 15)];
    unsigned short h = f2bf(v);
    Chh[(size_t)img*2048 + i] = h;
    Chl[(size_t)img*2048 + i] = f2bf(v - bf2f(h));
  }
}

// ================= FC GEMM v3: bf16x2 3-term MFMA, no LDS, split-K=4, prefetch dbuf ======
// R26: grid is only 512 blocks -> 2 waves/SIMD; latency can't hide via TLP (same pathology
// as R24 k_moe). Double-buffer next-ks A(4) + B(8) loads before current MFMAs. Bit-exact.
__global__ __launch_bounds__(256) void k_fc(const unsigned short* __restrict__ Chh,
    const unsigned short* __restrict__ Chl,
    const unsigned short* __restrict__ wfh, const unsigned short* __restrict__ wfl,
    float* __restrict__ P0, float* __restrict__ P1,
    float* __restrict__ P2, float* __restrict__ P3) {
  const int t = threadIdx.x;
  const int r0 = blockIdx.x * 32;
  const int kq = blockIdx.z;
  float* __restrict__ P = (kq == 0) ? P0 : (kq == 1) ? P1 : (kq == 2) ? P2 : P3;
  const int lane = t & 63, wv = t >> 6;
  const int lr = lane & 15, lq = lane >> 4;
  f32x4 acc[2][4];
  #pragma unroll
  for (int i = 0; i < 2; ++i)
    #pragma unroll
    for (int j = 0; j < 4; ++j) acc[i][j] = (f32x4){0.f,0.f,0.f,0.f};
  bf16x8 ah[2], al[2], bh[4], bl[4];
  #pragma unroll
  for (int rt = 0; rt < 2; ++rt) {
    size_t ao = (size_t)(r0 + rt*16 + lr)*2048 + kq*512 + lq*8;
    ah[rt] = *(const bf16x8*)&Chh[ao];
    al[rt] = *(const bf16x8*)&Chl[ao];
  }
  #pragma unroll
  for (int nt = 0; nt < 4; ++nt) {
    size_t bo = ((size_t)((wv*4 + nt)*64 + kq*16)*64 + lane)*8;
    bh[nt] = *(const bf16x8*)&wfh[bo];
    bl[nt] = *(const bf16x8*)&wfl[bo];
  }
  #pragma unroll 4
  for (int ks = 0; ks < 16; ++ks) {
    bf16x8 nah[2], nal[2], nbh[4], nbl[4];
    if (ks < 15) {
      #pragma unroll
      for (int rt = 0; rt < 2; ++rt) {
        size_t ao = (size_t)(r0 + rt*16 + lr)*2048 + kq*512 + (ks+1)*32 + lq*8;
        nah[rt] = *(const bf16x8*)&Chh[ao];
        nal[rt] = *(const bf16x8*)&Chl[ao];
      }
      #pragma unroll
      for (int nt = 0; nt < 4; ++nt) {
        size_t bo = ((size_t)((wv*4 + nt)*64 + kq*16 + ks + 1)*64 + lane)*8;
        nbh[nt] = *(const bf16x8*)&wfh[bo];
        nbl[nt] = *(const bf16x8*)&wfl[bo];
      }
    }
    #pragma unroll
    for (int nt = 0; nt < 4; ++nt) {
      acc[0][nt] = __builtin_amdgcn_mfma_f32_16x16x32_bf16(ah[0], bh[nt], acc[0][nt], 0, 0, 0);
      acc[1][nt] = __builtin_amdgcn_mfma_f32_16x16x32_bf16(ah[1], bh[nt], acc[1][nt], 0, 0, 0);
      acc[0][nt] = __builtin_amdgcn_mfma_f32_16x16x32_bf16(ah[0], bl[nt], acc[0][nt], 0, 0, 0);
      acc[1][nt] = __builtin_amdgcn_mfma_f32_16x16x32_bf16(ah[1], bl[nt], acc[1][nt], 0, 0, 0);
      acc[0][nt] = __builtin_amdgcn_mfma_f32_16x16x32_bf16(al[0], bh[nt], acc[0][nt], 0, 0, 0);
      acc[1][nt] = __builtin_amdgcn_mfma_f32_16x16x32_bf16(al[1], bh[nt], acc[1][nt], 0, 0, 0);
    }
    if (ks < 15) {
      #pragma unroll
      for (int rt = 0; rt < 2; ++rt) { ah[rt] = nah[rt]; al[rt] = nal[rt]; }
      #pragma unroll
      for (int nt = 0; nt < 4; ++nt) { bh[nt] = nbh[nt]; bl[nt] = nbl[nt]; }
    }
  }
  #pragma unroll
  for (int rt = 0; rt < 2; ++rt)
    #pragma unroll
    for (int nt = 0; nt < 4; ++nt)
      #pragma unroll
      for (int r = 0; r < 4; ++r)
        P[(size_t)(r0 + rt*16 + lq*4 + r)*256 + (wv*4 + nt)*16 + lr] = acc[rt][nt][r];
}

// ================= gate: feat = P0+P1+P2+P3+fcb; logits; top-2 softmax; expert lists
__global__ __launch_bounds__(256) void k_gate(const float* __restrict__ P0,
    const float* __restrict__ P1, const float* __restrict__ P2, const float* __restrict__ P3,
    const float* __restrict__ fcb,
    const float* __restrict__ gw, const float* __restrict__ gb,
    float* __restrict__ feat, int* __restrict__ cnt, float* __restrict__ gsum,
    int* __restrict__ lrow, float* __restrict__ lg) {
  __shared__ float ft[16][256];
  __shared__ float lgs[16][16];
  __shared__ float gwl[4096];
  const int t = threadIdx.x;
  const int r0 = blockIdx.x * 16;
  for (int i = t; i < 4096; i += 256) gwl[i] = gw[i];
  float bb = fcb[t];
  #pragma unroll
  for (int r = 0; r < 16; ++r) {
    size_t off = (size_t)(r0+r)*256 + t;
    float v = P0[off] + P1[off] + P2[off] + P3[off] + bb;
    ft[r][t] = v;
    feat[off] = v;
  }
  __syncthreads();
  {
    int r = t >> 4, e = t & 15;
    float s = gb[e];
    for (int k = 0; k < 256; ++k) s = fmaf(ft[r][k], gwl[k*16 + e], s);
    lgs[r][e] = s;
  }
  __syncthreads();
  if (t < 16) {
    int r = t;
    float v1 = -3.402823e38f, v2 = -3.402823e38f;
    int i1 = 0, i2 = 0;
    for (int e = 0; e < 16; ++e) {
      float v = lgs[r][e];
      if (v > v1)      { v2 = v1; i2 = i1; v1 = v; i1 = e; }
      else if (v > v2) { v2 = v;  i2 = e; }
    }
    float ex = __expf(v2 - v1);
    float g1 = 1.f / (1.f + ex);
    float g2 = ex  / (1.f + ex);
    int row = r0 + r;
    int p1 = atomicAdd(&cnt[i1], 1); lrow[i1*4096 + p1] = row; lg[i1*4096 + p1] = g1;
    int p2 = atomicAdd(&cnt[i2], 1); lrow[i2*4096 + p2] = row; lg[i2*4096 + p2] = g2;
    atomicAdd(&gsum[i1], g1);
    atomicAdd(&gsum[i2], g2);
  }
}

// ================= MoE v5: 32-row tiles x split-K(8), prefetch-pipelined weights ========
__global__ __launch_bounds__(256) void k_moe(const float* __restrict__ feat,
    const unsigned short* __restrict__ w1th, const unsigned short* __restrict__ w1tl,
    const unsigned short* __restrict__ w2th, const unsigned short* __restrict__ w2tl,
    const float* __restrict__ eb1, const float* __restrict__ eb2,
    const int* __restrict__ cnt, const int* __restrict__ lrow, const float* __restrict__ lgw,
    float* __restrict__ moe) {
  const int e = blockIdx.y;
  const int n_e = cnt[e];
  const int start = blockIdx.x * 32;
  if (start >= n_e) return;
  const int c = blockIdx.z;
  const int n = min(32, n_e - start);
  __shared__ unsigned short fh[8192], fl[8192];
  __shared__ unsigned short h1h[4096], h1l[4096];
  __shared__ int   rws[32];
  __shared__ float gws[32];
  const int t = threadIdx.x;
  if (t < 32) {
    rws[t] = (t < n) ? lrow[e*4096 + start + t] : 0;
    gws[t] = (t < n) ? lgw[e*4096 + start + t] : 0.f;
  }
  __syncthreads();
  for (int j = 0; j < 32; ++j) {
    float v = (j < n) ? feat[(size_t)rws[j]*256 + t] : 0.f;
    unsigned short h = f2bf(v);
    int us = (j*32 + ((t >> 3) ^ (j & 7)))*8 + (t & 7);
    fh[us] = h; fl[us] = f2bf(v - bf2f(h));
  }
  const int lane = t & 63, wv = t >> 6;
  const int lr = lane & 15, lq = lane >> 4;
  const int rh = wv & 1, qh = wv >> 1;
  const int arow = rh*16 + lr;
  const int rsw = arow & 7;
  const size_t ewb = (size_t)e << 18;

  f32x4 acc2[8];
  #pragma unroll
  for (int i = 0; i < 8; ++i) acc2[i] = (f32x4){0.f,0.f,0.f,0.f};

  __syncthreads();

  {
    // -------- GEMM1: K=256 (8 ks), 4 htiles/wave; prefetch ks+1 weights --------
    f32x4 acc1[4];
    #pragma unroll
    for (int i = 0; i < 4; ++i) acc1[i] = (f32x4){0.f,0.f,0.f,0.f};
    bf16x8 wbh[4], wbl[4];
    #pragma unroll
    for (int ht = 0; ht < 4; ++ht) {
      size_t bo = ewb + ((size_t)((c*8 + qh*4 + ht)*8 + 0)*64 + lane)*8;
      wbh[ht] = *(const bf16x8*)&w1th[bo];
      wbl[ht] = *(const bf16x8*)&w1tl[bo];
    }
    #pragma unroll
    for (int ks = 0; ks < 8; ++ks) {
      bf16x8 nbh[4], nbl[4];
      if (ks < 7) {
        #pragma unroll
        for (int ht = 0; ht < 4; ++ht) {
          size_t bo = ewb + ((size_t)((c*8 + qh*4 + ht)*8 + ks + 1)*64 + lane)*8;
          nbh[ht] = *(const bf16x8*)&w1th[bo];
          nbl[ht] = *(const bf16x8*)&w1tl[bo];
        }
      }
      int aoff = (arow*32 + ((ks*4 + lq) ^ rsw))*8;
      bf16x8 ah = *(const bf16x8*)&fh[aoff];
      bf16x8 al = *(const bf16x8*)&fl[aoff];
      #pragma unroll
      for (int ht = 0; ht < 4; ++ht) {
        acc1[ht] = __builtin_amdgcn_mfma_f32_16x16x32_bf16(ah, wbh[ht], acc1[ht], 0, 0, 0);
        acc1[ht] = __builtin_amdgcn_mfma_f32_16x16x32_bf16(ah, wbl[ht], acc1[ht], 0, 0, 0);
        acc1[ht] = __builtin_amdgcn_mfma_f32_16x16x32_bf16(al, wbh[ht], acc1[ht], 0, 0, 0);
      }
      if (ks < 7) {
        #pragma unroll
        for (int ht = 0; ht < 4; ++ht) { wbh[ht] = nbh[ht]; wbl[ht] = nbl[ht]; }
      }
    }
    __syncthreads();
    #pragma unroll
    for (int ht = 0; ht < 4; ++ht) {
      int hloc = qh*64 + ht*16 + lr;
      float bb = eb1[e*1024 + c*128 + hloc];
      #pragma unroll
      for (int r = 0; r < 4; ++r) {
        int orow = rh*16 + lq*4 + r;
        float v = fmaxf(acc1[ht][r] + bb, 0.f);
        unsigned short hh = f2bf(v);
        int us = (orow*16 + ((hloc >> 3) ^ (orow & 7)))*8 + (hloc & 7);
        h1h[us] = hh; h1l[us] = f2bf(v - bf2f(hh));
      }
    }
    __syncthreads();
    // -------- GEMM2: K=128 local (4 ks), 8 dtiles/wave; prefetch per half-dt group ----
    bf16x8 w2h[4], w2l[4];
    #pragma unroll
    for (int dt = 0; dt < 4; ++dt) {
      size_t bo = ewb + ((size_t)((qh*8 + dt)*32 + c*4 + 0)*64 + lane)*8;
      w2h[dt] = *(const bf16x8*)&w2th[bo];
      w2l[dt] = *(const bf16x8*)&w2tl[bo];
    }
    #pragma unroll
    for (int g = 0; g < 8; ++g) {
      const int ks = g >> 1, dth = (g & 1)*4;
      bf16x8 nh[4], nl[4];
      if (g < 7) {
        const int ks2 = (g+1) >> 1, dth2 = ((g+1) & 1)*4;
        #pragma unroll
        for (int dt = 0; dt < 4; ++dt) {
          size_t bo = ewb + ((size_t)((qh*8 + dth2 + dt)*32 + c*4 + ks2)*64 + lane)*8;
          nh[dt] = *(const bf16x8*)&w2th[bo];
          nl[dt] = *(const bf16x8*)&w2tl[bo];
        }
      }
      int aoff = (arow*16 + ((ks*4 + lq) ^ rsw))*8;
      bf16x8 ah = *(const bf16x8*)&h1h[aoff];
      bf16x8 al = *(const bf16x8*)&h1l[aoff];
      #pragma unroll
      for (int dt = 0; dt < 4; ++dt) {
        acc2[dth+dt] = __builtin_amdgcn_mfma_f32_16x16x32_bf16(ah, w2h[dt], acc2[dth+dt], 0, 0, 0);
        acc2[dth+dt] = __builtin_amdgcn_mfma_f32_16x16x32_bf16(ah, w2l[dt], acc2[dth+dt], 0, 0, 0);
        acc2[dth+dt] = __builtin_amdgcn_mfma_f32_16x16x32_bf16(al, w2h[dt], acc2[dth+dt], 0, 0, 0);
      }
      if (g < 7) {
        #pragma unroll
        for (int dt = 0; dt < 4; ++dt) { w2h[dt] = nh[dt]; w2l[dt] = nl[dt]; }
      }
    }
  }
  #pragma unroll
  for (int dt = 0; dt < 8; ++dt) {
    int d = qh*128 + dt*16 + lr;
    float b2 = (c == 0) ? eb2[e*256 + d] : 0.f;
    #pragma unroll
    for (int r = 0; r < 4; ++r) {
      int orow = rh*16 + lq*4 + r;
      if (orow < n)
        atomicAdd(&moe[(size_t)rws[orow]*256 + d], gws[orow]*(acc2[dt][r] + b2));
    }
  }
}

// ================= LayerNorm(moe + feat) -> y bf16 hi/lo; block 4096 computes lb_loss ======
__global__ __launch_bounds__(256) void k_ln(const float* __restrict__ feat,
    const float* __restrict__ moe, const float* __restrict__ g, const float* __restrict__ bp,
    unsigned short* __restrict__ yh, unsigned short* __restrict__ yl,
    const float* __restrict__ gsum, float* __restrict__ out_lb) {
  const int r = blockIdx.x, t = threadIdx.x;
  if (r == NB) {            // lb block: wave 0 only, no barriers on this path
    if (t < 64) {
      float term = 0.f;
      if (t < 16) {
        float D = gsum[t] * (1.f/4096.f);
        term = D * logf(D + 1e-8f);
      }
      #pragma unroll
      for (int o = 8; o > 0; o >>= 1) term += __shfl_down(term, o, 64);
      if (t == 0) *out_lb = term;
    }
    return;
  }
  float v = moe[(size_t)r*256 + t] + feat[(size_t)r*256 + t];
  float s = v, q = v * v;
  #pragma unroll
  for (int o = 32; o > 0; o >>= 1) {
    s += __shfl_down(s, o, 64);
    q += __shfl_down(q, o, 64);
  }
  __shared__ float ss[4], qq[4];
  int wv = t >> 6;
  if ((t & 63) == 0) { ss[wv] = s; qq[wv] = q; }
  __syncthreads();
  float S = ss[0]+ss[1]+ss[2]+ss[3];
  float Q = qq[0]+qq[1]+qq[2]+qq[3];
  float mu  = S * (1.f/256.f);
  float var = Q * (1.f/256.f) - mu*mu;
  float inv = rsqrtf(var + 1e-5f);
  float y = (v - mu) * inv * g[t] + bp[t];
  unsigned short h = f2bf(y);
  yh[(size_t)r*256 + t] = h;
  yl[(size_t)r*256 + t] = f2bf(y - bf2f(h));
}

// ================= output GEMM v2: bf16x2 3-term MFMA, no LDS =================
__global__ __launch_bounds__(256) void k_out(const unsigned short* __restrict__ yh,
    const unsigned short* __restrict__ yl,
    const unsigned short* __restrict__ owh, const unsigned short* __restrict__ owl,
    const float* __restrict__ ob, float* __restrict__ out) {
  const int t = threadIdx.x;
  const int r0 = blockIdx.x * 32;
  const int lane = t & 63, wv = t >> 6;
  const int lr = lane & 15, lq = lane >> 4;
  const int ntile = blockIdx.y*4 + wv;
  f32x4 acc[2];
  acc[0] = (f32x4){0.f,0.f,0.f,0.f};
  acc[1] = (f32x4){0.f,0.f,0.f,0.f};
  #pragma unroll
  for (int ks = 0; ks < 8; ++ks) {
    bf16x8 bh = *(const bf16x8*)&owh[((size_t)(ntile*8 + ks)*64 + lane)*8];
    bf16x8 bl = *(const bf16x8*)&owl[((size_t)(ntile*8 + ks)*64 + lane)*8];
    #pragma unroll
    for (int rt = 0; rt < 2; ++rt) {
      size_t ao = (size_t)(r0 + rt*16 + lr)*256 + ks*32 + lq*8;
      bf16x8 ah = *(const bf16x8*)&yh[ao];
      bf16x8 al = *(const bf16x8*)&yl[ao];
      acc[rt] = __builtin_amdgcn_mfma_f32_16x16x32_bf16(ah, bh, acc[rt], 0, 0, 0);
      acc[rt] = __builtin_amdgcn_mfma_f32_16x16x32_bf16(ah, bl, acc[rt], 0, 0, 0);
      acc[rt] = __builtin_amdgcn_mfma_f32_16x16x32_bf16(al, bh, acc[rt], 0, 0, 0);
    }
  }
  const int col = ntile*16 + lr;
  if (col < NCLS) {
    float bb = ob[col];
    #pragma unroll
    for (int rt = 0; rt < 2; ++rt)
      #pragma unroll
      for (int r = 0; r < 4; ++r)
        out[(size_t)(r0 + rt*16 + lq*4 + r)*NCLS + col] = acc[rt][r] + bb;
  }
}

// ================= launch =================
extern "C" void kernel_launch(void* const* d_in, const int* in_sizes, int n_in,
                              void* d_out, int out_size, void* d_ws, size_t ws_size,
                              hipStream_t stream) {
  const float* x   = (const float*)d_in[0];
  const float* c1w = (const float*)d_in[1];
  const float* c1b = (const float*)d_in[2];
  const float* c2w = (const float*)d_in[3];
  const float* c2b = (const float*)d_in[4];
  const float* c3w = (const float*)d_in[5];
  const float* c3b = (const float*)d_in[6];
  const float* fcw = (const float*)d_in[7];
  const float* fcb = (const float*)d_in[8];
  const float* gw  = (const float*)d_in[9];
  const float* gb  = (const float*)d_in[10];
  const float* ew1 = (const float*)d_in[11];
  const float* eb1 = (const float*)d_in[12];
  const float* ew2 = (const float*)d_in[13];
  const float* eb2 = (const float*)d_in[14];
  const float* lng = (const float*)d_in[15];
  const float* lnb = (const float*)d_in[16];
  const float* ow  = (const float*)d_in[17];
  const float* ob  = (const float*)d_in[18];
  char* ws = (char*)d_ws;
  float* Bb   = (float*)(ws + OFF_B);
  float* P0   = (float*)(ws + OFF_P0);
  float* P1   = (float*)(ws + OFF_P1);
  float* P2   = (float*)(ws + OFF_P2);
  float* P3   = (float*)(ws + OFF_P3);
  unsigned short* Chh = (unsigned short*)(ws + OFF_CHH);
  unsigned short* Chl = (unsigned short*)(ws + OFF_CHL);
  unsigned short* wBh = (unsigned short*)(ws + OFF_CHH);   // aliases Chh (written after conv12)
  unsigned short* wBl = (unsigned short*)(ws + OFF_WBL);
  unsigned short* wA1h = (unsigned short*)(ws + OFF_WA1H);
  unsigned short* wA1l = (unsigned short*)(ws + OFF_WA1L);
  unsigned short* wAh = (unsigned short*)(ws + OFF_FEAT);  // aliases feat (written later)
  unsigned short* wAl = (unsigned short*)(ws + OFF_WAL);
  unsigned short* w1th = (unsigned short*)(ws + OFF_W1TH);
  unsigned short* w1tl = (unsigned short*)(ws + OFF_W1TL);
  unsigned short* w2th = (unsigned short*)(ws + OFF_W2TH);
  unsigned short* w2tl = (unsigned short*)(ws + OFF_W2TL);
  unsigned short* wfh = (unsigned short*)(ws + OFF_WFCH);
  unsigned short* wfl = (unsigned short*)(ws + OFF_WFCL);
  unsigned short* owph = (unsigned short*)(ws + OFF_OWH);
  unsigned short* owpl = (unsigned short*)(ws + OFF_OWL);
  unsigned short* yh = (unsigned short*)(ws + OFF_P0);     // aliases P0 (dead after gate)
  unsigned short* yl = (unsigned short*)(ws + OFF_P1);     // aliases P1
  float* feat = (float*)(ws + OFF_FEAT);
  float* moe  = (float*)(ws + OFF_MOE);
  int*   cnt  = (int*)(ws + OFF_CNT);
  float* gsum = (float*)(ws + OFF_GSUM);
  int*   lrow = (int*)(ws + OFF_LROW);
  float* lgv  = (float*)(ws + OFF_LG);
  float* outp = (float*)d_out;

  hipMemsetAsync(ws + OFF_MOE, 0, 4194304 + 128, stream);

  hipLaunchKernelGGL(k_wprep,  dim3(364),     dim3(256), 0, stream,
                     c1w, wA1h, wA1l, c2w, wBh, wBl, c3w, wAh, wAl);
  hipLaunchKernelGGL(k_conv12, dim3(4096),    dim3(512), 0, stream, x, wA1h, wA1l, c1b, wBh, wBl, c2b, Bb);
  hipLaunchKernelGGL(k_conv3,  dim3(4096),    dim3(256), 0, stream, Bb, wAh, wAl, c3b, Chh, Chl);
  // Bb dead now -> build ALL packed weights that live in its region (one kernel)
  hipLaunchKernelGGL(k_packall, dim3(3200),   dim3(256), 0, stream,
                     ew1, w1th, w1tl, ew2, w2th, w2tl, fcw, wfh, wfl, ow, owph, owpl);
  hipLaunchKernelGGL(k_fc,     dim3(128, 1, 4), dim3(256), 0, stream, Chh, Chl, wfh, wfl, P0, P1, P2, P3);
  hipLaunchKernelGGL(k_gate,   dim3(256),     dim3(256), 0, stream, P0, P1, P2, P3, fcb, gw, gb,
                     feat, cnt, gsum, lrow, lgv);
  hipLaunchKernelGGL(k_moe,    dim3(128, 16, 8), dim3(256), 0, stream, feat, w1th, w1tl, w2th, w2tl,
                     eb1, eb2, cnt, lrow, lgv, moe);
  hipLaunchKernelGGL(k_ln,     dim3(4097),    dim3(256), 0, stream, feat, moe, lng, lnb, yh, yl,
                     gsum, outp + (size_t)NB*NCLS);
  hipLaunchKernelGGL(k_out,    dim3(128, 16), dim3(256), 0, stream, yh, yl, owph, owpl, ob, outp);
}

// Round 27
// 730.057 us; speedup vs baseline: 1.1147x; 1.0193x over previous
//
#include <hip/hip_runtime.h>
#include <hip/hip_bf16.h>

typedef short bf16x8 __attribute__((ext_vector_type(8)));
typedef float f32x4 __attribute__((ext_vector_type(4)));

// ---------------- problem sizes ----------------
#define NB   4096
#define NEXP 16
#define DDIM 256
#define HDIM 1024
#define NCLS 1000

// ---------------- workspace layout (bytes) ----------------
// Base layout (always valid). If ws_size >= WS_BIG, packed weights move to the
// relocated region (no Bb alias) and k_packall fuses into conv3's grid.
#define OFF_B    ((size_t)0)
#define OFF_P0   ((size_t)0)           // f32 [4096][256] FC partial (kq 0); ALSO yh after gate
#define OFF_P1   ((size_t)4194304)     // f32 [4096][256] FC partial (kq 1); ALSO yl after gate
#define OFF_W1TH ((size_t)8388608)     // bf16 packed [16][64 ht][8 ks][64 lane][8]  8 MB
#define OFF_W1TL ((size_t)16777216)
#define OFF_W2TH ((size_t)25165824)    // bf16 packed [16][16 dt][32 ks][64 lane][8] 8 MB
#define OFF_W2TL ((size_t)33554432)
#define OFF_WFCH ((size_t)41943040)    // fcw packed hi (1 MB)
#define OFF_WFCL ((size_t)42991616)    // fcw packed lo (1 MB)
#define OFF_P2   ((size_t)44040192)    // f32 [4096][256] FC partial (kq 2)
#define OFF_P3   ((size_t)48234496)    // f32 [4096][256] FC partial (kq 3)
#define OFF_OWH  ((size_t)52428800)    // ow packed hi [64 nt][8 ks][64][8] (512 KB)
#define OFF_OWL  ((size_t)53477376)
#define OFF_CHH  ((size_t)67108864)    // conv3 out hi bf16 [4096][2048]; ALSO wBh/wBl/wA1 before conv12
#define OFF_CHL  ((size_t)83886080)    // conv3 out lo bf16
#define OFF_WBL  ((size_t)67145728)
#define OFF_WA1H ((size_t)67182592)
#define OFF_WA1L ((size_t)67184640)
#define OFF_FEAT ((size_t)100663296)   // f32 [4096][256]; ALSO wAh/wAl (288 KB) before k_gate
#define OFF_WAL  ((size_t)100810752)
#define OFF_MOE  ((size_t)104857600)   // f32 [4096][256]
#define OFF_CNT  ((size_t)109051904)   // int [16]
#define OFF_GSUM ((size_t)109051968)   // f32 [16]
#define OFF_LROW ((size_t)109052032)   // int [16][4096]
#define OFF_LG   ((size_t)109314176)   // f32 [16][4096]  (ends 109576320)
// relocated packed-weight region (no alias with Bb) for the fused-pack path:
#define OFF2_W1TH ((size_t)109600768)
#define OFF2_W1TL ((size_t)117989376)
#define OFF2_W2TH ((size_t)126377984)
#define OFF2_W2TL ((size_t)134766592)
#define OFF2_WFCH ((size_t)143155200)
#define OFF2_WFCL ((size_t)144203776)
#define OFF2_OWH  ((size_t)145252352)
#define OFF2_OWL  ((size_t)146300928)
#define WS_BIG    ((size_t)147349504)

__device__ inline unsigned short f2bf(float v) {
  __hip_bfloat16 h = __float2bfloat16(v);
  return *(unsigned short*)&h;
}
__device__ inline float bf2f(unsigned short u) {
  union { unsigned int i; float f; } c; c.i = ((unsigned int)u) << 16; return c.f;
}

// ====== merged weight prep: conv1(1024) + conv2(18432) + conv3(73728) elems, range-split
__global__ __launch_bounds__(256) void k_wprep(
    const float* __restrict__ c1w, unsigned short* __restrict__ a1h, unsigned short* __restrict__ a1l,
    const float* __restrict__ c2w, unsigned short* __restrict__ b2h, unsigned short* __restrict__ b2l,
    const float* __restrict__ c3w, unsigned short* __restrict__ a3h, unsigned short* __restrict__ a3l) {
  int i = blockIdx.x*256 + threadIdx.x;   // over 93184
  if (i < 1024) {
    int k = i & 31, oc = i >> 5;
    float v = (k < 27) ? c1w[oc*27 + k] : 0.f;
    unsigned short h = f2bf(v);
    a1h[i] = h; a1l[i] = f2bf(v - bf2f(h));
  } else if (i < 19456) {
    int j = i - 1024;
    int ic = j & 31, rem = j >> 5;
    int oc = rem & 63, tap = rem >> 6;
    float v = c2w[(oc*32 + ic)*9 + tap];
    unsigned short h = f2bf(v);
    b2h[j] = h; b2l[j] = f2bf(v - bf2f(h));
  } else if (i < 93184) {
    int j = i - 19456;
    int ic = j & 63, rem = j >> 6;
    int oc = rem & 127, tap = rem >> 7;
    float v = c3w[(oc*64 + ic)*9 + tap];
    unsigned short h = f2bf(v);
    a3h[j] = h; a3l[j] = f2bf(v - bf2f(h));
  }
}

// ====== generic pack body: in[e][R][C] -> packed hi/lo
__device__ inline void pack_body(const float* __restrict__ in,
    unsigned short* __restrict__ oh, unsigned short* __restrict__ ol,
    int R, int C, int bx, int by, int e, int t, float (*tile)[65]) {
  const size_t eb = (size_t)e * R * C;
  const int c0 = bx*64, r0 = by*64;
  const int cc = t & 63, r4 = t >> 6;
  #pragma unroll
  for (int j = 0; j < 16; ++j) {
    int rr = r4 + j*4;
    tile[rr][cc] = in[eb + (size_t)(r0+rr)*C + c0 + cc];
  }
  __syncthreads();
  const int K32 = R >> 5;
  #pragma unroll
  for (int j = 0; j < 16; ++j) {
    int idx = t + j*256;
    int jin = idx & 7, lane = (idx >> 3) & 63, ksl = (idx >> 9) & 1, ntl = idx >> 10;
    int kl = ksl*32 + ((lane >> 4) << 3) + jin;
    int nl = ntl*16 + (lane & 15);
    float v = tile[kl][nl];
    unsigned short h = f2bf(v);
    size_t o = eb + ((size_t)(((c0 >> 4) + ntl)*K32 + (r0 >> 5) + ksl)*64 + lane)*8 + jin;
    oh[o] = h;
    ol[o] = f2bf(v - bf2f(h));
  }
}

// ====== pack block dispatch (shared by k_packall and fused conv3 path)
__device__ inline void pack_dispatch(int b, int t, float (*tile)[65],
    const float* __restrict__ ew1, unsigned short* __restrict__ w1th, unsigned short* __restrict__ w1tl,
    const float* __restrict__ ew2, unsigned short* __restrict__ w2th, unsigned short* __restrict__ w2tl,
    const float* __restrict__ fcw, unsigned short* __restrict__ wfh,  unsigned short* __restrict__ wfl,
    const float* __restrict__ ow,  unsigned short* __restrict__ owh,  unsigned short* __restrict__ owl) {
  if (b < 1024) {                       // ew1: R=256, C=1024
    int bx = b & 15, by = (b >> 4) & 3, e = b >> 6;
    pack_body(ew1, w1th, w1tl, 256, 1024, bx, by, e, t, tile);
  } else if (b < 2048) {                // ew2: R=1024, C=256
    int lb = b - 1024;
    int bx = lb & 3, by = (lb >> 2) & 15, e = lb >> 6;
    pack_body(ew2, w2th, w2tl, 1024, 256, bx, by, e, t, tile);
  } else if (b < 2176) {                // fcw: R=2048, C=256
    int lb = b - 2048;
    int bx = lb & 3, by = lb >> 2;
    pack_body(fcw, wfh, wfl, 2048, 256, bx, by, 0, t, tile);
  } else {                              // ow pack (elementwise)
    int lb = b - 2176;
    int i = lb*256 + t;                 // over 262144
    int j = i & 7, lane = (i >> 3) & 63, ks = (i >> 9) & 7, nt = i >> 12;
    int k = ks*32 + ((lane >> 4) << 3) + j;
    int n = nt*16 + (lane & 15);
    float v = (n < NCLS) ? ow[(size_t)k*NCLS + n] : 0.f;
    unsigned short h = f2bf(v);
    owh[i] = h;
    owl[i] = f2bf(v - bf2f(h));
  }
}

// ====== standalone merged packs (fallback path when ws is small)
__global__ __launch_bounds__(256) void k_packall(
    const float* __restrict__ ew1, unsigned short* __restrict__ w1th, unsigned short* __restrict__ w1tl,
    const float* __restrict__ ew2, unsigned short* __restrict__ w2th, unsigned short* __restrict__ w2tl,
    const float* __restrict__ fcw, unsigned short* __restrict__ wfh,  unsigned short* __restrict__ wfl,
    const float* __restrict__ ow,  unsigned short* __restrict__ owh,  unsigned short* __restrict__ owl) {
  __shared__ float tile[64][65];
  pack_dispatch(blockIdx.x, threadIdx.x, tile,
                ew1, w1th, w1tl, ew2, w2th, w2tl, fcw, wfh, wfl, ow, owh, owl);
}

// ============ fused conv1(reg-im2col bf16x2 MFMA) + conv2(bf16x2 MFMA, 3-term) per image ====
// R27: padded-k loads made unconditional via 1152-word zero tail after xsu (removes
// 128 v_cndmask/thread). LDS 71.5 KB, still 2 blocks/CU. Values bit-exact.
__global__ __launch_bounds__(512, 4) void k_conv12(const float* __restrict__ x,
    const unsigned short* __restrict__ wA1h, const unsigned short* __restrict__ wA1l,
    const float* __restrict__ b1,
    const unsigned short* __restrict__ wBh, const unsigned short* __restrict__ wBl,
    const float* __restrict__ b2, float* __restrict__ outB) {
  __shared__ unsigned int xsu[3*34*36 + 1152]; // packed bf16 image + zero tail (19.3 KB)
  __shared__ __align__(16) unsigned short ishB[2][12960]; // [pl][5 slots][8] padded (51.8 KB)
  __shared__ float bs1[32];
  __shared__ float bs2[64];
  const int t = threadIdx.x;
  const int img = blockIdx.x;
  for (int i = t; i < 3*34*36 + 1152; i += 512) xsu[i] = 0u;
  {
    // border-only zero: pls with y==0, y==17, x==0 or x==17; 20 u32 per pl per plane
    unsigned int* z = (unsigned int*)&ishB[0][0];
    for (int i = t; i < 2720; i += 512) {
      int plane = i / 1360, rem = i - plane*1360;
      int b = rem / 20, o = rem - b*20;
      int pl;
      if (b < 18)      pl = b;                    // y = 0
      else if (b < 36) pl = 306 + (b - 18);       // y = 17
      else if (b < 52) pl = (b - 35) * 18;        // x = 0,  y = 1..16
      else             pl = (b - 51) * 18 + 17;   // x = 17, y = 1..16
      z[plane*6480 + pl*20 + o] = 0u;
    }
  }
  __syncthreads();
  for (int i = t; i < 3072; i += 512) {
    int ic = i >> 10, rem = i & 1023, y = rem >> 5, xx = rem & 31;
    float v = x[(size_t)img*3072 + i];
    unsigned short h = f2bf(v);
    unsigned short l = f2bf(v - bf2f(h));
    xsu[ic*34*36 + (y+1)*36 + (xx+1)] = ((unsigned int)l << 16) | (unsigned int)h;
  }
  if (t < 32) bs1[t] = b1[t];
  else if (t >= 64 && t < 128) bs2[t-64] = b2[t-64];

  const int lane = t & 63, wvv = t >> 6;
  const int lr = lane & 15, lq = lane >> 4;

  const int oct1 = wvv & 1;
  const bf16x8 a1h = *(const bf16x8*)&wA1h[((oct1*16 + lr) << 5) + lq*8];
  const bf16x8 a1l = *(const bf16x8*)&wA1l[((oct1*16 + lr) << 5) + lq*8];

  int koff[8];
  #pragma unroll
  for (int j = 0; j < 8; ++j) {
    int k = lq*8 + j;
    if (k < 27) {
      int ic = k/9, tap = k - ic*9, dy = tap/3, dx = tap - dy*3;
      koff[j] = ic*34*36 + dy*36 + dx;
    } else koff[j] = 3*34*36;            // zero tail -> loads return 0 unconditionally
  }
  __syncthreads();

  // ---- conv1 via MFMA, barrier-free: 8 passes of 4 pre-pool rows ----
  {
    const int rp  = wvv >> 1;
    const int ly0 = (rp >> 1) << 1;      // 0 or 2
    const int xh  = rp & 1;
    const int X   = xh*16 + lr;
    for (int ps = 0; ps < 8; ++ps) {
      const int baseA = (ps*4 + ly0)*36 + X;
      f32x4 aA = (f32x4){0.f,0.f,0.f,0.f}, aB = (f32x4){0.f,0.f,0.f,0.f};
      {
        union { unsigned int u[4]; bf16x8 v; } bh_, bl_;
        #pragma unroll
        for (int jj = 0; jj < 4; ++jj) {
          unsigned int e0 = xsu[koff[2*jj]   + baseA];
          unsigned int e1 = xsu[koff[2*jj+1] + baseA];
          bh_.u[jj] = __builtin_amdgcn_perm(e1, e0, 0x05040100u);
          bl_.u[jj] = __builtin_amdgcn_perm(e1, e0, 0x07060302u);
        }
        aA = __builtin_amdgcn_mfma_f32_16x16x32_bf16(a1h, bh_.v, aA, 0, 0, 0);
        aA = __builtin_amdgcn_mfma_f32_16x16x32_bf16(a1h, bl_.v, aA, 0, 0, 0);
        aA = __builtin_amdgcn_mfma_f32_16x16x32_bf16(a1l, bh_.v, aA, 0, 0, 0);
      }
      {
        union { unsigned int u[4]; bf16x8 v; } bh_, bl_;
        #pragma unroll
        for (int jj = 0; jj < 4; ++jj) {
          unsigned int e0 = xsu[koff[2*jj]   + baseA + 36];
          unsigned int e1 = xsu[koff[2*jj+1] + baseA + 36];
          bh_.u[jj] = __builtin_amdgcn_perm(e1, e0, 0x05040100u);
          bl_.u[jj] = __builtin_amdgcn_perm(e1, e0, 0x07060302u);
        }
        aB = __builtin_amdgcn_mfma_f32_16x16x32_bf16(a1h, bh_.v, aB, 0, 0, 0);
        aB = __builtin_amdgcn_mfma_f32_16x16x32_bf16(a1h, bl_.v, aB, 0, 0, 0);
        aB = __builtin_amdgcn_mfma_f32_16x16x32_bf16(a1l, bh_.v, aB, 0, 0, 0);
      }
      #pragma unroll
      for (int r = 0; r < 4; ++r) {
        float v = fmaxf(aA[r], aB[r]);
        v = fmaxf(v, __shfl_xor(v, 1, 64));
        if ((lr & 1) == 0) {
          int oc = oct1*16 + lq*4 + r;
          int Xp = xh*8 + (lr >> 1);
          int Yp = ps*2 + (ly0 >> 1);
          float m = fmaxf(v + bs1[oc], 0.f);
          unsigned short h = f2bf(m);
          unsigned short l = f2bf(m - bf2f(h));
          int pl = (Yp+1)*18 + (Xp+1);
          int us = (pl*5 + (oc >> 3))*8 + (oc & 7);   // padded layout, slot = oc>>3
          ishB[0][us] = h; ishB[1][us] = l;
        }
      }
    }
  }
  __syncthreads();
  // ---- conv2 bf16x2 MFMA (3-term) + fused pool + relu; A loaded directly per tap ----
  {
    const int mtp = (wvv & 1)*2;
    const int rq = wvv >> 1;
    f32x4 acc[2][4];
    #pragma unroll
    for (int i = 0; i < 2; ++i)
      #pragma unroll
      for (int j = 0; j < 4; ++j) acc[i][j] = (f32x4){0.f,0.f,0.f,0.f};
    #pragma unroll
    for (int tap = 0; tap < 9; ++tap) {
      const int off0 = ((tap*64 + mtp*16     + lr) << 5) + lq*8;
      const int off1 = ((tap*64 + (mtp+1)*16 + lr) << 5) + lq*8;
      bf16x8 ah0 = *(const bf16x8*)&wBh[off0];
      bf16x8 al0 = *(const bf16x8*)&wBl[off0];
      bf16x8 ah1 = *(const bf16x8*)&wBh[off1];
      bf16x8 al1 = *(const bf16x8*)&wBl[off1];
      const int dy = tap/3, dx = tap - dy*3;
      #pragma unroll
      for (int j = 0; j < 4; ++j) {
        int pl = (rq*4 + j + dy)*18 + lr + dx;
        int slot = pl*5 + lq;                        // padded layout, slot = lq
        bf16x8 bh = *(const bf16x8*)&ishB[0][slot << 3];
        bf16x8 bl = *(const bf16x8*)&ishB[1][slot << 3];
        acc[0][j] = __builtin_amdgcn_mfma_f32_16x16x32_bf16(ah0, bh, acc[0][j], 0, 0, 0);
        acc[1][j] = __builtin_amdgcn_mfma_f32_16x16x32_bf16(ah1, bh, acc[1][j], 0, 0, 0);
        acc[0][j] = __builtin_amdgcn_mfma_f32_16x16x32_bf16(ah0, bl, acc[0][j], 0, 0, 0);
        acc[1][j] = __builtin_amdgcn_mfma_f32_16x16x32_bf16(ah1, bl, acc[1][j], 0, 0, 0);
        acc[0][j] = __builtin_amdgcn_mfma_f32_16x16x32_bf16(al0, bh, acc[0][j], 0, 0, 0);
        acc[1][j] = __builtin_amdgcn_mfma_f32_16x16x32_bf16(al1, bh, acc[1][j], 0, 0, 0);
      }
    }
    __syncthreads();
    float* ps2 = (float*)&ishB[0][0];
    #pragma unroll
    for (int m = 0; m < 2; ++m)
      #pragma unroll
      for (int k = 0; k < 2; ++k)
        #pragma unroll
        for (int r = 0; r < 4; ++r) {
          float v = fmaxf(acc[m][2*k][r], acc[m][2*k+1][r]);
          v = fmaxf(v, __shfl_xor(v, 1, 64));
          if ((lr & 1) == 0) {
            int oc = (mtp + m)*16 + lq*4 + r;
            int Y = rq*2 + k, X = lr >> 1;
            ps2[oc*65 + Y*8 + X] = fmaxf(v + bs2[oc], 0.f);
          }
        }
    __syncthreads();
    float* op = outB + (size_t)img*4096;
    #pragma unroll
    for (int jj = 0; jj < 8; ++jj) {
      int i = jj*512 + t;
      op[i] = ps2[(i >> 6)*65 + (i & 63)];
    }
  }
}

// ================= conv3 v6: bf16x2 split MFMA; blocks >= 4096 run pack work (fused path)
__global__ __launch_bounds__(256) void k_conv3(const float* __restrict__ inB,
    const unsigned short* __restrict__ wAh, const unsigned short* __restrict__ wAl,
    const float* __restrict__ bias,
    unsigned short* __restrict__ Chh, unsigned short* __restrict__ Chl,
    const float* __restrict__ ew1, unsigned short* __restrict__ w1th, unsigned short* __restrict__ w1tl,
    const float* __restrict__ ew2, unsigned short* __restrict__ w2th, unsigned short* __restrict__ w2tl,
    const float* __restrict__ fcw, unsigned short* __restrict__ wfh,  unsigned short* __restrict__ wfl,
    const float* __restrict__ ow,  unsigned short* __restrict__ owh,  unsigned short* __restrict__ owl) {
  __shared__ unsigned short ish[2][6400];
  const int t = threadIdx.x;
  if (blockIdx.x >= 4096) {       // fused pack blocks (only present in big-ws path)
    float (*tile)[65] = (float(*)[65])&ish[0][0];   // 16.6 KB <= 25.6 KB
    pack_dispatch(blockIdx.x - 4096, t, tile,
                  ew1, w1th, w1tl, ew2, w2th, w2tl, fcw, wfh, wfl, ow, owh, owl);
    return;
  }
  const int img = blockIdx.x;
  {
    unsigned int* z = (unsigned int*)&ish[0][0];
    #pragma unroll
    for (int j = 0; j < 25; ++j) z[t + 256*j] = 0u;
  }
  __syncthreads();
  {
    const float* src = inB + (size_t)img*4096;
    #pragma unroll
    for (int j = 0; j < 16; ++j) {
      int f = t + 256*j;
      int ic = f >> 6, p = f & 63;
      int pl = ((p >> 3) + 1)*10 + (p & 7) + 1;
      float v = src[f];
      unsigned short h = f2bf(v);
      unsigned short l = f2bf(v - bf2f(h));
      int u = pl*64 + ic;
      int us = (((u >> 3) ^ (pl & 7)) << 3) | (u & 7);
      ish[0][us] = h; ish[1][us] = l;
    }
  }
  __syncthreads();

  const int lane = t & 63, wid = t >> 6;
  const int lr = lane & 15, lq = lane >> 4;
  const int mt0 = wid*2;
  const int yb = lr >> 3, xb = lr & 7;

  f32x4 acc[2][4];
  #pragma unroll
  for (int i = 0; i < 2; ++i)
    #pragma unroll
    for (int j = 0; j < 4; ++j) acc[i][j] = (f32x4){0.f,0.f,0.f,0.f};

  for (int tap = 0; tap < 9; ++tap) {
    const int dy = tap/3, dx = tap - dy*3;
    #pragma unroll
    for (int kc = 0; kc < 2; ++kc) {
      const int kb = kc*32 + lq*8;
      const int wbase = ((tap << 7) << 6) + kb;
      bf16x8 a0h = *(const bf16x8*)&wAh[wbase + ((mt0*16 + lr) << 6)];
      bf16x8 a0l = *(const bf16x8*)&wAl[wbase + ((mt0*16 + lr) << 6)];
      bf16x8 a1h = *(const bf16x8*)&wAh[wbase + (((mt0+1)*16 + lr) << 6)];
      bf16x8 a1l = *(const bf16x8*)&wAl[wbase + (((mt0+1)*16 + lr) << 6)];
      #pragma unroll
      for (int nt = 0; nt < 4; ++nt) {
        const int pl = (2*nt + yb + dy)*10 + xb + dx;
        const int u = pl*64 + kb;
        const int us = (((u >> 3) ^ (pl & 7)) << 3);
        bf16x8 bh = *(const bf16x8*)&ish[0][us];
        bf16x8 bl = *(const bf16x8*)&ish[1][us];
        acc[0][nt] = __builtin_amdgcn_mfma_f32_16x16x32_bf16(a0h, bh, acc[0][nt], 0, 0, 0);
        acc[0][nt] = __builtin_amdgcn_mfma_f32_16x16x32_bf16(a0h, bl, acc[0][nt], 0, 0, 0);
        acc[0][nt] = __builtin_amdgcn_mfma_f32_16x16x32_bf16(a0l, bh, acc[0][nt], 0, 0, 0);
        acc[1][nt] = __builtin_amdgcn_mfma_f32_16x16x32_bf16(a1h, bh, acc[1][nt], 0, 0, 0);
        acc[1][nt] = __builtin_amdgcn_mfma_f32_16x16x32_bf16(a1h, bl, acc[1][nt], 0, 0, 0);
        acc[1][nt] = __builtin_amdgcn_mfma_f32_16x16x32_bf16(a1l, bh, acc[1][nt], 0, 0, 0);
      }
    }
  }
  __syncthreads();
  float* stg = (float*)&ish[0][0];   // [128 oc][17]
  #pragma unroll
  for (int mtl = 0; mtl < 2; ++mtl)
    #pragma unroll
    for (int nt = 0; nt < 4; ++nt)
      #pragma unroll
      for (int r = 0; r < 4; ++r) {
        float v = acc[mtl][nt][r];
        v = fmaxf(v, __shfl_xor(v, 1, 64));
        v = fmaxf(v, __shfl_xor(v, 8, 64));
        if ((lane & 9) == 0) {
          int oc = (mt0 + mtl)*16 + lq*4 + r;
          int pix = nt*4 + (xb >> 1);
          stg[oc*17 + pix] = fmaxf(v + bias[oc], 0.f);
        }
      }
  __syncthreads();
  #pragma unroll
  for (int j = 0; j < 8; ++j) {
    int i = t + 256*j;
    float v = stg[(i >> 4)*17 + (i & 15)];
    unsigned short h = f2bf(v);
    Chh[(size_t)img*2048 + i] = h;
    Chl[(size_t)img*2048 + i] = f2bf(v - bf2f(h));
  }
}

// ================= FC GEMM v3: bf16x2 3-term MFMA, no LDS, split-K=4, prefetch dbuf ======
__global__ __launch_bounds__(256) void k_fc(const unsigned short* __restrict__ Chh,
    const unsigned short* __restrict__ Chl,
    const unsigned short* __restrict__ wfh, const unsigned short* __restrict__ wfl,
    float* __restrict__ P0, float* __restrict__ P1,
    float* __restrict__ P2, float* __restrict__ P3) {
  const int t = threadIdx.x;
  const int r0 = blockIdx.x * 32;
  const int kq = blockIdx.z;
  float* __restrict__ P = (kq == 0) ? P0 : (kq == 1) ? P1 : (kq == 2) ? P2 : P3;
  const int lane = t & 63, wv = t >> 6;
  const int lr = lane & 15, lq = lane >> 4;
  f32x4 acc[2][4];
  #pragma unroll
  for (int i = 0; i < 2; ++i)
    #pragma unroll
    for (int j = 0; j < 4; ++j) acc[i][j] = (f32x4){0.f,0.f,0.f,0.f};
  bf16x8 ah[2], al[2], bh[4], bl[4];
  #pragma unroll
  for (int rt = 0; rt < 2; ++rt) {
    size_t ao = (size_t)(r0 + rt*16 + lr)*2048 + kq*512 + lq*8;
    ah[rt] = *(const bf16x8*)&Chh[ao];
    al[rt] = *(const bf16x8*)&Chl[ao];
  }
  #pragma unroll
  for (int nt = 0; nt < 4; ++nt) {
    size_t bo = ((size_t)((wv*4 + nt)*64 + kq*16)*64 + lane)*8;
    bh[nt] = *(const bf16x8*)&wfh[bo];
    bl[nt] = *(const bf16x8*)&wfl[bo];
  }
  #pragma unroll 4
  for (int ks = 0; ks < 16; ++ks) {
    bf16x8 nah[2], nal[2], nbh[4], nbl[4];
    if (ks < 15) {
      #pragma unroll
      for (int rt = 0; rt < 2; ++rt) {
        size_t ao = (size_t)(r0 + rt*16 + lr)*2048 + kq*512 + (ks+1)*32 + lq*8;
        nah[rt] = *(const bf16x8*)&Chh[ao];
        nal[rt] = *(const bf16x8*)&Chl[ao];
      }
      #pragma unroll
      for (int nt = 0; nt < 4; ++nt) {
        size_t bo = ((size_t)((wv*4 + nt)*64 + kq*16 + ks + 1)*64 + lane)*8;
        nbh[nt] = *(const bf16x8*)&wfh[bo];
        nbl[nt] = *(const bf16x8*)&wfl[bo];
      }
    }
    #pragma unroll
    for (int nt = 0; nt < 4; ++nt) {
      acc[0][nt] = __builtin_amdgcn_mfma_f32_16x16x32_bf16(ah[0], bh[nt], acc[0][nt], 0, 0, 0);
      acc[1][nt] = __builtin_amdgcn_mfma_f32_16x16x32_bf16(ah[1], bh[nt], acc[1][nt], 0, 0, 0);
      acc[0][nt] = __builtin_amdgcn_mfma_f32_16x16x32_bf16(ah[0], bl[nt], acc[0][nt], 0, 0, 0);
      acc[1][nt] = __builtin_amdgcn_mfma_f32_16x16x32_bf16(ah[1], bl[nt], acc[1][nt], 0, 0, 0);
      acc[0][nt] = __builtin_amdgcn_mfma_f32_16x16x32_bf16(al[0], bh[nt], acc[0][nt], 0, 0, 0);
      acc[1][nt] = __builtin_amdgcn_mfma_f32_16x16x32_bf16(al[1], bh[nt], acc[1][nt], 0, 0, 0);
    }
    if (ks < 15) {
      #pragma unroll
      for (int rt = 0; rt < 2; ++rt) { ah[rt] = nah[rt]; al[rt] = nal[rt]; }
      #pragma unroll
      for (int nt = 0; nt < 4; ++nt) { bh[nt] = nbh[nt]; bl[nt] = nbl[nt]; }
    }
  }
  #pragma unroll
  for (int rt = 0; rt < 2; ++rt)
    #pragma unroll
    for (int nt = 0; nt < 4; ++nt)
      #pragma unroll
      for (int r = 0; r < 4; ++r)
        P[(size_t)(r0 + rt*16 + lq*4 + r)*256 + (wv*4 + nt)*16 + lr] = acc[rt][nt][r];
}

// ================= gate: feat = P0+P1+P2+P3+fcb; logits; top-2 softmax; expert lists
__global__ __launch_bounds__(256) void k_gate(const float* __restrict__ P0,
    const float* __restrict__ P1, const float* __restrict__ P2, const float* __restrict__ P3,
    const float* __restrict__ fcb,
    const float* __restrict__ gw, const float* __restrict__ gb,
    float* __restrict__ feat, int* __restrict__ cnt, float* __restrict__ gsum,
    int* __restrict__ lrow, float* __restrict__ lg) {
  __shared__ float ft[16][256];
  __shared__ float lgs[16][16];
  __shared__ float gwl[4096];
  const int t = threadIdx.x;
  const int r0 = blockIdx.x * 16;
  for (int i = t; i < 4096; i += 256) gwl[i] = gw[i];
  float bb = fcb[t];
  #pragma unroll
  for (int r = 0; r < 16; ++r) {
    size_t off = (size_t)(r0+r)*256 + t;
    float v = P0[off] + P1[off] + P2[off] + P3[off] + bb;
    ft[r][t] = v;
    feat[off] = v;
  }
  __syncthreads();
  {
    int r = t >> 4, e = t & 15;
    float s = gb[e];
    for (int k = 0; k < 256; ++k) s = fmaf(ft[r][k], gwl[k*16 + e], s);
    lgs[r][e] = s;
  }
  __syncthreads();
  if (t < 16) {
    int r = t;
    float v1 = -3.402823e38f, v2 = -3.402823e38f;
    int i1 = 0, i2 = 0;
    for (int e = 0; e < 16; ++e) {
      float v = lgs[r][e];
      if (v > v1)      { v2 = v1; i2 = i1; v1 = v; i1 = e; }
      else if (v > v2) { v2 = v;  i2 = e; }
    }
    float ex = __expf(v2 - v1);
    float g1 = 1.f / (1.f + ex);
    float g2 = ex  / (1.f + ex);
    int row = r0 + r;
    int p1 = atomicAdd(&cnt[i1], 1); lrow[i1*4096 + p1] = row; lg[i1*4096 + p1] = g1;
    int p2 = atomicAdd(&cnt[i2], 1); lrow[i2*4096 + p2] = row; lg[i2*4096 + p2] = g2;
    atomicAdd(&gsum[i1], g1);
    atomicAdd(&gsum[i2], g2);
  }
}

// ================= MoE v5: 32-row tiles x split-K(8), prefetch-pipelined weights ========
__global__ __launch_bounds__(256) void k_moe(const float* __restrict__ feat,
    const unsigned short* __restrict__ w1th, const unsigned short* __restrict__ w1tl,
    const unsigned short* __restrict__ w2th, const unsigned short* __restrict__ w2tl,
    const float* __restrict__ eb1, const float* __restrict__ eb2,
    const int* __restrict__ cnt, const int* __restrict__ lrow, const float* __restrict__ lgw,
    float* __restrict__ moe) {
  const int e = blockIdx.y;
  const int n_e = cnt[e];
  const int start = blockIdx.x * 32;
  if (start >= n_e) return;
  const int c = blockIdx.z;
  const int n = min(32, n_e - start);
  __shared__ unsigned short fh[8192], fl[8192];
  __shared__ unsigned short h1h[4096], h1l[4096];
  __shared__ int   rws[32];
  __shared__ float gws[32];
  const int t = threadIdx.x;
  if (t < 32) {
    rws[t] = (t < n) ? lrow[e*4096 + start + t] : 0;
    gws[t] = (t < n) ? lgw[e*4096 + start + t] : 0.f;
  }
  __syncthreads();
  for (int j = 0; j < 32; ++j) {
    float v = (j < n) ? feat[(size_t)rws[j]*256 + t] : 0.f;
    unsigned short h = f2bf(v);
    int us = (j*32 + ((t >> 3) ^ (j & 7)))*8 + (t & 7);
    fh[us] = h; fl[us] = f2bf(v - bf2f(h));
  }
  const int lane = t & 63, wv = t >> 6;
  const int lr = lane & 15, lq = lane >> 4;
  const int rh = wv & 1, qh = wv >> 1;
  const int arow = rh*16 + lr;
  const int rsw = arow & 7;
  const size_t ewb = (size_t)e << 18;

  f32x4 acc2[8];
  #pragma unroll
  for (int i = 0; i < 8; ++i) acc2[i] = (f32x4){0.f,0.f,0.f,0.f};

  __syncthreads();

  {
    // -------- GEMM1: K=256 (8 ks), 4 htiles/wave; prefetch ks+1 weights --------
    f32x4 acc1[4];
    #pragma unroll
    for (int i = 0; i < 4; ++i) acc1[i] = (f32x4){0.f,0.f,0.f,0.f};
    bf16x8 wbh[4], wbl[4];
    #pragma unroll
    for (int ht = 0; ht < 4; ++ht) {
      size_t bo = ewb + ((size_t)((c*8 + qh*4 + ht)*8 + 0)*64 + lane)*8;
      wbh[ht] = *(const bf16x8*)&w1th[bo];
      wbl[ht] = *(const bf16x8*)&w1tl[bo];
    }
    #pragma unroll
    for (int ks = 0; ks < 8; ++ks) {
      bf16x8 nbh[4], nbl[4];
      if (ks < 7) {
        #pragma unroll
        for (int ht = 0; ht < 4; ++ht) {
          size_t bo = ewb + ((size_t)((c*8 + qh*4 + ht)*8 + ks + 1)*64 + lane)*8;
          nbh[ht] = *(const bf16x8*)&w1th[bo];
          nbl[ht] = *(const bf16x8*)&w1tl[bo];
        }
      }
      int aoff = (arow*32 + ((ks*4 + lq) ^ rsw))*8;
      bf16x8 ah = *(const bf16x8*)&fh[aoff];
      bf16x8 al = *(const bf16x8*)&fl[aoff];
      #pragma unroll
      for (int ht = 0; ht < 4; ++ht) {
        acc1[ht] = __builtin_amdgcn_mfma_f32_16x16x32_bf16(ah, wbh[ht], acc1[ht], 0, 0, 0);
        acc1[ht] = __builtin_amdgcn_mfma_f32_16x16x32_bf16(ah, wbl[ht], acc1[ht], 0, 0, 0);
        acc1[ht] = __builtin_amdgcn_mfma_f32_16x16x32_bf16(al, wbh[ht], acc1[ht], 0, 0, 0);
      }
      if (ks < 7) {
        #pragma unroll
        for (int ht = 0; ht < 4; ++ht) { wbh[ht] = nbh[ht]; wbl[ht] = nbl[ht]; }
      }
    }
    __syncthreads();
    #pragma unroll
    for (int ht = 0; ht < 4; ++ht) {
      int hloc = qh*64 + ht*16 + lr;
      float bb = eb1[e*1024 + c*128 + hloc];
      #pragma unroll
      for (int r = 0; r < 4; ++r) {
        int orow = rh*16 + lq*4 + r;
        float v = fmaxf(acc1[ht][r] + bb, 0.f);
        unsigned short hh = f2bf(v);
        int us = (orow*16 + ((hloc >> 3) ^ (orow & 7)))*8 + (hloc & 7);
        h1h[us] = hh; h1l[us] = f2bf(v - bf2f(hh));
      }
    }
    __syncthreads();
    // -------- GEMM2: K=128 local (4 ks), 8 dtiles/wave; prefetch per half-dt group ----
    bf16x8 w2h[4], w2l[4];
    #pragma unroll
    for (int dt = 0; dt < 4; ++dt) {
      size_t bo = ewb + ((size_t)((qh*8 + dt)*32 + c*4 + 0)*64 + lane)*8;
      w2h[dt] = *(const bf16x8*)&w2th[bo];
      w2l[dt] = *(const bf16x8*)&w2tl[bo];
    }
    #pragma unroll
    for (int g = 0; g < 8; ++g) {
      const int ks = g >> 1, dth = (g & 1)*4;
      bf16x8 nh[4], nl[4];
      if (g < 7) {
        const int ks2 = (g+1) >> 1, dth2 = ((g+1) & 1)*4;
        #pragma unroll
        for (int dt = 0; dt < 4; ++dt) {
          size_t bo = ewb + ((size_t)((qh*8 + dth2 + dt)*32 + c*4 + ks2)*64 + lane)*8;
          nh[dt] = *(const bf16x8*)&w2th[bo];
          nl[dt] = *(const bf16x8*)&w2tl[bo];
        }
      }
      int aoff = (arow*16 + ((ks*4 + lq) ^ rsw))*8;
      bf16x8 ah = *(const bf16x8*)&h1h[aoff];
      bf16x8 al = *(const bf16x8*)&h1l[aoff];
      #pragma unroll
      for (int dt = 0; dt < 4; ++dt) {
        acc2[dth+dt] = __builtin_amdgcn_mfma_f32_16x16x32_bf16(ah, w2h[dt], acc2[dth+dt], 0, 0, 0);
        acc2[dth+dt] = __builtin_amdgcn_mfma_f32_16x16x32_bf16(ah, w2l[dt], acc2[dth+dt], 0, 0, 0);
        acc2[dth+dt] = __builtin_amdgcn_mfma_f32_16x16x32_bf16(al, w2h[dt], acc2[dth+dt], 0, 0, 0);
      }
      if (g < 7) {
        #pragma unroll
        for (int dt = 0; dt < 4; ++dt) { w2h[dt] = nh[dt]; w2l[dt] = nl[dt]; }
      }
    }
  }
  #pragma unroll
  for (int dt = 0; dt < 8; ++dt) {
    int d = qh*128 + dt*16 + lr;
    float b2 = (c == 0) ? eb2[e*256 + d] : 0.f;
    #pragma unroll
    for (int r = 0; r < 4; ++r) {
      int orow = rh*16 + lq*4 + r;
      if (orow < n)
        atomicAdd(&moe[(size_t)rws[orow]*256 + d], gws[orow]*(acc2[dt][r] + b2));
    }
  }
}

// ================= LayerNorm(moe + feat) -> y bf16 hi/lo; block 4096 computes lb_loss ======
__global__ __launch_bounds__(256) void k_ln(const float* __restrict__ feat,
    const float* __restrict__ moe, const float* __restrict__ g, const float* __restrict__ bp,
    unsigned short* __restrict__ yh, unsigned short* __restrict__ yl,
    const float* __restrict__ gsum, float* __restrict__ out_lb) {
  const int r = blockIdx.x, t = threadIdx.x;
  if (r == NB) {            // lb block: wave 0 only, no barriers on this path
    if (t < 64) {
      float term = 0.f;
      if (t < 16) {
        float D = gsum[t] * (1.f/4096.f);
        term = D * logf(D + 1e-8f);
      }
      #pragma unroll
      for (int o = 8; o > 0; o >>= 1) term += __shfl_down(term, o, 64);
      if (t == 0) *out_lb = term;
    }
    return;
  }
  float v = moe[(size_t)r*256 + t] + feat[(size_t)r*256 + t];
  float s = v, q = v * v;
  #pragma unroll
  for (int o = 32; o > 0; o >>= 1) {
    s += __shfl_down(s, o, 64);
    q += __shfl_down(q, o, 64);
  }
  __shared__ float ss[4], qq[4];
  int wv = t >> 6;
  if ((t & 63) == 0) { ss[wv] = s; qq[wv] = q; }
  __syncthreads();
  float S = ss[0]+ss[1]+ss[2]+ss[3];
  float Q = qq[0]+qq[1]+qq[2]+qq[3];
  float mu  = S * (1.f/256.f);
  float var = Q * (1.f/256.f) - mu*mu;
  float inv = rsqrtf(var + 1e-5f);
  float y = (v - mu) * inv * g[t] + bp[t];
  unsigned short h = f2bf(y);
  yh[(size_t)r*256 + t] = h;
  yl[(size_t)r*256 + t] = f2bf(y - bf2f(h));
}

// ================= output GEMM v3: bf16x2 3-term MFMA, no LDS, prefetch dbuf ============
__global__ __launch_bounds__(256) void k_out(const unsigned short* __restrict__ yh,
    const unsigned short* __restrict__ yl,
    const unsigned short* __restrict__ owh, const unsigned short* __restrict__ owl,
    const float* __restrict__ ob, float* __restrict__ out) {
  const int t = threadIdx.x;
  const int r0 = blockIdx.x * 32;
  const int lane = t & 63, wv = t >> 6;
  const int lr = lane & 15, lq = lane >> 4;
  const int ntile = blockIdx.y*4 + wv;
  f32x4 acc[2];
  acc[0] = (f32x4){0.f,0.f,0.f,0.f};
  acc[1] = (f32x4){0.f,0.f,0.f,0.f};
  bf16x8 bh, bl, ah[2], al[2];
  {
    size_t bo = ((size_t)(ntile*8)*64 + lane)*8;
    bh = *(const bf16x8*)&owh[bo];
    bl = *(const bf16x8*)&owl[bo];
  }
  #pragma unroll
  for (int rt = 0; rt < 2; ++rt) {
    size_t ao = (size_t)(r0 + rt*16 + lr)*256 + lq*8;
    ah[rt] = *(const bf16x8*)&yh[ao];
    al[rt] = *(const bf16x8*)&yl[ao];
  }
  #pragma unroll
  for (int ks = 0; ks < 8; ++ks) {
    bf16x8 nbh, nbl, nah[2], nal[2];
    if (ks < 7) {
      size_t bo = ((size_t)(ntile*8 + ks + 1)*64 + lane)*8;
      nbh = *(const bf16x8*)&owh[bo];
      nbl = *(const bf16x8*)&owl[bo];
      #pragma unroll
      for (int rt = 0; rt < 2; ++rt) {
        size_t ao = (size_t)(r0 + rt*16 + lr)*256 + (ks+1)*32 + lq*8;
        nah[rt] = *(const bf16x8*)&yh[ao];
        nal[rt] = *(const bf16x8*)&yl[ao];
      }
    }
    #pragma unroll
    for (int rt = 0; rt < 2; ++rt) {
      acc[rt] = __builtin_amdgcn_mfma_f32_16x16x32_bf16(ah[rt], bh, acc[rt], 0, 0, 0);
      acc[rt] = __builtin_amdgcn_mfma_f32_16x16x32_bf16(ah[rt], bl, acc[rt], 0, 0, 0);
      acc[rt] = __builtin_amdgcn_mfma_f32_16x16x32_bf16(al[rt], bh, acc[rt], 0, 0, 0);
    }
    if (ks < 7) {
      bh = nbh; bl = nbl;
      #pragma unroll
      for (int rt = 0; rt < 2; ++rt) { ah[rt] = nah[rt]; al[rt] = nal[rt]; }
    }
  }
  const int col = ntile*16 + lr;
  if (col < NCLS) {
    float bb = ob[col];
    #pragma unroll
    for (int rt = 0; rt < 2; ++rt)
      #pragma unroll
      for (int r = 0; r < 4; ++r)
        out[(size_t)(r0 + rt*16 + lq*4 + r)*NCLS + col] = acc[rt][r] + bb;
  }
}

// ================= launch =================
extern "C" void kernel_launch(void* const* d_in, const int* in_sizes, int n_in,
                              void* d_out, int out_size, void* d_ws, size_t ws_size,
                              hipStream_t stream) {
  const float* x   = (const float*)d_in[0];
  const float* c1w = (const float*)d_in[1];
  const float* c1b = (const float*)d_in[2];
  const float* c2w = (const float*)d_in[3];
  const float* c2b = (const float*)d_in[4];
  const float* c3w = (const float*)d_in[5];
  const float* c3b = (const float*)d_in[6];
  const float* fcw = (const float*)d_in[7];
  const float* fcb = (const float*)d_in[8];
  const float* gw  = (const float*)d_in[9];
  const float* gb  = (const float*)d_in[10];
  const float* ew1 = (const float*)d_in[11];
  const float* eb1 = (const float*)d_in[12];
  const float* ew2 = (const float*)d_in[13];
  const float* eb2 = (const float*)d_in[14];
  const float* lng = (const float*)d_in[15];
  const float* lnb = (const float*)d_in[16];
  const float* ow  = (const float*)d_in[17];
  const float* ob  = (const float*)d_in[18];
  char* ws = (char*)d_ws;
  const bool bigws = ws_size >= WS_BIG;   // host-side branch, resolved at capture time
  const size_t oW1TH = bigws ? OFF2_W1TH : OFF_W1TH;
  const size_t oW1TL = bigws ? OFF2_W1TL : OFF_W1TL;
  const size_t oW2TH = bigws ? OFF2_W2TH : OFF_W2TH;
  const size_t oW2TL = bigws ? OFF2_W2TL : OFF_W2TL;
  const size_t oWFCH = bigws ? OFF2_WFCH : OFF_WFCH;
  const size_t oWFCL = bigws ? OFF2_WFCL : OFF_WFCL;
  const size_t oOWH  = bigws ? OFF2_OWH  : OFF_OWH;
  const size_t oOWL  = bigws ? OFF2_OWL  : OFF_OWL;

  float* Bb   = (float*)(ws + OFF_B);
  float* P0   = (float*)(ws + OFF_P0);
  float* P1   = (float*)(ws + OFF_P1);
  float* P2   = (float*)(ws + OFF_P2);
  float* P3   = (float*)(ws + OFF_P3);
  unsigned short* Chh = (unsigned short*)(ws + OFF_CHH);
  unsigned short* Chl = (unsigned short*)(ws + OFF_CHL);
  unsigned short* wBh = (unsigned short*)(ws + OFF_CHH);   // aliases Chh (written after conv12)
  unsigned short* wBl = (unsigned short*)(ws + OFF_WBL);
  unsigned short* wA1h = (unsigned short*)(ws + OFF_WA1H);
  unsigned short* wA1l = (unsigned short*)(ws + OFF_WA1L);
  unsigned short* wAh = (unsigned short*)(ws + OFF_FEAT);  // aliases feat (written later)
  unsigned short* wAl = (unsigned short*)(ws + OFF_WAL);
  unsigned short* w1th = (unsigned short*)(ws + oW1TH);
  unsigned short* w1tl = (unsigned short*)(ws + oW1TL);
  unsigned short* w2th = (unsigned short*)(ws + oW2TH);
  unsigned short* w2tl = (unsigned short*)(ws + oW2TL);
  unsigned short* wfh = (unsigned short*)(ws + oWFCH);
  unsigned short* wfl = (unsigned short*)(ws + oWFCL);
  unsigned short* owph = (unsigned short*)(ws + oOWH);
  unsigned short* owpl = (unsigned short*)(ws + oOWL);
  unsigned short* yh = (unsigned short*)(ws + OFF_P0);     // aliases P0 (dead after gate)
  unsigned short* yl = (unsigned short*)(ws + OFF_P1);     // aliases P1
  float* feat = (float*)(ws + OFF_FEAT);
  float* moe  = (float*)(ws + OFF_MOE);
  int*   cnt  = (int*)(ws + OFF_CNT);
  float* gsum = (float*)(ws + OFF_GSUM);
  int*   lrow = (int*)(ws + OFF_LROW);
  float* lgv  = (float*)(ws + OFF_LG);
  float* outp = (float*)d_out;

  hipMemsetAsync(ws + OFF_MOE, 0, 4194304 + 128, stream);

  hipLaunchKernelGGL(k_wprep,  dim3(364),     dim3(256), 0, stream,
                     c1w, wA1h, wA1l, c2w, wBh, wBl, c3w, wAh, wAl);
  hipLaunchKernelGGL(k_conv12, dim3(4096),    dim3(512), 0, stream, x, wA1h, wA1l, c1b, wBh, wBl, c2b, Bb);
  // conv3; in big-ws mode the extra 3200 blocks run the weight packs concurrently
  hipLaunchKernelGGL(k_conv3,  dim3(bigws ? 7296 : 4096), dim3(256), 0, stream,
                     Bb, wAh, wAl, c3b, Chh, Chl,
                     ew1, w1th, w1tl, ew2, w2th, w2tl, fcw, wfh, wfl, ow, owph, owpl);
  if (!bigws)   // fallback: packed weights alias Bb -> must pack after conv3, standalone
    hipLaunchKernelGGL(k_packall, dim3(3200), dim3(256), 0, stream,
                       ew1, w1th, w1tl, ew2, w2th, w2tl, fcw, wfh, wfl, ow, owph, owpl);
  hipLaunchKernelGGL(k_fc,     dim3(128, 1, 4), dim3(256), 0, stream, Chh, Chl, wfh, wfl, P0, P1, P2, P3);
  hipLaunchKernelGGL(k_gate,   dim3(256),     dim3(256), 0, stream, P0, P1, P2, P3, fcb, gw, gb,
                     feat, cnt, gsum, lrow, lgv);
  hipLaunchKernelGGL(k_moe,    dim3(128, 16, 8), dim3(256), 0, stream, feat, w1th, w1tl, w2th, w2tl,
                     eb1, eb2, cnt, lrow, lgv, moe);
  hipLaunchKernelGGL(k_ln,     dim3(4097),    dim3(256), 0, stream, feat, moe, lng, lnb, yh, yl,
                     gsum, outp + (size_t)NB*NCLS);
  hipLaunchKernelGGL(k_out,    dim3(128, 16), dim3(256), 0, stream, yh, yl, owph, owpl, ob, outp);
}

// Round 28
// 719.211 us; speedup vs baseline: 1.1315x; 1.0151x over previous
//
#include <hip/hip_runtime.h>
#include <hip/hip_bf16.h>

typedef short bf16x8 __attribute__((ext_vector_type(8)));
typedef float f32x4 __attribute__((ext_vector_type(4)));

// ---------------- problem sizes ----------------
#define NB   4096
#define NEXP 16
#define DDIM 256
#define HDIM 1024
#define NCLS 1000

// ---------------- workspace layout (bytes) ----------------
// Base layout (always valid). If ws_size >= WS_BIG, packed weights move to the
// relocated region (no Bb alias) and k_packall fuses into conv3's grid.
#define OFF_B    ((size_t)0)
#define OFF_P0   ((size_t)0)           // f32 [4096][256] FC partial (kq 0); ALSO yh after gate
#define OFF_P1   ((size_t)4194304)     // f32 [4096][256] FC partial (kq 1); ALSO yl after gate
#define OFF_W1TH ((size_t)8388608)     // bf16 packed [16][64 ht][8 ks][64 lane][8]  8 MB
#define OFF_W1TL ((size_t)16777216)
#define OFF_W2TH ((size_t)25165824)    // bf16 packed [16][16 dt][32 ks][64 lane][8] 8 MB
#define OFF_W2TL ((size_t)33554432)
#define OFF_WFCH ((size_t)41943040)    // fcw packed hi (1 MB)
#define OFF_WFCL ((size_t)42991616)    // fcw packed lo (1 MB)
#define OFF_P2   ((size_t)44040192)    // f32 [4096][256] FC partial (kq 2)
#define OFF_P3   ((size_t)48234496)    // f32 [4096][256] FC partial (kq 3)
#define OFF_OWH  ((size_t)52428800)    // ow packed hi [64 nt][8 ks][64][8] (512 KB)
#define OFF_OWL  ((size_t)53477376)
#define OFF_CHH  ((size_t)67108864)    // conv3 out hi bf16 [4096][2048]; ALSO wBh/wBl/wA1 before conv12
#define OFF_CHL  ((size_t)83886080)    // conv3 out lo bf16
#define OFF_WBL  ((size_t)67145728)
#define OFF_WA1H ((size_t)67182592)
#define OFF_WA1L ((size_t)67184640)
#define OFF_FEAT ((size_t)100663296)   // f32 [4096][256]; ALSO wAh/wAl (288 KB) before k_gate
#define OFF_WAL  ((size_t)100810752)
#define OFF_MOE  ((size_t)104857600)   // f32 [4096][256]
#define OFF_CNT  ((size_t)109051904)   // int [16]
#define OFF_GSUM ((size_t)109051968)   // f32 [16]
#define OFF_LROW ((size_t)109052032)   // int [16][4096]
#define OFF_LG   ((size_t)109314176)   // f32 [16][4096]  (ends 109576320)
// relocated packed-weight region (no alias with Bb) for the fused-pack path:
#define OFF2_W1TH ((size_t)109600768)
#define OFF2_W1TL ((size_t)117989376)
#define OFF2_W2TH ((size_t)126377984)
#define OFF2_W2TL ((size_t)134766592)
#define OFF2_WFCH ((size_t)143155200)
#define OFF2_WFCL ((size_t)144203776)
#define OFF2_OWH  ((size_t)145252352)
#define OFF2_OWL  ((size_t)146300928)
#define WS_BIG    ((size_t)147349504)

__device__ inline unsigned short f2bf(float v) {
  __hip_bfloat16 h = __float2bfloat16(v);
  return *(unsigned short*)&h;
}
__device__ inline float bf2f(unsigned short u) {
  union { unsigned int i; float f; } c; c.i = ((unsigned int)u) << 16; return c.f;
}

// ====== merged weight prep: conv1(1024) + conv2(18432) + conv3(73728) elems, range-split
__global__ __launch_bounds__(256) void k_wprep(
    const float* __restrict__ c1w, unsigned short* __restrict__ a1h, unsigned short* __restrict__ a1l,
    const float* __restrict__ c2w, unsigned short* __restrict__ b2h, unsigned short* __restrict__ b2l,
    const float* __restrict__ c3w, unsigned short* __restrict__ a3h, unsigned short* __restrict__ a3l) {
  int i = blockIdx.x*256 + threadIdx.x;   // over 93184
  if (i < 1024) {
    int k = i & 31, oc = i >> 5;
    float v = (k < 27) ? c1w[oc*27 + k] : 0.f;
    unsigned short h = f2bf(v);
    a1h[i] = h; a1l[i] = f2bf(v - bf2f(h));
  } else if (i < 19456) {
    int j = i - 1024;
    int ic = j & 31, rem = j >> 5;
    int oc = rem & 63, tap = rem >> 6;
    float v = c2w[(oc*32 + ic)*9 + tap];
    unsigned short h = f2bf(v);
    b2h[j] = h; b2l[j] = f2bf(v - bf2f(h));
  } else if (i < 93184) {
    int j = i - 19456;
    int ic = j & 63, rem = j >> 6;
    int oc = rem & 127, tap = rem >> 7;
    float v = c3w[(oc*64 + ic)*9 + tap];
    unsigned short h = f2bf(v);
    a3h[j] = h; a3l[j] = f2bf(v - bf2f(h));
  }
}

// ====== generic pack body: in[e][R][C] -> packed hi/lo
__device__ inline void pack_body(const float* __restrict__ in,
    unsigned short* __restrict__ oh, unsigned short* __restrict__ ol,
    int R, int C, int bx, int by, int e, int t, float (*tile)[65]) {
  const size_t eb = (size_t)e * R * C;
  const int c0 = bx*64, r0 = by*64;
  const int cc = t & 63, r4 = t >> 6;
  #pragma unroll
  for (int j = 0; j < 16; ++j) {
    int rr = r4 + j*4;
    tile[rr][cc] = in[eb + (size_t)(r0+rr)*C + c0 + cc];
  }
  __syncthreads();
  const int K32 = R >> 5;
  #pragma unroll
  for (int j = 0; j < 16; ++j) {
    int idx = t + j*256;
    int jin = idx & 7, lane = (idx >> 3) & 63, ksl = (idx >> 9) & 1, ntl = idx >> 10;
    int kl = ksl*32 + ((lane >> 4) << 3) + jin;
    int nl = ntl*16 + (lane & 15);
    float v = tile[kl][nl];
    unsigned short h = f2bf(v);
    size_t o = eb + ((size_t)(((c0 >> 4) + ntl)*K32 + (r0 >> 5) + ksl)*64 + lane)*8 + jin;
    oh[o] = h;
    ol[o] = f2bf(v - bf2f(h));
  }
}

// ====== pack block dispatch (shared by k_packall and fused conv3 path)
__device__ inline void pack_dispatch(int b, int t, float (*tile)[65],
    const float* __restrict__ ew1, unsigned short* __restrict__ w1th, unsigned short* __restrict__ w1tl,
    const float* __restrict__ ew2, unsigned short* __restrict__ w2th, unsigned short* __restrict__ w2tl,
    const float* __restrict__ fcw, unsigned short* __restrict__ wfh,  unsigned short* __restrict__ wfl,
    const float* __restrict__ ow,  unsigned short* __restrict__ owh,  unsigned short* __restrict__ owl) {
  if (b < 1024) {                       // ew1: R=256, C=1024
    int bx = b & 15, by = (b >> 4) & 3, e = b >> 6;
    pack_body(ew1, w1th, w1tl, 256, 1024, bx, by, e, t, tile);
  } else if (b < 2048) {                // ew2: R=1024, C=256
    int lb = b - 1024;
    int bx = lb & 3, by = (lb >> 2) & 15, e = lb >> 6;
    pack_body(ew2, w2th, w2tl, 1024, 256, bx, by, e, t, tile);
  } else if (b < 2176) {                // fcw: R=2048, C=256
    int lb = b - 2048;
    int bx = lb & 3, by = lb >> 2;
    pack_body(fcw, wfh, wfl, 2048, 256, bx, by, 0, t, tile);
  } else {                              // ow pack (elementwise)
    int lb = b - 2176;
    int i = lb*256 + t;                 // over 262144
    int j = i & 7, lane = (i >> 3) & 63, ks = (i >> 9) & 7, nt = i >> 12;
    int k = ks*32 + ((lane >> 4) << 3) + j;
    int n = nt*16 + (lane & 15);
    float v = (n < NCLS) ? ow[(size_t)k*NCLS + n] : 0.f;
    unsigned short h = f2bf(v);
    owh[i] = h;
    owl[i] = f2bf(v - bf2f(h));
  }
}

// ====== standalone merged packs (fallback path when ws is small)
__global__ __launch_bounds__(256) void k_packall(
    const float* __restrict__ ew1, unsigned short* __restrict__ w1th, unsigned short* __restrict__ w1tl,
    const float* __restrict__ ew2, unsigned short* __restrict__ w2th, unsigned short* __restrict__ w2tl,
    const float* __restrict__ fcw, unsigned short* __restrict__ wfh,  unsigned short* __restrict__ wfl,
    const float* __restrict__ ow,  unsigned short* __restrict__ owh,  unsigned short* __restrict__ owl) {
  __shared__ float tile[64][65];
  pack_dispatch(blockIdx.x, threadIdx.x, tile,
                ew1, w1th, w1tl, ew2, w2th, w2tl, fcw, wfh, wfl, ow, owh, owl);
}

// ============ fused conv1(reg-im2col bf16x2 MFMA) + conv2(bf16x2 MFMA, 3-term) per image ====
// R27: padded-k loads made unconditional via 1152-word zero tail after xsu (removes
// 128 v_cndmask/thread). LDS 71.5 KB, still 2 blocks/CU. Values bit-exact.
__global__ __launch_bounds__(512, 4) void k_conv12(const float* __restrict__ x,
    const unsigned short* __restrict__ wA1h, const unsigned short* __restrict__ wA1l,
    const float* __restrict__ b1,
    const unsigned short* __restrict__ wBh, const unsigned short* __restrict__ wBl,
    const float* __restrict__ b2, float* __restrict__ outB) {
  __shared__ unsigned int xsu[3*34*36 + 1152]; // packed bf16 image + zero tail (19.3 KB)
  __shared__ __align__(16) unsigned short ishB[2][12960]; // [pl][5 slots][8] padded (51.8 KB)
  __shared__ float bs1[32];
  __shared__ float bs2[64];
  const int t = threadIdx.x;
  const int img = blockIdx.x;
  for (int i = t; i < 3*34*36 + 1152; i += 512) xsu[i] = 0u;
  {
    // border-only zero: pls with y==0, y==17, x==0 or x==17; 20 u32 per pl per plane
    unsigned int* z = (unsigned int*)&ishB[0][0];
    for (int i = t; i < 2720; i += 512) {
      int plane = i / 1360, rem = i - plane*1360;
      int b = rem / 20, o = rem - b*20;
      int pl;
      if (b < 18)      pl = b;                    // y = 0
      else if (b < 36) pl = 306 + (b - 18);       // y = 17
      else if (b < 52) pl = (b - 35) * 18;        // x = 0,  y = 1..16
      else             pl = (b - 51) * 18 + 17;   // x = 17, y = 1..16
      z[plane*6480 + pl*20 + o] = 0u;
    }
  }
  __syncthreads();
  for (int i = t; i < 3072; i += 512) {
    int ic = i >> 10, rem = i & 1023, y = rem >> 5, xx = rem & 31;
    float v = x[(size_t)img*3072 + i];
    unsigned short h = f2bf(v);
    unsigned short l = f2bf(v - bf2f(h));
    xsu[ic*34*36 + (y+1)*36 + (xx+1)] = ((unsigned int)l << 16) | (unsigned int)h;
  }
  if (t < 32) bs1[t] = b1[t];
  else if (t >= 64 && t < 128) bs2[t-64] = b2[t-64];

  const int lane = t & 63, wvv = t >> 6;
  const int lr = lane & 15, lq = lane >> 4;

  const int oct1 = wvv & 1;
  const bf16x8 a1h = *(const bf16x8*)&wA1h[((oct1*16 + lr) << 5) + lq*8];
  const bf16x8 a1l = *(const bf16x8*)&wA1l[((oct1*16 + lr) << 5) + lq*8];

  int koff[8];
  #pragma unroll
  for (int j = 0; j < 8; ++j) {
    int k = lq*8 + j;
    if (k < 27) {
      int ic = k/9, tap = k - ic*9, dy = tap/3, dx = tap - dy*3;
      koff[j] = ic*34*36 + dy*36 + dx;
    } else koff[j] = 3*34*36;            // zero tail -> loads return 0 unconditionally
  }
  __syncthreads();

  // ---- conv1 via MFMA, barrier-free: 8 passes of 4 pre-pool rows ----
  {
    const int rp  = wvv >> 1;
    const int ly0 = (rp >> 1) << 1;      // 0 or 2
    const int xh  = rp & 1;
    const int X   = xh*16 + lr;
    for (int ps = 0; ps < 8; ++ps) {
      const int baseA = (ps*4 + ly0)*36 + X;
      f32x4 aA = (f32x4){0.f,0.f,0.f,0.f}, aB = (f32x4){0.f,0.f,0.f,0.f};
      {
        union { unsigned int u[4]; bf16x8 v; } bh_, bl_;
        #pragma unroll
        for (int jj = 0; jj < 4; ++jj) {
          unsigned int e0 = xsu[koff[2*jj]   + baseA];
          unsigned int e1 = xsu[koff[2*jj+1] + baseA];
          bh_.u[jj] = __builtin_amdgcn_perm(e1, e0, 0x05040100u);
          bl_.u[jj] = __builtin_amdgcn_perm(e1, e0, 0x07060302u);
        }
        aA = __builtin_amdgcn_mfma_f32_16x16x32_bf16(a1h, bh_.v, aA, 0, 0, 0);
        aA = __builtin_amdgcn_mfma_f32_16x16x32_bf16(a1h, bl_.v, aA, 0, 0, 0);
        aA = __builtin_amdgcn_mfma_f32_16x16x32_bf16(a1l, bh_.v, aA, 0, 0, 0);
      }
      {
        union { unsigned int u[4]; bf16x8 v; } bh_, bl_;
        #pragma unroll
        for (int jj = 0; jj < 4; ++jj) {
          unsigned int e0 = xsu[koff[2*jj]   + baseA + 36];
          unsigned int e1 = xsu[koff[2*jj+1] + baseA + 36];
          bh_.u[jj] = __builtin_amdgcn_perm(e1, e0, 0x05040100u);
          bl_.u[jj] = __builtin_amdgcn_perm(e1, e0, 0x07060302u);
        }
        aB = __builtin_amdgcn_mfma_f32_16x16x32_bf16(a1h, bh_.v, aB, 0, 0, 0);
        aB = __builtin_amdgcn_mfma_f32_16x16x32_bf16(a1h, bl_.v, aB, 0, 0, 0);
        aB = __builtin_amdgcn_mfma_f32_16x16x32_bf16(a1l, bh_.v, aB, 0, 0, 0);
      }
      #pragma unroll
      for (int r = 0; r < 4; ++r) {
        float v = fmaxf(aA[r], aB[r]);
        v = fmaxf(v, __shfl_xor(v, 1, 64));
        if ((lr & 1) == 0) {
          int oc = oct1*16 + lq*4 + r;
          int Xp = xh*8 + (lr >> 1);
          int Yp = ps*2 + (ly0 >> 1);
          float m = fmaxf(v + bs1[oc], 0.f);
          unsigned short h = f2bf(m);
          unsigned short l = f2bf(m - bf2f(h));
          int pl = (Yp+1)*18 + (Xp+1);
          int us = (pl*5 + (oc >> 3))*8 + (oc & 7);   // padded layout, slot = oc>>3
          ishB[0][us] = h; ishB[1][us] = l;
        }
      }
    }
  }
  __syncthreads();
  // ---- conv2 bf16x2 MFMA (3-term) + fused pool + relu; A loaded directly per tap ----
  {
    const int mtp = (wvv & 1)*2;
    const int rq = wvv >> 1;
    f32x4 acc[2][4];
    #pragma unroll
    for (int i = 0; i < 2; ++i)
      #pragma unroll
      for (int j = 0; j < 4; ++j) acc[i][j] = (f32x4){0.f,0.f,0.f,0.f};
    #pragma unroll
    for (int tap = 0; tap < 9; ++tap) {
      const int off0 = ((tap*64 + mtp*16     + lr) << 5) + lq*8;
      const int off1 = ((tap*64 + (mtp+1)*16 + lr) << 5) + lq*8;
      bf16x8 ah0 = *(const bf16x8*)&wBh[off0];
      bf16x8 al0 = *(const bf16x8*)&wBl[off0];
      bf16x8 ah1 = *(const bf16x8*)&wBh[off1];
      bf16x8 al1 = *(const bf16x8*)&wBl[off1];
      const int dy = tap/3, dx = tap - dy*3;
      #pragma unroll
      for (int j = 0; j < 4; ++j) {
        int pl = (rq*4 + j + dy)*18 + lr + dx;
        int slot = pl*5 + lq;                        // padded layout, slot = lq
        bf16x8 bh = *(const bf16x8*)&ishB[0][slot << 3];
        bf16x8 bl = *(const bf16x8*)&ishB[1][slot << 3];
        acc[0][j] = __builtin_amdgcn_mfma_f32_16x16x32_bf16(ah0, bh, acc[0][j], 0, 0, 0);
        acc[1][j] = __builtin_amdgcn_mfma_f32_16x16x32_bf16(ah1, bh, acc[1][j], 0, 0, 0);
        acc[0][j] = __builtin_amdgcn_mfma_f32_16x16x32_bf16(ah0, bl, acc[0][j], 0, 0, 0);
        acc[1][j] = __builtin_amdgcn_mfma_f32_16x16x32_bf16(ah1, bl, acc[1][j], 0, 0, 0);
        acc[0][j] = __builtin_amdgcn_mfma_f32_16x16x32_bf16(al0, bh, acc[0][j], 0, 0, 0);
        acc[1][j] = __builtin_amdgcn_mfma_f32_16x16x32_bf16(al1, bh, acc[1][j], 0, 0, 0);
      }
    }
    __syncthreads();
    float* ps2 = (float*)&ishB[0][0];
    #pragma unroll
    for (int m = 0; m < 2; ++m)
      #pragma unroll
      for (int k = 0; k < 2; ++k)
        #pragma unroll
        for (int r = 0; r < 4; ++r) {
          float v = fmaxf(acc[m][2*k][r], acc[m][2*k+1][r]);
          v = fmaxf(v, __shfl_xor(v, 1, 64));
          if ((lr & 1) == 0) {
            int oc = (mtp + m)*16 + lq*4 + r;
            int Y = rq*2 + k, X = lr >> 1;
            ps2[oc*65 + Y*8 + X] = fmaxf(v + bs2[oc], 0.f);
          }
        }
    __syncthreads();
    float* op = outB + (size_t)img*4096;
    #pragma unroll
    for (int jj = 0; jj < 8; ++jj) {
      int i = jj*512 + t;
      op[i] = ps2[(i >> 6)*65 + (i & 63)];
    }
  }
}

// ================= conv3 v7: bf16x2 split MFMA, prefetch-pipelined weights (R28) =========
// R27 PMC: MfmaUtil 25, VALUBusy 30, Occ 33 -> ~45% idle = exposed weight-load latency
// (18 serialized L2 round-trips/block). Flatten (tap,kc) -> 18 its, preload it+1's 4 frags
// before it's 24 MFMAs. Flattened MFMA order identical -> bit-exact.
__global__ __launch_bounds__(256) void k_conv3(const float* __restrict__ inB,
    const unsigned short* __restrict__ wAh, const unsigned short* __restrict__ wAl,
    const float* __restrict__ bias,
    unsigned short* __restrict__ Chh, unsigned short* __restrict__ Chl,
    const float* __restrict__ ew1, unsigned short* __restrict__ w1th, unsigned short* __restrict__ w1tl,
    const float* __restrict__ ew2, unsigned short* __restrict__ w2th, unsigned short* __restrict__ w2tl,
    const float* __restrict__ fcw, unsigned short* __restrict__ wfh,  unsigned short* __restrict__ wfl,
    const float* __restrict__ ow,  unsigned short* __restrict__ owh,  unsigned short* __restrict__ owl) {
  __shared__ unsigned short ish[2][6400];
  const int t = threadIdx.x;
  if (blockIdx.x >= 4096) {       // fused pack blocks (only present in big-ws path)
    float (*tile)[65] = (float(*)[65])&ish[0][0];   // 16.6 KB <= 25.6 KB
    pack_dispatch(blockIdx.x - 4096, t, tile,
                  ew1, w1th, w1tl, ew2, w2th, w2tl, fcw, wfh, wfl, ow, owh, owl);
    return;
  }
  const int img = blockIdx.x;
  {
    unsigned int* z = (unsigned int*)&ish[0][0];
    #pragma unroll
    for (int j = 0; j < 25; ++j) z[t + 256*j] = 0u;
  }
  __syncthreads();
  {
    const float* src = inB + (size_t)img*4096;
    #pragma unroll
    for (int j = 0; j < 16; ++j) {
      int f = t + 256*j;
      int ic = f >> 6, p = f & 63;
      int pl = ((p >> 3) + 1)*10 + (p & 7) + 1;
      float v = src[f];
      unsigned short h = f2bf(v);
      unsigned short l = f2bf(v - bf2f(h));
      int u = pl*64 + ic;
      int us = (((u >> 3) ^ (pl & 7)) << 3) | (u & 7);
      ish[0][us] = h; ish[1][us] = l;
    }
  }
  __syncthreads();

  const int lane = t & 63, wid = t >> 6;
  const int lr = lane & 15, lq = lane >> 4;
  const int mt0 = wid*2;
  const int yb = lr >> 3, xb = lr & 7;
  const int wrow0 = (mt0*16 + lr) << 6;
  const int wrow1 = ((mt0+1)*16 + lr) << 6;

  f32x4 acc[2][4];
  #pragma unroll
  for (int i = 0; i < 2; ++i)
    #pragma unroll
    for (int j = 0; j < 4; ++j) acc[i][j] = (f32x4){0.f,0.f,0.f,0.f};

  // prefetch it=0 (tap=0, kc=0)
  bf16x8 a0h, a0l, a1h, a1l;
  {
    const int wb = lq*8;
    a0h = *(const bf16x8*)&wAh[wb + wrow0];
    a0l = *(const bf16x8*)&wAl[wb + wrow0];
    a1h = *(const bf16x8*)&wAh[wb + wrow1];
    a1l = *(const bf16x8*)&wAl[wb + wrow1];
  }
  for (int it = 0; it < 18; ++it) {
    const int tap = it >> 1, kc = it & 1;
    bf16x8 n0h, n0l, n1h, n1l;
    if (it < 17) {
      const int tap2 = (it+1) >> 1, kc2 = (it+1) & 1;
      const int wb2 = ((tap2 << 7) << 6) + kc2*32 + lq*8;
      n0h = *(const bf16x8*)&wAh[wb2 + wrow0];
      n0l = *(const bf16x8*)&wAl[wb2 + wrow0];
      n1h = *(const bf16x8*)&wAh[wb2 + wrow1];
      n1l = *(const bf16x8*)&wAl[wb2 + wrow1];
    }
    const int dy = tap/3, dx = tap - dy*3;
    const int kb = kc*32 + lq*8;
    #pragma unroll
    for (int nt = 0; nt < 4; ++nt) {
      const int pl = (2*nt + yb + dy)*10 + xb + dx;
      const int u = pl*64 + kb;
      const int us = (((u >> 3) ^ (pl & 7)) << 3);
      bf16x8 bh = *(const bf16x8*)&ish[0][us];
      bf16x8 bl = *(const bf16x8*)&ish[1][us];
      acc[0][nt] = __builtin_amdgcn_mfma_f32_16x16x32_bf16(a0h, bh, acc[0][nt], 0, 0, 0);
      acc[0][nt] = __builtin_amdgcn_mfma_f32_16x16x32_bf16(a0h, bl, acc[0][nt], 0, 0, 0);
      acc[0][nt] = __builtin_amdgcn_mfma_f32_16x16x32_bf16(a0l, bh, acc[0][nt], 0, 0, 0);
      acc[1][nt] = __builtin_amdgcn_mfma_f32_16x16x32_bf16(a1h, bh, acc[1][nt], 0, 0, 0);
      acc[1][nt] = __builtin_amdgcn_mfma_f32_16x16x32_bf16(a1h, bl, acc[1][nt], 0, 0, 0);
      acc[1][nt] = __builtin_amdgcn_mfma_f32_16x16x32_bf16(a1l, bh, acc[1][nt], 0, 0, 0);
    }
    if (it < 17) { a0h = n0h; a0l = n0l; a1h = n1h; a1l = n1l; }
  }
  __syncthreads();
  float* stg = (float*)&ish[0][0];   // [128 oc][17]
  #pragma unroll
  for (int mtl = 0; mtl < 2; ++mtl)
    #pragma unroll
    for (int nt = 0; nt < 4; ++nt)
      #pragma unroll
      for (int r = 0; r < 4; ++r) {
        float v = acc[mtl][nt][r];
        v = fmaxf(v, __shfl_xor(v, 1, 64));
        v = fmaxf(v, __shfl_xor(v, 8, 64));
        if ((lane & 9) == 0) {
          int oc = (mt0 + mtl)*16 + lq*4 + r;
          int pix = nt*4 + (xb >> 1);
          stg[oc*17 + pix] = fmaxf(v + bias[oc], 0.f);
        }
      }
  __syncthreads();
  #pragma unroll
  for (int j = 0; j < 8; ++j) {
    int i = t + 256*j;
    float v = stg[(i >> 4)*17 + (i & 15)];
    unsigned short h = f2bf(v);
    Chh[(size_t)img*2048 + i] = h;
    Chl[(size_t)img*2048 + i] = f2bf(v - bf2f(h));
  }
}

// ================= FC GEMM v3: bf16x2 3-term MFMA, no LDS, split-K=4, prefetch dbuf ======
__global__ __launch_bounds__(256) void k_fc(const unsigned short* __restrict__ Chh,
    const unsigned short* __restrict__ Chl,
    const unsigned short* __restrict__ wfh, const unsigned short* __restrict__ wfl,
    float* __restrict__ P0, float* __restrict__ P1,
    float* __restrict__ P2, float* __restrict__ P3) {
  const int t = threadIdx.x;
  const int r0 = blockIdx.x * 32;
  const int kq = blockIdx.z;
  float* __restrict__ P = (kq == 0) ? P0 : (kq == 1) ? P1 : (kq == 2) ? P2 : P3;
  const int lane = t & 63, wv = t >> 6;
  const int lr = lane & 15, lq = lane >> 4;
  f32x4 acc[2][4];
  #pragma unroll
  for (int i = 0; i < 2; ++i)
    #pragma unroll
    for (int j = 0; j < 4; ++j) acc[i][j] = (f32x4){0.f,0.f,0.f,0.f};
  bf16x8 ah[2], al[2], bh[4], bl[4];
  #pragma unroll
  for (int rt = 0; rt < 2; ++rt) {
    size_t ao = (size_t)(r0 + rt*16 + lr)*2048 + kq*512 + lq*8;
    ah[rt] = *(const bf16x8*)&Chh[ao];
    al[rt] = *(const bf16x8*)&Chl[ao];
  }
  #pragma unroll
  for (int nt = 0; nt < 4; ++nt) {
    size_t bo = ((size_t)((wv*4 + nt)*64 + kq*16)*64 + lane)*8;
    bh[nt] = *(const bf16x8*)&wfh[bo];
    bl[nt] = *(const bf16x8*)&wfl[bo];
  }
  #pragma unroll 4
  for (int ks = 0; ks < 16; ++ks) {
    bf16x8 nah[2], nal[2], nbh[4], nbl[4];
    if (ks < 15) {
      #pragma unroll
      for (int rt = 0; rt < 2; ++rt) {
        size_t ao = (size_t)(r0 + rt*16 + lr)*2048 + kq*512 + (ks+1)*32 + lq*8;
        nah[rt] = *(const bf16x8*)&Chh[ao];
        nal[rt] = *(const bf16x8*)&Chl[ao];
      }
      #pragma unroll
      for (int nt = 0; nt < 4; ++nt) {
        size_t bo = ((size_t)((wv*4 + nt)*64 + kq*16 + ks + 1)*64 + lane)*8;
        nbh[nt] = *(const bf16x8*)&wfh[bo];
        nbl[nt] = *(const bf16x8*)&wfl[bo];
      }
    }
    #pragma unroll
    for (int nt = 0; nt < 4; ++nt) {
      acc[0][nt] = __builtin_amdgcn_mfma_f32_16x16x32_bf16(ah[0], bh[nt], acc[0][nt], 0, 0, 0);
      acc[1][nt] = __builtin_amdgcn_mfma_f32_16x16x32_bf16(ah[1], bh[nt], acc[1][nt], 0, 0, 0);
      acc[0][nt] = __builtin_amdgcn_mfma_f32_16x16x32_bf16(ah[0], bl[nt], acc[0][nt], 0, 0, 0);
      acc[1][nt] = __builtin_amdgcn_mfma_f32_16x16x32_bf16(ah[1], bl[nt], acc[1][nt], 0, 0, 0);
      acc[0][nt] = __builtin_amdgcn_mfma_f32_16x16x32_bf16(al[0], bh[nt], acc[0][nt], 0, 0, 0);
      acc[1][nt] = __builtin_amdgcn_mfma_f32_16x16x32_bf16(al[1], bh[nt], acc[1][nt], 0, 0, 0);
    }
    if (ks < 15) {
      #pragma unroll
      for (int rt = 0; rt < 2; ++rt) { ah[rt] = nah[rt]; al[rt] = nal[rt]; }
      #pragma unroll
      for (int nt = 0; nt < 4; ++nt) { bh[nt] = nbh[nt]; bl[nt] = nbl[nt]; }
    }
  }
  #pragma unroll
  for (int rt = 0; rt < 2; ++rt)
    #pragma unroll
    for (int nt = 0; nt < 4; ++nt)
      #pragma unroll
      for (int r = 0; r < 4; ++r)
        P[(size_t)(r0 + rt*16 + lq*4 + r)*256 + (wv*4 + nt)*16 + lr] = acc[rt][nt][r];
}

// ================= gate: feat = P0+P1+P2+P3+fcb; logits; top-2 softmax; expert lists
__global__ __launch_bounds__(256) void k_gate(const float* __restrict__ P0,
    const float* __restrict__ P1, const float* __restrict__ P2, const float* __restrict__ P3,
    const float* __restrict__ fcb,
    const float* __restrict__ gw, const float* __restrict__ gb,
    float* __restrict__ feat, int* __restrict__ cnt, float* __restrict__ gsum,
    int* __restrict__ lrow, float* __restrict__ lg) {
  __shared__ float ft[16][256];
  __shared__ float lgs[16][16];
  __shared__ float gwl[4096];
  const int t = threadIdx.x;
  const int r0 = blockIdx.x * 16;
  for (int i = t; i < 4096; i += 256) gwl[i] = gw[i];
  float bb = fcb[t];
  #pragma unroll
  for (int r = 0; r < 16; ++r) {
    size_t off = (size_t)(r0+r)*256 + t;
    float v = P0[off] + P1[off] + P2[off] + P3[off] + bb;
    ft[r][t] = v;
    feat[off] = v;
  }
  __syncthreads();
  {
    int r = t >> 4, e = t & 15;
    float s = gb[e];
    for (int k = 0; k < 256; ++k) s = fmaf(ft[r][k], gwl[k*16 + e], s);
    lgs[r][e] = s;
  }
  __syncthreads();
  if (t < 16) {
    int r = t;
    float v1 = -3.402823e38f, v2 = -3.402823e38f;
    int i1 = 0, i2 = 0;
    for (int e = 0; e < 16; ++e) {
      float v = lgs[r][e];
      if (v > v1)      { v2 = v1; i2 = i1; v1 = v; i1 = e; }
      else if (v > v2) { v2 = v;  i2 = e; }
    }
    float ex = __expf(v2 - v1);
    float g1 = 1.f / (1.f + ex);
    float g2 = ex  / (1.f + ex);
    int row = r0 + r;
    int p1 = atomicAdd(&cnt[i1], 1); lrow[i1*4096 + p1] = row; lg[i1*4096 + p1] = g1;
    int p2 = atomicAdd(&cnt[i2], 1); lrow[i2*4096 + p2] = row; lg[i2*4096 + p2] = g2;
    atomicAdd(&gsum[i1], g1);
    atomicAdd(&gsum[i2], g2);
  }
}

// ================= MoE v5: 32-row tiles x split-K(8), prefetch-pipelined weights ========
__global__ __launch_bounds__(256) void k_moe(const float* __restrict__ feat,
    const unsigned short* __restrict__ w1th, const unsigned short* __restrict__ w1tl,
    const unsigned short* __restrict__ w2th, const unsigned short* __restrict__ w2tl,
    const float* __restrict__ eb1, const float* __restrict__ eb2,
    const int* __restrict__ cnt, const int* __restrict__ lrow, const float* __restrict__ lgw,
    float* __restrict__ moe) {
  const int e = blockIdx.y;
  const int n_e = cnt[e];
  const int start = blockIdx.x * 32;
  if (start >= n_e) return;
  const int c = blockIdx.z;
  const int n = min(32, n_e - start);
  __shared__ unsigned short fh[8192], fl[8192];
  __shared__ unsigned short h1h[4096], h1l[4096];
  __shared__ int   rws[32];
  __shared__ float gws[32];
  const int t = threadIdx.x;
  if (t < 32) {
    rws[t] = (t < n) ? lrow[e*4096 + start + t] : 0;
    gws[t] = (t < n) ? lgw[e*4096 + start + t] : 0.f;
  }
  __syncthreads();
  for (int j = 0; j < 32; ++j) {
    float v = (j < n) ? feat[(size_t)rws[j]*256 + t] : 0.f;
    unsigned short h = f2bf(v);
    int us = (j*32 + ((t >> 3) ^ (j & 7)))*8 + (t & 7);
    fh[us] = h; fl[us] = f2bf(v - bf2f(h));
  }
  const int lane = t & 63, wv = t >> 6;
  const int lr = lane & 15, lq = lane >> 4;
  const int rh = wv & 1, qh = wv >> 1;
  const int arow = rh*16 + lr;
  const int rsw = arow & 7;
  const size_t ewb = (size_t)e << 18;

  f32x4 acc2[8];
  #pragma unroll
  for (int i = 0; i < 8; ++i) acc2[i] = (f32x4){0.f,0.f,0.f,0.f};

  __syncthreads();

  {
    // -------- GEMM1: K=256 (8 ks), 4 htiles/wave; prefetch ks+1 weights --------
    f32x4 acc1[4];
    #pragma unroll
    for (int i = 0; i < 4; ++i) acc1[i] = (f32x4){0.f,0.f,0.f,0.f};
    bf16x8 wbh[4], wbl[4];
    #pragma unroll
    for (int ht = 0; ht < 4; ++ht) {
      size_t bo = ewb + ((size_t)((c*8 + qh*4 + ht)*8 + 0)*64 + lane)*8;
      wbh[ht] = *(const bf16x8*)&w1th[bo];
      wbl[ht] = *(const bf16x8*)&w1tl[bo];
    }
    #pragma unroll
    for (int ks = 0; ks < 8; ++ks) {
      bf16x8 nbh[4], nbl[4];
      if (ks < 7) {
        #pragma unroll
        for (int ht = 0; ht < 4; ++ht) {
          size_t bo = ewb + ((size_t)((c*8 + qh*4 + ht)*8 + ks + 1)*64 + lane)*8;
          nbh[ht] = *(const bf16x8*)&w1th[bo];
          nbl[ht] = *(const bf16x8*)&w1tl[bo];
        }
      }
      int aoff = (arow*32 + ((ks*4 + lq) ^ rsw))*8;
      bf16x8 ah = *(const bf16x8*)&fh[aoff];
      bf16x8 al = *(const bf16x8*)&fl[aoff];
      #pragma unroll
      for (int ht = 0; ht < 4; ++ht) {
        acc1[ht] = __builtin_amdgcn_mfma_f32_16x16x32_bf16(ah, wbh[ht], acc1[ht], 0, 0, 0);
        acc1[ht] = __builtin_amdgcn_mfma_f32_16x16x32_bf16(ah, wbl[ht], acc1[ht], 0, 0, 0);
        acc1[ht] = __builtin_amdgcn_mfma_f32_16x16x32_bf16(al, wbh[ht], acc1[ht], 0, 0, 0);
      }
      if (ks < 7) {
        #pragma unroll
        for (int ht = 0; ht < 4; ++ht) { wbh[ht] = nbh[ht]; wbl[ht] = nbl[ht]; }
      }
    }
    __syncthreads();
    #pragma unroll
    for (int ht = 0; ht < 4; ++ht) {
      int hloc = qh*64 + ht*16 + lr;
      float bb = eb1[e*1024 + c*128 + hloc];
      #pragma unroll
      for (int r = 0; r < 4; ++r) {
        int orow = rh*16 + lq*4 + r;
        float v = fmaxf(acc1[ht][r] + bb, 0.f);
        unsigned short hh = f2bf(v);
        int us = (orow*16 + ((hloc >> 3) ^ (orow & 7)))*8 + (hloc & 7);
        h1h[us] = hh; h1l[us] = f2bf(v - bf2f(hh));
      }
    }
    __syncthreads();
    // -------- GEMM2: K=128 local (4 ks), 8 dtiles/wave; prefetch per half-dt group ----
    bf16x8 w2h[4], w2l[4];
    #pragma unroll
    for (int dt = 0; dt < 4; ++dt) {
      size_t bo = ewb + ((size_t)((qh*8 + dt)*32 + c*4 + 0)*64 + lane)*8;
      w2h[dt] = *(const bf16x8*)&w2th[bo];
      w2l[dt] = *(const bf16x8*)&w2tl[bo];
    }
    #pragma unroll
    for (int g = 0; g < 8; ++g) {
      const int ks = g >> 1, dth = (g & 1)*4;
      bf16x8 nh[4], nl[4];
      if (g < 7) {
        const int ks2 = (g+1) >> 1, dth2 = ((g+1) & 1)*4;
        #pragma unroll
        for (int dt = 0; dt < 4; ++dt) {
          size_t bo = ewb + ((size_t)((qh*8 + dth2 + dt)*32 + c*4 + ks2)*64 + lane)*8;
          nh[dt] = *(const bf16x8*)&w2th[bo];
          nl[dt] = *(const bf16x8*)&w2tl[bo];
        }
      }
      int aoff = (arow*16 + ((ks*4 + lq) ^ rsw))*8;
      bf16x8 ah = *(const bf16x8*)&h1h[aoff];
      bf16x8 al = *(const bf16x8*)&h1l[aoff];
      #pragma unroll
      for (int dt = 0; dt < 4; ++dt) {
        acc2[dth+dt] = __builtin_amdgcn_mfma_f32_16x16x32_bf16(ah, w2h[dt], acc2[dth+dt], 0, 0, 0);
        acc2[dth+dt] = __builtin_amdgcn_mfma_f32_16x16x32_bf16(ah, w2l[dt], acc2[dth+dt], 0, 0, 0);
        acc2[dth+dt] = __builtin_amdgcn_mfma_f32_16x16x32_bf16(al, w2h[dt], acc2[dth+dt], 0, 0, 0);
      }
      if (g < 7) {
        #pragma unroll
        for (int dt = 0; dt < 4; ++dt) { w2h[dt] = nh[dt]; w2l[dt] = nl[dt]; }
      }
    }
  }
  #pragma unroll
  for (int dt = 0; dt < 8; ++dt) {
    int d = qh*128 + dt*16 + lr;
    float b2 = (c == 0) ? eb2[e*256 + d] : 0.f;
    #pragma unroll
    for (int r = 0; r < 4; ++r) {
      int orow = rh*16 + lq*4 + r;
      if (orow < n)
        atomicAdd(&moe[(size_t)rws[orow]*256 + d], gws[orow]*(acc2[dt][r] + b2));
    }
  }
}

// ================= LayerNorm(moe + feat) -> y bf16 hi/lo; block 4096 computes lb_loss ======
__global__ __launch_bounds__(256) void k_ln(const float* __restrict__ feat,
    const float* __restrict__ moe, const float* __restrict__ g, const float* __restrict__ bp,
    unsigned short* __restrict__ yh, unsigned short* __restrict__ yl,
    const float* __restrict__ gsum, float* __restrict__ out_lb) {
  const int r = blockIdx.x, t = threadIdx.x;
  if (r == NB) {            // lb block: wave 0 only, no barriers on this path
    if (t < 64) {
      float term = 0.f;
      if (t < 16) {
        float D = gsum[t] * (1.f/4096.f);
        term = D * logf(D + 1e-8f);
      }
      #pragma unroll
      for (int o = 8; o > 0; o >>= 1) term += __shfl_down(term, o, 64);
      if (t == 0) *out_lb = term;
    }
    return;
  }
  float v = moe[(size_t)r*256 + t] + feat[(size_t)r*256 + t];
  float s = v, q = v * v;
  #pragma unroll
  for (int o = 32; o > 0; o >>= 1) {
    s += __shfl_down(s, o, 64);
    q += __shfl_down(q, o, 64);
  }
  __shared__ float ss[4], qq[4];
  int wv = t >> 6;
  if ((t & 63) == 0) { ss[wv] = s; qq[wv] = q; }
  __syncthreads();
  float S = ss[0]+ss[1]+ss[2]+ss[3];
  float Q = qq[0]+qq[1]+qq[2]+qq[3];
  float mu  = S * (1.f/256.f);
  float var = Q * (1.f/256.f) - mu*mu;
  float inv = rsqrtf(var + 1e-5f);
  float y = (v - mu) * inv * g[t] + bp[t];
  unsigned short h = f2bf(y);
  yh[(size_t)r*256 + t] = h;
  yl[(size_t)r*256 + t] = f2bf(y - bf2f(h));
}

// ================= output GEMM v3: bf16x2 3-term MFMA, no LDS, prefetch dbuf ============
__global__ __launch_bounds__(256) void k_out(const unsigned short* __restrict__ yh,
    const unsigned short* __restrict__ yl,
    const unsigned short* __restrict__ owh, const unsigned short* __restrict__ owl,
    const float* __restrict__ ob, float* __restrict__ out) {
  const int t = threadIdx.x;
  const int r0 = blockIdx.x * 32;
  const int lane = t & 63, wv = t >> 6;
  const int lr = lane & 15, lq = lane >> 4;
  const int ntile = blockIdx.y*4 + wv;
  f32x4 acc[2];
  acc[0] = (f32x4){0.f,0.f,0.f,0.f};
  acc[1] = (f32x4){0.f,0.f,0.f,0.f};
  bf16x8 bh, bl, ah[2], al[2];
  {
    size_t bo = ((size_t)(ntile*8)*64 + lane)*8;
    bh = *(const bf16x8*)&owh[bo];
    bl = *(const bf16x8*)&owl[bo];
  }
  #pragma unroll
  for (int rt = 0; rt < 2; ++rt) {
    size_t ao = (size_t)(r0 + rt*16 + lr)*256 + lq*8;
    ah[rt] = *(const bf16x8*)&yh[ao];
    al[rt] = *(const bf16x8*)&yl[ao];
  }
  #pragma unroll
  for (int ks = 0; ks < 8; ++ks) {
    bf16x8 nbh, nbl, nah[2], nal[2];
    if (ks < 7) {
      size_t bo = ((size_t)(ntile*8 + ks + 1)*64 + lane)*8;
      nbh = *(const bf16x8*)&owh[bo];
      nbl = *(const bf16x8*)&owl[bo];
      #pragma unroll
      for (int rt = 0; rt < 2; ++rt) {
        size_t ao = (size_t)(r0 + rt*16 + lr)*256 + (ks+1)*32 + lq*8;
        nah[rt] = *(const bf16x8*)&yh[ao];
        nal[rt] = *(const bf16x8*)&yl[ao];
      }
    }
    #pragma unroll
    for (int rt = 0; rt < 2; ++rt) {
      acc[rt] = __builtin_amdgcn_mfma_f32_16x16x32_bf16(ah[rt], bh, acc[rt], 0, 0, 0);
      acc[rt] = __builtin_amdgcn_mfma_f32_16x16x32_bf16(ah[rt], bl, acc[rt], 0, 0, 0);
      acc[rt] = __builtin_amdgcn_mfma_f32_16x16x32_bf16(al[rt], bh, acc[rt], 0, 0, 0);
    }
    if (ks < 7) {
      bh = nbh; bl = nbl;
      #pragma unroll
      for (int rt = 0; rt < 2; ++rt) { ah[rt] = nah[rt]; al[rt] = nal[rt]; }
    }
  }
  const int col = ntile*16 + lr;
  if (col < NCLS) {
    float bb = ob[col];
    #pragma unroll
    for (int rt = 0; rt < 2; ++rt)
      #pragma unroll
      for (int r = 0; r < 4; ++r)
        out[(size_t)(r0 + rt*16 + lq*4 + r)*NCLS + col] = acc[rt][r] + bb;
  }
}

// ================= launch =================
extern "C" void kernel_launch(void* const* d_in, const int* in_sizes, int n_in,
                              void* d_out, int out_size, void* d_ws, size_t ws_size,
                              hipStream_t stream) {
  const float* x   = (const float*)d_in[0];
  const float* c1w = (const float*)d_in[1];
  const float* c1b = (const float*)d_in[2];
  const float* c2w = (const float*)d_in[3];
  const float* c2b = (const float*)d_in[4];
  const float* c3w = (const float*)d_in[5];
  const float* c3b = (const float*)d_in[6];
  const float* fcw = (const float*)d_in[7];
  const float* fcb = (const float*)d_in[8];
  const float* gw  = (const float*)d_in[9];
  const float* gb  = (const float*)d_in[10];
  const float* ew1 = (const float*)d_in[11];
  const float* eb1 = (const float*)d_in[12];
  const float* ew2 = (const float*)d_in[13];
  const float* eb2 = (const float*)d_in[14];
  const float* lng = (const float*)d_in[15];
  const float* lnb = (const float*)d_in[16];
  const float* ow  = (const float*)d_in[17];
  const float* ob  = (const float*)d_in[18];
  char* ws = (char*)d_ws;
  const bool bigws = ws_size >= WS_BIG;   // host-side branch, resolved at capture time
  const size_t oW1TH = bigws ? OFF2_W1TH : OFF_W1TH;
  const size_t oW1TL = bigws ? OFF2_W1TL : OFF_W1TL;
  const size_t oW2TH = bigws ? OFF2_W2TH : OFF_W2TH;
  const size_t oW2TL = bigws ? OFF2_W2TL : OFF_W2TL;
  const size_t oWFCH = bigws ? OFF2_WFCH : OFF_WFCH;
  const size_t oWFCL = bigws ? OFF2_WFCL : OFF_WFCL;
  const size_t oOWH  = bigws ? OFF2_OWH  : OFF_OWH;
  const size_t oOWL  = bigws ? OFF2_OWL  : OFF_OWL;

  float* Bb   = (float*)(ws + OFF_B);
  float* P0   = (float*)(ws + OFF_P0);
  float* P1   = (float*)(ws + OFF_P1);
  float* P2   = (float*)(ws + OFF_P2);
  float* P3   = (float*)(ws + OFF_P3);
  unsigned short* Chh = (unsigned short*)(ws + OFF_CHH);
  unsigned short* Chl = (unsigned short*)(ws + OFF_CHL);
  unsigned short* wBh = (unsigned short*)(ws + OFF_CHH);   // aliases Chh (written after conv12)
  unsigned short* wBl = (unsigned short*)(ws + OFF_WBL);
  unsigned short* wA1h = (unsigned short*)(ws + OFF_WA1H);
  unsigned short* wA1l = (unsigned short*)(ws + OFF_WA1L);
  unsigned short* wAh = (unsigned short*)(ws + OFF_FEAT);  // aliases feat (written later)
  unsigned short* wAl = (unsigned short*)(ws + OFF_WAL);
  unsigned short* w1th = (unsigned short*)(ws + oW1TH);
  unsigned short* w1tl = (unsigned short*)(ws + oW1TL);
  unsigned short* w2th = (unsigned short*)(ws + oW2TH);
  unsigned short* w2tl = (unsigned short*)(ws + oW2TL);
  unsigned short* wfh = (unsigned short*)(ws + oWFCH);
  unsigned short* wfl = (unsigned short*)(ws + oWFCL);
  unsigned short* owph = (unsigned short*)(ws + oOWH);
  unsigned short* owpl = (unsigned short*)(ws + oOWL);
  unsigned short* yh = (unsigned short*)(ws + OFF_P0);     // aliases P0 (dead after gate)
  unsigned short* yl = (unsigned short*)(ws + OFF_P1);     // aliases P1
  float* feat = (float*)(ws + OFF_FEAT);
  float* moe  = (float*)(ws + OFF_MOE);
  int*   cnt  = (int*)(ws + OFF_CNT);
  float* gsum = (float*)(ws + OFF_GSUM);
  int*   lrow = (int*)(ws + OFF_LROW);
  float* lgv  = (float*)(ws + OFF_LG);
  float* outp = (float*)d_out;

  hipMemsetAsync(ws + OFF_MOE, 0, 4194304 + 128, stream);

  hipLaunchKernelGGL(k_wprep,  dim3(364),     dim3(256), 0, stream,
                     c1w, wA1h, wA1l, c2w, wBh, wBl, c3w, wAh, wAl);
  hipLaunchKernelGGL(k_conv12, dim3(4096),    dim3(512), 0, stream, x, wA1h, wA1l, c1b, wBh, wBl, c2b, Bb);
  // conv3; in big-ws mode the extra 3200 blocks run the weight packs concurrently
  hipLaunchKernelGGL(k_conv3,  dim3(bigws ? 7296 : 4096), dim3(256), 0, stream,
                     Bb, wAh, wAl, c3b, Chh, Chl,
                     ew1, w1th, w1tl, ew2, w2th, w2tl, fcw, wfh, wfl, ow, owph, owpl);
  if (!bigws)   // fallback: packed weights alias Bb -> must pack after conv3, standalone
    hipLaunchKernelGGL(k_packall, dim3(3200), dim3(256), 0, stream,
                       ew1, w1th, w1tl, ew2, w2th, w2tl, fcw, wfh, wfl, ow, owph, owpl);
  hipLaunchKernelGGL(k_fc,     dim3(128, 1, 4), dim3(256), 0, stream, Chh, Chl, wfh, wfl, P0, P1, P2, P3);
  hipLaunchKernelGGL(k_gate,   dim3(256),     dim3(256), 0, stream, P0, P1, P2, P3, fcb, gw, gb,
                     feat, cnt, gsum, lrow, lgv);
  hipLaunchKernelGGL(k_moe,    dim3(128, 16, 8), dim3(256), 0, stream, feat, w1th, w1tl, w2th, w2tl,
                     eb1, eb2, cnt, lrow, lgv, moe);
  hipLaunchKernelGGL(k_ln,     dim3(4097),    dim3(256), 0, stream, feat, moe, lng, lnb, yh, yl,
                     gsum, outp + (size_t)NB*NCLS);
  hipLaunchKernelGGL(k_out,    dim3(128, 16), dim3(256), 0, stream, yh, yl, owph, owpl, ob, outp);
}

// Round 29
// 647.124 us; speedup vs baseline: 1.2575x; 1.1114x over previous
//
#include <hip/hip_runtime.h>
#include <hip/hip_bf16.h>

typedef short bf16x8 __attribute__((ext_vector_type(8)));
typedef float f32x4 __attribute__((ext_vector_type(4)));

// ---------------- problem sizes ----------------
#define NB   4096
#define NEXP 16
#define DDIM 256
#define HDIM 1024
#define NCLS 1000

// ---------------- workspace layout (bytes) ----------------
// Base layout (always valid). If ws_size >= WS_BIG, packed weights move to the
// relocated region (no Bb alias) and k_packall fuses into conv3's grid.
#define OFF_B    ((size_t)0)
#define OFF_P0   ((size_t)0)           // f32 [4096][256] FC partial (kq 0); ALSO yh after gate
#define OFF_P1   ((size_t)4194304)     // f32 [4096][256] FC partial (kq 1); ALSO yl after gate
#define OFF_W1TH ((size_t)8388608)     // bf16 packed [16][64 ht][8 ks][64 lane][8]  8 MB
#define OFF_W1TL ((size_t)16777216)
#define OFF_W2TH ((size_t)25165824)    // bf16 packed [16][16 dt][32 ks][64 lane][8] 8 MB
#define OFF_W2TL ((size_t)33554432)
#define OFF_WFCH ((size_t)41943040)    // fcw packed hi (1 MB)
#define OFF_WFCL ((size_t)42991616)    // fcw packed lo (1 MB)
#define OFF_P2   ((size_t)44040192)    // f32 [4096][256] FC partial (kq 2)
#define OFF_P3   ((size_t)48234496)    // f32 [4096][256] FC partial (kq 3)
#define OFF_OWH  ((size_t)52428800)    // ow packed hi [64 nt][8 ks][64][8] (512 KB)
#define OFF_OWL  ((size_t)53477376)
#define OFF_CHH  ((size_t)67108864)    // conv3 out hi bf16 [4096][2048]; ALSO wBh/wBl/wA1 before conv12
#define OFF_CHL  ((size_t)83886080)    // conv3 out lo bf16
#define OFF_WBL  ((size_t)67145728)
#define OFF_WA1H ((size_t)67182592)
#define OFF_WA1L ((size_t)67184640)
#define OFF_FEAT ((size_t)100663296)   // f32 [4096][256]; ALSO wAh/wAl (288 KB) before k_gate
#define OFF_WAL  ((size_t)100810752)
#define OFF_MOE  ((size_t)104857600)   // f32 [4096][256]
#define OFF_CNT  ((size_t)109051904)   // int [16]
#define OFF_GSUM ((size_t)109051968)   // f32 [16]
#define OFF_LROW ((size_t)109052032)   // int [16][4096]
#define OFF_LG   ((size_t)109314176)   // f32 [16][4096]  (ends 109576320)
// relocated packed-weight region (no alias with Bb) for the fused-pack path:
#define OFF2_W1TH ((size_t)109600768)
#define OFF2_W1TL ((size_t)117989376)
#define OFF2_W2TH ((size_t)126377984)
#define OFF2_W2TL ((size_t)134766592)
#define OFF2_WFCH ((size_t)143155200)
#define OFF2_WFCL ((size_t)144203776)
#define OFF2_OWH  ((size_t)145252352)
#define OFF2_OWL  ((size_t)146300928)
#define WS_BIG    ((size_t)147349504)

__device__ inline unsigned short f2bf(float v) {
  __hip_bfloat16 h = __float2bfloat16(v);
  return *(unsigned short*)&h;
}
__device__ inline float bf2f(unsigned short u) {
  union { unsigned int i; float f; } c; c.i = ((unsigned int)u) << 16; return c.f;
}

// ====== merged weight prep: conv1(1024) + conv2(18432) + conv3(73728) elems, range-split
__global__ __launch_bounds__(256) void k_wprep(
    const float* __restrict__ c1w, unsigned short* __restrict__ a1h, unsigned short* __restrict__ a1l,
    const float* __restrict__ c2w, unsigned short* __restrict__ b2h, unsigned short* __restrict__ b2l,
    const float* __restrict__ c3w, unsigned short* __restrict__ a3h, unsigned short* __restrict__ a3l) {
  int i = blockIdx.x*256 + threadIdx.x;   // over 93184
  if (i < 1024) {
    int k = i & 31, oc = i >> 5;
    float v = (k < 27) ? c1w[oc*27 + k] : 0.f;
    unsigned short h = f2bf(v);
    a1h[i] = h; a1l[i] = f2bf(v - bf2f(h));
  } else if (i < 19456) {
    int j = i - 1024;
    int ic = j & 31, rem = j >> 5;
    int oc = rem & 63, tap = rem >> 6;
    float v = c2w[(oc*32 + ic)*9 + tap];
    unsigned short h = f2bf(v);
    b2h[j] = h; b2l[j] = f2bf(v - bf2f(h));
  } else if (i < 93184) {
    int j = i - 19456;
    int ic = j & 63, rem = j >> 6;
    int oc = rem & 127, tap = rem >> 7;
    float v = c3w[(oc*64 + ic)*9 + tap];
    unsigned short h = f2bf(v);
    a3h[j] = h; a3l[j] = f2bf(v - bf2f(h));
  }
}

// ====== generic pack body: in[e][R][C] -> packed hi/lo
__device__ inline void pack_body(const float* __restrict__ in,
    unsigned short* __restrict__ oh, unsigned short* __restrict__ ol,
    int R, int C, int bx, int by, int e, int t, float (*tile)[65]) {
  const size_t eb = (size_t)e * R * C;
  const int c0 = bx*64, r0 = by*64;
  const int cc = t & 63, r4 = t >> 6;
  #pragma unroll
  for (int j = 0; j < 16; ++j) {
    int rr = r4 + j*4;
    tile[rr][cc] = in[eb + (size_t)(r0+rr)*C + c0 + cc];
  }
  __syncthreads();
  const int K32 = R >> 5;
  #pragma unroll
  for (int j = 0; j < 16; ++j) {
    int idx = t + j*256;
    int jin = idx & 7, lane = (idx >> 3) & 63, ksl = (idx >> 9) & 1, ntl = idx >> 10;
    int kl = ksl*32 + ((lane >> 4) << 3) + jin;
    int nl = ntl*16 + (lane & 15);
    float v = tile[kl][nl];
    unsigned short h = f2bf(v);
    size_t o = eb + ((size_t)(((c0 >> 4) + ntl)*K32 + (r0 >> 5) + ksl)*64 + lane)*8 + jin;
    oh[o] = h;
    ol[o] = f2bf(v - bf2f(h));
  }
}

// ====== pack block dispatch (shared by k_packall and fused conv3 path)
__device__ inline void pack_dispatch(int b, int t, float (*tile)[65],
    const float* __restrict__ ew1, unsigned short* __restrict__ w1th, unsigned short* __restrict__ w1tl,
    const float* __restrict__ ew2, unsigned short* __restrict__ w2th, unsigned short* __restrict__ w2tl,
    const float* __restrict__ fcw, unsigned short* __restrict__ wfh,  unsigned short* __restrict__ wfl,
    const float* __restrict__ ow,  unsigned short* __restrict__ owh,  unsigned short* __restrict__ owl) {
  if (b < 1024) {                       // ew1: R=256, C=1024
    int bx = b & 15, by = (b >> 4) & 3, e = b >> 6;
    pack_body(ew1, w1th, w1tl, 256, 1024, bx, by, e, t, tile);
  } else if (b < 2048) {                // ew2: R=1024, C=256
    int lb = b - 1024;
    int bx = lb & 3, by = (lb >> 2) & 15, e = lb >> 6;
    pack_body(ew2, w2th, w2tl, 1024, 256, bx, by, e, t, tile);
  } else if (b < 2176) {                // fcw: R=2048, C=256
    int lb = b - 2048;
    int bx = lb & 3, by = lb >> 2;
    pack_body(fcw, wfh, wfl, 2048, 256, bx, by, 0, t, tile);
  } else {                              // ow pack (elementwise)
    int lb = b - 2176;
    int i = lb*256 + t;                 // over 262144
    int j = i & 7, lane = (i >> 3) & 63, ks = (i >> 9) & 7, nt = i >> 12;
    int k = ks*32 + ((lane >> 4) << 3) + j;
    int n = nt*16 + (lane & 15);
    float v = (n < NCLS) ? ow[(size_t)k*NCLS + n] : 0.f;
    unsigned short h = f2bf(v);
    owh[i] = h;
    owl[i] = f2bf(v - bf2f(h));
  }
}

// ====== standalone merged packs (fallback path when ws is small)
__global__ __launch_bounds__(256) void k_packall(
    const float* __restrict__ ew1, unsigned short* __restrict__ w1th, unsigned short* __restrict__ w1tl,
    const float* __restrict__ ew2, unsigned short* __restrict__ w2th, unsigned short* __restrict__ w2tl,
    const float* __restrict__ fcw, unsigned short* __restrict__ wfh,  unsigned short* __restrict__ wfl,
    const float* __restrict__ ow,  unsigned short* __restrict__ owh,  unsigned short* __restrict__ owl) {
  __shared__ float tile[64][65];
  pack_dispatch(blockIdx.x, threadIdx.x, tile,
                ew1, w1th, w1tl, ew2, w2th, w2tl, fcw, wfh, wfl, ow, owh, owl);
}

// ============ fused conv1(reg-im2col bf16x2 MFMA) + conv2(bf16x2 MFMA, 3-term) per image ====
// R27: padded-k loads made unconditional via 1152-word zero tail after xsu (removes
// 128 v_cndmask/thread). LDS 71.5 KB, still 2 blocks/CU. Values bit-exact.
__global__ __launch_bounds__(512, 4) void k_conv12(const float* __restrict__ x,
    const unsigned short* __restrict__ wA1h, const unsigned short* __restrict__ wA1l,
    const float* __restrict__ b1,
    const unsigned short* __restrict__ wBh, const unsigned short* __restrict__ wBl,
    const float* __restrict__ b2, float* __restrict__ outB) {
  __shared__ unsigned int xsu[3*34*36 + 1152]; // packed bf16 image + zero tail (19.3 KB)
  __shared__ __align__(16) unsigned short ishB[2][12960]; // [pl][5 slots][8] padded (51.8 KB)
  __shared__ float bs1[32];
  __shared__ float bs2[64];
  const int t = threadIdx.x;
  const int img = blockIdx.x;
  for (int i = t; i < 3*34*36 + 1152; i += 512) xsu[i] = 0u;
  {
    // border-only zero: pls with y==0, y==17, x==0 or x==17; 20 u32 per pl per plane
    unsigned int* z = (unsigned int*)&ishB[0][0];
    for (int i = t; i < 2720; i += 512) {
      int plane = i / 1360, rem = i - plane*1360;
      int b = rem / 20, o = rem - b*20;
      int pl;
      if (b < 18)      pl = b;                    // y = 0
      else if (b < 36) pl = 306 + (b - 18);       // y = 17
      else if (b < 52) pl = (b - 35) * 18;        // x = 0,  y = 1..16
      else             pl = (b - 51) * 18 + 17;   // x = 17, y = 1..16
      z[plane*6480 + pl*20 + o] = 0u;
    }
  }
  __syncthreads();
  for (int i = t; i < 3072; i += 512) {
    int ic = i >> 10, rem = i & 1023, y = rem >> 5, xx = rem & 31;
    float v = x[(size_t)img*3072 + i];
    unsigned short h = f2bf(v);
    unsigned short l = f2bf(v - bf2f(h));
    xsu[ic*34*36 + (y+1)*36 + (xx+1)] = ((unsigned int)l << 16) | (unsigned int)h;
  }
  if (t < 32) bs1[t] = b1[t];
  else if (t >= 64 && t < 128) bs2[t-64] = b2[t-64];

  const int lane = t & 63, wvv = t >> 6;
  const int lr = lane & 15, lq = lane >> 4;

  const int oct1 = wvv & 1;
  const bf16x8 a1h = *(const bf16x8*)&wA1h[((oct1*16 + lr) << 5) + lq*8];
  const bf16x8 a1l = *(const bf16x8*)&wA1l[((oct1*16 + lr) << 5) + lq*8];

  int koff[8];
  #pragma unroll
  for (int j = 0; j < 8; ++j) {
    int k = lq*8 + j;
    if (k < 27) {
      int ic = k/9, tap = k - ic*9, dy = tap/3, dx = tap - dy*3;
      koff[j] = ic*34*36 + dy*36 + dx;
    } else koff[j] = 3*34*36;            // zero tail -> loads return 0 unconditionally
  }
  __syncthreads();

  // ---- conv1 via MFMA, barrier-free: 8 passes of 4 pre-pool rows ----
  {
    const int rp  = wvv >> 1;
    const int ly0 = (rp >> 1) << 1;      // 0 or 2
    const int xh  = rp & 1;
    const int X   = xh*16 + lr;
    for (int ps = 0; ps < 8; ++ps) {
      const int baseA = (ps*4 + ly0)*36 + X;
      f32x4 aA = (f32x4){0.f,0.f,0.f,0.f}, aB = (f32x4){0.f,0.f,0.f,0.f};
      {
        union { unsigned int u[4]; bf16x8 v; } bh_, bl_;
        #pragma unroll
        for (int jj = 0; jj < 4; ++jj) {
          unsigned int e0 = xsu[koff[2*jj]   + baseA];
          unsigned int e1 = xsu[koff[2*jj+1] + baseA];
          bh_.u[jj] = __builtin_amdgcn_perm(e1, e0, 0x05040100u);
          bl_.u[jj] = __builtin_amdgcn_perm(e1, e0, 0x07060302u);
        }
        aA = __builtin_amdgcn_mfma_f32_16x16x32_bf16(a1h, bh_.v, aA, 0, 0, 0);
        aA = __builtin_amdgcn_mfma_f32_16x16x32_bf16(a1h, bl_.v, aA, 0, 0, 0);
        aA = __builtin_amdgcn_mfma_f32_16x16x32_bf16(a1l, bh_.v, aA, 0, 0, 0);
      }
      {
        union { unsigned int u[4]; bf16x8 v; } bh_, bl_;
        #pragma unroll
        for (int jj = 0; jj < 4; ++jj) {
          unsigned int e0 = xsu[koff[2*jj]   + baseA + 36];
          unsigned int e1 = xsu[koff[2*jj+1] + baseA + 36];
          bh_.u[jj] = __builtin_amdgcn_perm(e1, e0, 0x05040100u);
          bl_.u[jj] = __builtin_amdgcn_perm(e1, e0, 0x07060302u);
        }
        aB = __builtin_amdgcn_mfma_f32_16x16x32_bf16(a1h, bh_.v, aB, 0, 0, 0);
        aB = __builtin_amdgcn_mfma_f32_16x16x32_bf16(a1h, bl_.v, aB, 0, 0, 0);
        aB = __builtin_amdgcn_mfma_f32_16x16x32_bf16(a1l, bh_.v, aB, 0, 0, 0);
      }
      #pragma unroll
      for (int r = 0; r < 4; ++r) {
        float v = fmaxf(aA[r], aB[r]);
        v = fmaxf(v, __shfl_xor(v, 1, 64));
        if ((lr & 1) == 0) {
          int oc = oct1*16 + lq*4 + r;
          int Xp = xh*8 + (lr >> 1);
          int Yp = ps*2 + (ly0 >> 1);
          float m = fmaxf(v + bs1[oc], 0.f);
          unsigned short h = f2bf(m);
          unsigned short l = f2bf(m - bf2f(h));
          int pl = (Yp+1)*18 + (Xp+1);
          int us = (pl*5 + (oc >> 3))*8 + (oc & 7);   // padded layout, slot = oc>>3
          ishB[0][us] = h; ishB[1][us] = l;
        }
      }
    }
  }
  __syncthreads();
  // ---- conv2 bf16x2 MFMA (3-term) + fused pool + relu; A loaded directly per tap ----
  {
    const int mtp = (wvv & 1)*2;
    const int rq = wvv >> 1;
    f32x4 acc[2][4];
    #pragma unroll
    for (int i = 0; i < 2; ++i)
      #pragma unroll
      for (int j = 0; j < 4; ++j) acc[i][j] = (f32x4){0.f,0.f,0.f,0.f};
    #pragma unroll
    for (int tap = 0; tap < 9; ++tap) {
      const int off0 = ((tap*64 + mtp*16     + lr) << 5) + lq*8;
      const int off1 = ((tap*64 + (mtp+1)*16 + lr) << 5) + lq*8;
      bf16x8 ah0 = *(const bf16x8*)&wBh[off0];
      bf16x8 al0 = *(const bf16x8*)&wBl[off0];
      bf16x8 ah1 = *(const bf16x8*)&wBh[off1];
      bf16x8 al1 = *(const bf16x8*)&wBl[off1];
      const int dy = tap/3, dx = tap - dy*3;
      #pragma unroll
      for (int j = 0; j < 4; ++j) {
        int pl = (rq*4 + j + dy)*18 + lr + dx;
        int slot = pl*5 + lq;                        // padded layout, slot = lq
        bf16x8 bh = *(const bf16x8*)&ishB[0][slot << 3];
        bf16x8 bl = *(const bf16x8*)&ishB[1][slot << 3];
        acc[0][j] = __builtin_amdgcn_mfma_f32_16x16x32_bf16(ah0, bh, acc[0][j], 0, 0, 0);
        acc[1][j] = __builtin_amdgcn_mfma_f32_16x16x32_bf16(ah1, bh, acc[1][j], 0, 0, 0);
        acc[0][j] = __builtin_amdgcn_mfma_f32_16x16x32_bf16(ah0, bl, acc[0][j], 0, 0, 0);
        acc[1][j] = __builtin_amdgcn_mfma_f32_16x16x32_bf16(ah1, bl, acc[1][j], 0, 0, 0);
        acc[0][j] = __builtin_amdgcn_mfma_f32_16x16x32_bf16(al0, bh, acc[0][j], 0, 0, 0);
        acc[1][j] = __builtin_amdgcn_mfma_f32_16x16x32_bf16(al1, bh, acc[1][j], 0, 0, 0);
      }
    }
    __syncthreads();
    float* ps2 = (float*)&ishB[0][0];
    #pragma unroll
    for (int m = 0; m < 2; ++m)
      #pragma unroll
      for (int k = 0; k < 2; ++k)
        #pragma unroll
        for (int r = 0; r < 4; ++r) {
          float v = fmaxf(acc[m][2*k][r], acc[m][2*k+1][r]);
          v = fmaxf(v, __shfl_xor(v, 1, 64));
          if ((lr & 1) == 0) {
            int oc = (mtp + m)*16 + lq*4 + r;
            int Y = rq*2 + k, X = lr >> 1;
            ps2[oc*65 + Y*8 + X] = fmaxf(v + bs2[oc], 0.f);
          }
        }
    __syncthreads();
    float* op = outB + (size_t)img*4096;
    #pragma unroll
    for (int jj = 0; jj < 8; ++jj) {
      int i = jj*512 + t;
      op[i] = ps2[(i >> 6)*65 + (i & 63)];
    }
  }
}

// ================= conv3 v7: bf16x2 split MFMA, prefetch-pipelined weights (R28) =========
__global__ __launch_bounds__(256) void k_conv3(const float* __restrict__ inB,
    const unsigned short* __restrict__ wAh, const unsigned short* __restrict__ wAl,
    const float* __restrict__ bias,
    unsigned short* __restrict__ Chh, unsigned short* __restrict__ Chl,
    const float* __restrict__ ew1, unsigned short* __restrict__ w1th, unsigned short* __restrict__ w1tl,
    const float* __restrict__ ew2, unsigned short* __restrict__ w2th, unsigned short* __restrict__ w2tl,
    const float* __restrict__ fcw, unsigned short* __restrict__ wfh,  unsigned short* __restrict__ wfl,
    const float* __restrict__ ow,  unsigned short* __restrict__ owh,  unsigned short* __restrict__ owl) {
  __shared__ unsigned short ish[2][6400];
  const int t = threadIdx.x;
  if (blockIdx.x >= 4096) {       // fused pack blocks (only present in big-ws path)
    float (*tile)[65] = (float(*)[65])&ish[0][0];   // 16.6 KB <= 25.6 KB
    pack_dispatch(blockIdx.x - 4096, t, tile,
                  ew1, w1th, w1tl, ew2, w2th, w2tl, fcw, wfh, wfl, ow, owh, owl);
    return;
  }
  const int img = blockIdx.x;
  {
    unsigned int* z = (unsigned int*)&ish[0][0];
    #pragma unroll
    for (int j = 0; j < 25; ++j) z[t + 256*j] = 0u;
  }
  __syncthreads();
  {
    const float* src = inB + (size_t)img*4096;
    #pragma unroll
    for (int j = 0; j < 16; ++j) {
      int f = t + 256*j;
      int ic = f >> 6, p = f & 63;
      int pl = ((p >> 3) + 1)*10 + (p & 7) + 1;
      float v = src[f];
      unsigned short h = f2bf(v);
      unsigned short l = f2bf(v - bf2f(h));
      int u = pl*64 + ic;
      int us = (((u >> 3) ^ (pl & 7)) << 3) | (u & 7);
      ish[0][us] = h; ish[1][us] = l;
    }
  }
  __syncthreads();

  const int lane = t & 63, wid = t >> 6;
  const int lr = lane & 15, lq = lane >> 4;
  const int mt0 = wid*2;
  const int yb = lr >> 3, xb = lr & 7;
  const int wrow0 = (mt0*16 + lr) << 6;
  const int wrow1 = ((mt0+1)*16 + lr) << 6;

  f32x4 acc[2][4];
  #pragma unroll
  for (int i = 0; i < 2; ++i)
    #pragma unroll
    for (int j = 0; j < 4; ++j) acc[i][j] = (f32x4){0.f,0.f,0.f,0.f};

  // prefetch it=0 (tap=0, kc=0)
  bf16x8 a0h, a0l, a1h, a1l;
  {
    const int wb = lq*8;
    a0h = *(const bf16x8*)&wAh[wb + wrow0];
    a0l = *(const bf16x8*)&wAl[wb + wrow0];
    a1h = *(const bf16x8*)&wAh[wb + wrow1];
    a1l = *(const bf16x8*)&wAl[wb + wrow1];
  }
  for (int it = 0; it < 18; ++it) {
    const int tap = it >> 1, kc = it & 1;
    bf16x8 n0h, n0l, n1h, n1l;
    if (it < 17) {
      const int tap2 = (it+1) >> 1, kc2 = (it+1) & 1;
      const int wb2 = ((tap2 << 7) << 6) + kc2*32 + lq*8;
      n0h = *(const bf16x8*)&wAh[wb2 + wrow0];
      n0l = *(const bf16x8*)&wAl[wb2 + wrow0];
      n1h = *(const bf16x8*)&wAh[wb2 + wrow1];
      n1l = *(const bf16x8*)&wAl[wb2 + wrow1];
    }
    const int dy = tap/3, dx = tap - dy*3;
    const int kb = kc*32 + lq*8;
    #pragma unroll
    for (int nt = 0; nt < 4; ++nt) {
      const int pl = (2*nt + yb + dy)*10 + xb + dx;
      const int u = pl*64 + kb;
      const int us = (((u >> 3) ^ (pl & 7)) << 3);
      bf16x8 bh = *(const bf16x8*)&ish[0][us];
      bf16x8 bl = *(const bf16x8*)&ish[1][us];
      acc[0][nt] = __builtin_amdgcn_mfma_f32_16x16x32_bf16(a0h, bh, acc[0][nt], 0, 0, 0);
      acc[0][nt] = __builtin_amdgcn_mfma_f32_16x16x32_bf16(a0h, bl, acc[0][nt], 0, 0, 0);
      acc[0][nt] = __builtin_amdgcn_mfma_f32_16x16x32_bf16(a0l, bh, acc[0][nt], 0, 0, 0);
      acc[1][nt] = __builtin_amdgcn_mfma_f32_16x16x32_bf16(a1h, bh, acc[1][nt], 0, 0, 0);
      acc[1][nt] = __builtin_amdgcn_mfma_f32_16x16x32_bf16(a1h, bl, acc[1][nt], 0, 0, 0);
      acc[1][nt] = __builtin_amdgcn_mfma_f32_16x16x32_bf16(a1l, bh, acc[1][nt], 0, 0, 0);
    }
    if (it < 17) { a0h = n0h; a0l = n0l; a1h = n1h; a1l = n1l; }
  }
  __syncthreads();
  float* stg = (float*)&ish[0][0];   // [128 oc][17]
  #pragma unroll
  for (int mtl = 0; mtl < 2; ++mtl)
    #pragma unroll
    for (int nt = 0; nt < 4; ++nt)
      #pragma unroll
      for (int r = 0; r < 4; ++r) {
        float v = acc[mtl][nt][r];
        v = fmaxf(v, __shfl_xor(v, 1, 64));
        v = fmaxf(v, __shfl_xor(v, 8, 64));
        if ((lane & 9) == 0) {
          int oc = (mt0 + mtl)*16 + lq*4 + r;
          int pix = nt*4 + (xb >> 1);
          stg[oc*17 + pix] = fmaxf(v + bias[oc], 0.f);
        }
      }
  __syncthreads();
  #pragma unroll
  for (int j = 0; j < 8; ++j) {
    int i = t + 256*j;
    float v = stg[(i >> 4)*17 + (i & 15)];
    unsigned short h = f2bf(v);
    Chh[(size_t)img*2048 + i] = h;
    Chl[(size_t)img*2048 + i] = f2bf(v - bf2f(h));
  }
}

// ================= FC GEMM v3: bf16x2 3-term MFMA, no LDS, split-K=4, prefetch dbuf ======
__global__ __launch_bounds__(256) void k_fc(const unsigned short* __restrict__ Chh,
    const unsigned short* __restrict__ Chl,
    const unsigned short* __restrict__ wfh, const unsigned short* __restrict__ wfl,
    float* __restrict__ P0, float* __restrict__ P1,
    float* __restrict__ P2, float* __restrict__ P3) {
  const int t = threadIdx.x;
  const int r0 = blockIdx.x * 32;
  const int kq = blockIdx.z;
  float* __restrict__ P = (kq == 0) ? P0 : (kq == 1) ? P1 : (kq == 2) ? P2 : P3;
  const int lane = t & 63, wv = t >> 6;
  const int lr = lane & 15, lq = lane >> 4;
  f32x4 acc[2][4];
  #pragma unroll
  for (int i = 0; i < 2; ++i)
    #pragma unroll
    for (int j = 0; j < 4; ++j) acc[i][j] = (f32x4){0.f,0.f,0.f,0.f};
  bf16x8 ah[2], al[2], bh[4], bl[4];
  #pragma unroll
  for (int rt = 0; rt < 2; ++rt) {
    size_t ao = (size_t)(r0 + rt*16 + lr)*2048 + kq*512 + lq*8;
    ah[rt] = *(const bf16x8*)&Chh[ao];
    al[rt] = *(const bf16x8*)&Chl[ao];
  }
  #pragma unroll
  for (int nt = 0; nt < 4; ++nt) {
    size_t bo = ((size_t)((wv*4 + nt)*64 + kq*16)*64 + lane)*8;
    bh[nt] = *(const bf16x8*)&wfh[bo];
    bl[nt] = *(const bf16x8*)&wfl[bo];
  }
  #pragma unroll 4
  for (int ks = 0; ks < 16; ++ks) {
    bf16x8 nah[2], nal[2], nbh[4], nbl[4];
    if (ks < 15) {
      #pragma unroll
      for (int rt = 0; rt < 2; ++rt) {
        size_t ao = (size_t)(r0 + rt*16 + lr)*2048 + kq*512 + (ks+1)*32 + lq*8;
        nah[rt] = *(const bf16x8*)&Chh[ao];
        nal[rt] = *(const bf16x8*)&Chl[ao];
      }
      #pragma unroll
      for (int nt = 0; nt < 4; ++nt) {
        size_t bo = ((size_t)((wv*4 + nt)*64 + kq*16 + ks + 1)*64 + lane)*8;
        nbh[nt] = *(const bf16x8*)&wfh[bo];
        nbl[nt] = *(const bf16x8*)&wfl[bo];
      }
    }
    #pragma unroll
    for (int nt = 0; nt < 4; ++nt) {
      acc[0][nt] = __builtin_amdgcn_mfma_f32_16x16x32_bf16(ah[0], bh[nt], acc[0][nt], 0, 0, 0);
      acc[1][nt] = __builtin_amdgcn_mfma_f32_16x16x32_bf16(ah[1], bh[nt], acc[1][nt], 0, 0, 0);
      acc[0][nt] = __builtin_amdgcn_mfma_f32_16x16x32_bf16(ah[0], bl[nt], acc[0][nt], 0, 0, 0);
      acc[1][nt] = __builtin_amdgcn_mfma_f32_16x16x32_bf16(ah[1], bl[nt], acc[1][nt], 0, 0, 0);
      acc[0][nt] = __builtin_amdgcn_mfma_f32_16x16x32_bf16(al[0], bh[nt], acc[0][nt], 0, 0, 0);
      acc[1][nt] = __builtin_amdgcn_mfma_f32_16x16x32_bf16(al[1], bh[nt], acc[1][nt], 0, 0, 0);
    }
    if (ks < 15) {
      #pragma unroll
      for (int rt = 0; rt < 2; ++rt) { ah[rt] = nah[rt]; al[rt] = nal[rt]; }
      #pragma unroll
      for (int nt = 0; nt < 4; ++nt) { bh[nt] = nbh[nt]; bl[nt] = nbl[nt]; }
    }
  }
  #pragma unroll
  for (int rt = 0; rt < 2; ++rt)
    #pragma unroll
    for (int nt = 0; nt < 4; ++nt)
      #pragma unroll
      for (int r = 0; r < 4; ++r)
        P[(size_t)(r0 + rt*16 + lq*4 + r)*256 + (wv*4 + nt)*16 + lr] = acc[rt][nt][r];
}

// ================= gate: feat = P0+P1+P2+P3+fcb; logits; top-2 softmax; expert lists
__global__ __launch_bounds__(256) void k_gate(const float* __restrict__ P0,
    const float* __restrict__ P1, const float* __restrict__ P2, const float* __restrict__ P3,
    const float* __restrict__ fcb,
    const float* __restrict__ gw, const float* __restrict__ gb,
    float* __restrict__ feat, int* __restrict__ cnt, float* __restrict__ gsum,
    int* __restrict__ lrow, float* __restrict__ lg) {
  __shared__ float ft[16][256];
  __shared__ float lgs[16][16];
  __shared__ float gwl[4096];
  const int t = threadIdx.x;
  const int r0 = blockIdx.x * 16;
  for (int i = t; i < 4096; i += 256) gwl[i] = gw[i];
  float bb = fcb[t];
  #pragma unroll
  for (int r = 0; r < 16; ++r) {
    size_t off = (size_t)(r0+r)*256 + t;
    float v = P0[off] + P1[off] + P2[off] + P3[off] + bb;
    ft[r][t] = v;
    feat[off] = v;
  }
  __syncthreads();
  {
    int r = t >> 4, e = t & 15;
    float s = gb[e];
    for (int k = 0; k < 256; ++k) s = fmaf(ft[r][k], gwl[k*16 + e], s);
    lgs[r][e] = s;
  }
  __syncthreads();
  if (t < 16) {
    int r = t;
    float v1 = -3.402823e38f, v2 = -3.402823e38f;
    int i1 = 0, i2 = 0;
    for (int e = 0; e < 16; ++e) {
      float v = lgs[r][e];
      if (v > v1)      { v2 = v1; i2 = i1; v1 = v; i1 = e; }
      else if (v > v2) { v2 = v;  i2 = e; }
    }
    float ex = __expf(v2 - v1);
    float g1 = 1.f / (1.f + ex);
    float g2 = ex  / (1.f + ex);
    int row = r0 + r;
    int p1 = atomicAdd(&cnt[i1], 1); lrow[i1*4096 + p1] = row; lg[i1*4096 + p1] = g1;
    int p2 = atomicAdd(&cnt[i2], 1); lrow[i2*4096 + p2] = row; lg[i2*4096 + p2] = g2;
    atomicAdd(&gsum[i1], g1);
    atomicAdd(&gsum[i2], g2);
  }
}

// ================= MoE v6 (R29): 16-row tiles x z=4 H/K-split, prefetch-pipelined ========
// z=8->4 + 32->16 rows: same active blocks (~2048), same MFMA/wave (192), but staging
// and atomic traffic HALVE. h1 accumulation chains unchanged (ks asc, 3-term order) ->
// h1 bit-exact; moe sum association differs only where atomics already race (tolerated).
__global__ __launch_bounds__(256) void k_moe(const float* __restrict__ feat,
    const unsigned short* __restrict__ w1th, const unsigned short* __restrict__ w1tl,
    const unsigned short* __restrict__ w2th, const unsigned short* __restrict__ w2tl,
    const float* __restrict__ eb1, const float* __restrict__ eb2,
    const int* __restrict__ cnt, const int* __restrict__ lrow, const float* __restrict__ lgw,
    float* __restrict__ moe) {
  const int e = blockIdx.y;
  const int n_e = cnt[e];
  const int start = blockIdx.x * 16;
  if (start >= n_e) return;
  const int c = blockIdx.z;            // 0..3: H-slice of 256 (GEMM1 N, GEMM2 K)
  const int n = min(16, n_e - start);
  __shared__ unsigned short fh[4096], fl[4096];     // [16 rows][32 grp][8]
  __shared__ unsigned short h1h[4096], h1l[4096];   // [16 rows][32 grp][8]
  __shared__ int   rws[16];
  __shared__ float gws[16];
  const int t = threadIdx.x;
  if (t < 16) {
    rws[t] = (t < n) ? lrow[e*4096 + start + t] : 0;
    gws[t] = (t < n) ? lgw[e*4096 + start + t] : 0.f;
  }
  __syncthreads();
  for (int j = 0; j < 16; ++j) {
    float v = (j < n) ? feat[(size_t)rws[j]*256 + t] : 0.f;
    unsigned short h = f2bf(v);
    int us = (j*32 + ((t >> 3) ^ (j & 7)))*8 + (t & 7);
    fh[us] = h; fl[us] = f2bf(v - bf2f(h));
  }
  const int lane = t & 63, wv = t >> 6;
  const int lr = lane & 15, lq = lane >> 4;
  const int arow = lr;                 // M=16
  const int rsw = arow & 7;
  const size_t ewb = (size_t)e << 18;

  __syncthreads();

  // -------- GEMM1: K=256 (8 ks), 4 htiles/wave (wave N=64, block N=256 = c-slice) ------
  f32x4 acc1[4];
  #pragma unroll
  for (int i = 0; i < 4; ++i) acc1[i] = (f32x4){0.f,0.f,0.f,0.f};
  {
    bf16x8 wbh[4], wbl[4];
    #pragma unroll
    for (int ht = 0; ht < 4; ++ht) {
      size_t bo = ewb + ((size_t)((c*16 + wv*4 + ht)*8 + 0)*64 + lane)*8;
      wbh[ht] = *(const bf16x8*)&w1th[bo];
      wbl[ht] = *(const bf16x8*)&w1tl[bo];
    }
    #pragma unroll
    for (int ks = 0; ks < 8; ++ks) {
      bf16x8 nbh[4], nbl[4];
      if (ks < 7) {
        #pragma unroll
        for (int ht = 0; ht < 4; ++ht) {
          size_t bo = ewb + ((size_t)((c*16 + wv*4 + ht)*8 + ks + 1)*64 + lane)*8;
          nbh[ht] = *(const bf16x8*)&w1th[bo];
          nbl[ht] = *(const bf16x8*)&w1tl[bo];
        }
      }
      int aoff = (arow*32 + ((ks*4 + lq) ^ rsw))*8;
      bf16x8 ah = *(const bf16x8*)&fh[aoff];
      bf16x8 al = *(const bf16x8*)&fl[aoff];
      #pragma unroll
      for (int ht = 0; ht < 4; ++ht) {
        acc1[ht] = __builtin_amdgcn_mfma_f32_16x16x32_bf16(ah, wbh[ht], acc1[ht], 0, 0, 0);
        acc1[ht] = __builtin_amdgcn_mfma_f32_16x16x32_bf16(ah, wbl[ht], acc1[ht], 0, 0, 0);
        acc1[ht] = __builtin_amdgcn_mfma_f32_16x16x32_bf16(al, wbh[ht], acc1[ht], 0, 0, 0);
      }
      if (ks < 7) {
        #pragma unroll
        for (int ht = 0; ht < 4; ++ht) { wbh[ht] = nbh[ht]; wbl[ht] = nbl[ht]; }
      }
    }
  }
  __syncthreads();
  #pragma unroll
  for (int ht = 0; ht < 4; ++ht) {
    int hloc = wv*64 + ht*16 + lr;               // 0..255 within c-slice
    float bb = eb1[e*1024 + c*256 + hloc];
    #pragma unroll
    for (int r = 0; r < 4; ++r) {
      int orow = lq*4 + r;                       // 0..15
      float v = fmaxf(acc1[ht][r] + bb, 0.f);
      unsigned short hh = f2bf(v);
      int us = (orow*32 + ((hloc >> 3) ^ (orow & 7)))*8 + (hloc & 7);
      h1h[us] = hh; h1l[us] = f2bf(v - bf2f(hh));
    }
  }
  __syncthreads();
  // -------- GEMM2: K=256 local (8 ks), 4 dtiles/wave (wave N=64, block N=256) ----------
  f32x4 acc2[4];
  #pragma unroll
  for (int i = 0; i < 4; ++i) acc2[i] = (f32x4){0.f,0.f,0.f,0.f};
  {
    bf16x8 w2h[4], w2l[4];
    #pragma unroll
    for (int dt = 0; dt < 4; ++dt) {
      size_t bo = ewb + ((size_t)((wv*4 + dt)*32 + c*8 + 0)*64 + lane)*8;
      w2h[dt] = *(const bf16x8*)&w2th[bo];
      w2l[dt] = *(const bf16x8*)&w2tl[bo];
    }
    #pragma unroll
    for (int ks = 0; ks < 8; ++ks) {
      bf16x8 nh[4], nl[4];
      if (ks < 7) {
        #pragma unroll
        for (int dt = 0; dt < 4; ++dt) {
          size_t bo = ewb + ((size_t)((wv*4 + dt)*32 + c*8 + ks + 1)*64 + lane)*8;
          nh[dt] = *(const bf16x8*)&w2th[bo];
          nl[dt] = *(const bf16x8*)&w2tl[bo];
        }
      }
      int aoff = (arow*32 + ((ks*4 + lq) ^ rsw))*8;
      bf16x8 ah = *(const bf16x8*)&h1h[aoff];
      bf16x8 al = *(const bf16x8*)&h1l[aoff];
      #pragma unroll
      for (int dt = 0; dt < 4; ++dt) {
        acc2[dt] = __builtin_amdgcn_mfma_f32_16x16x32_bf16(ah, w2h[dt], acc2[dt], 0, 0, 0);
        acc2[dt] = __builtin_amdgcn_mfma_f32_16x16x32_bf16(ah, w2l[dt], acc2[dt], 0, 0, 0);
        acc2[dt] = __builtin_amdgcn_mfma_f32_16x16x32_bf16(al, w2h[dt], acc2[dt], 0, 0, 0);
      }
      if (ks < 7) {
        #pragma unroll
        for (int dt = 0; dt < 4; ++dt) { w2h[dt] = nh[dt]; w2l[dt] = nl[dt]; }
      }
    }
  }
  #pragma unroll
  for (int dt = 0; dt < 4; ++dt) {
    int d = wv*64 + dt*16 + lr;
    float b2 = (c == 0) ? eb2[e*256 + d] : 0.f;
    #pragma unroll
    for (int r = 0; r < 4; ++r) {
      int orow = lq*4 + r;
      if (orow < n)
        atomicAdd(&moe[(size_t)rws[orow]*256 + d], gws[orow]*(acc2[dt][r] + b2));
    }
  }
}

// ================= LayerNorm(moe + feat) -> y bf16 hi/lo; block 4096 computes lb_loss ======
__global__ __launch_bounds__(256) void k_ln(const float* __restrict__ feat,
    const float* __restrict__ moe, const float* __restrict__ g, const float* __restrict__ bp,
    unsigned short* __restrict__ yh, unsigned short* __restrict__ yl,
    const float* __restrict__ gsum, float* __restrict__ out_lb) {
  const int r = blockIdx.x, t = threadIdx.x;
  if (r == NB) {            // lb block: wave 0 only, no barriers on this path
    if (t < 64) {
      float term = 0.f;
      if (t < 16) {
        float D = gsum[t] * (1.f/4096.f);
        term = D * logf(D + 1e-8f);
      }
      #pragma unroll
      for (int o = 8; o > 0; o >>= 1) term += __shfl_down(term, o, 64);
      if (t == 0) *out_lb = term;
    }
    return;
  }
  float v = moe[(size_t)r*256 + t] + feat[(size_t)r*256 + t];
  float s = v, q = v * v;
  #pragma unroll
  for (int o = 32; o > 0; o >>= 1) {
    s += __shfl_down(s, o, 64);
    q += __shfl_down(q, o, 64);
  }
  __shared__ float ss[4], qq[4];
  int wv = t >> 6;
  if ((t & 63) == 0) { ss[wv] = s; qq[wv] = q; }
  __syncthreads();
  float S = ss[0]+ss[1]+ss[2]+ss[3];
  float Q = qq[0]+qq[1]+qq[2]+qq[3];
  float mu  = S * (1.f/256.f);
  float var = Q * (1.f/256.f) - mu*mu;
  float inv = rsqrtf(var + 1e-5f);
  float y = (v - mu) * inv * g[t] + bp[t];
  unsigned short h = f2bf(y);
  yh[(size_t)r*256 + t] = h;
  yl[(size_t)r*256 + t] = f2bf(y - bf2f(h));
}

// ================= output GEMM v3: bf16x2 3-term MFMA, no LDS, prefetch dbuf ============
__global__ __launch_bounds__(256) void k_out(const unsigned short* __restrict__ yh,
    const unsigned short* __restrict__ yl,
    const unsigned short* __restrict__ owh, const unsigned short* __restrict__ owl,
    const float* __restrict__ ob, float* __restrict__ out) {
  const int t = threadIdx.x;
  const int r0 = blockIdx.x * 32;
  const int lane = t & 63, wv = t >> 6;
  const int lr = lane & 15, lq = lane >> 4;
  const int ntile = blockIdx.y*4 + wv;
  f32x4 acc[2];
  acc[0] = (f32x4){0.f,0.f,0.f,0.f};
  acc[1] = (f32x4){0.f,0.f,0.f,0.f};
  bf16x8 bh, bl, ah[2], al[2];
  {
    size_t bo = ((size_t)(ntile*8)*64 + lane)*8;
    bh = *(const bf16x8*)&owh[bo];
    bl = *(const bf16x8*)&owl[bo];
  }
  #pragma unroll
  for (int rt = 0; rt < 2; ++rt) {
    size_t ao = (size_t)(r0 + rt*16 + lr)*256 + lq*8;
    ah[rt] = *(const bf16x8*)&yh[ao];
    al[rt] = *(const bf16x8*)&yl[ao];
  }
  #pragma unroll
  for (int ks = 0; ks < 8; ++ks) {
    bf16x8 nbh, nbl, nah[2], nal[2];
    if (ks < 7) {
      size_t bo = ((size_t)(ntile*8 + ks + 1)*64 + lane)*8;
      nbh = *(const bf16x8*)&owh[bo];
      nbl = *(const bf16x8*)&owl[bo];
      #pragma unroll
      for (int rt = 0; rt < 2; ++rt) {
        size_t ao = (size_t)(r0 + rt*16 + lr)*256 + (ks+1)*32 + lq*8;
        nah[rt] = *(const bf16x8*)&yh[ao];
        nal[rt] = *(const bf16x8*)&yl[ao];
      }
    }
    #pragma unroll
    for (int rt = 0; rt < 2; ++rt) {
      acc[rt] = __builtin_amdgcn_mfma_f32_16x16x32_bf16(ah[rt], bh, acc[rt], 0, 0, 0);
      acc[rt] = __builtin_amdgcn_mfma_f32_16x16x32_bf16(ah[rt], bl, acc[rt], 0, 0, 0);
      acc[rt] = __builtin_amdgcn_mfma_f32_16x16x32_bf16(al[rt], bh, acc[rt], 0, 0, 0);
    }
    if (ks < 7) {
      bh = nbh; bl = nbl;
      #pragma unroll
      for (int rt = 0; rt < 2; ++rt) { ah[rt] = nah[rt]; al[rt] = nal[rt]; }
    }
  }
  const int col = ntile*16 + lr;
  if (col < NCLS) {
    float bb = ob[col];
    #pragma unroll
    for (int rt = 0; rt < 2; ++rt)
      #pragma unroll
      for (int r = 0; r < 4; ++r)
        out[(size_t)(r0 + rt*16 + lq*4 + r)*NCLS + col] = acc[rt][r] + bb;
  }
}

// ================= launch =================
extern "C" void kernel_launch(void* const* d_in, const int* in_sizes, int n_in,
                              void* d_out, int out_size, void* d_ws, size_t ws_size,
                              hipStream_t stream) {
  const float* x   = (const float*)d_in[0];
  const float* c1w = (const float*)d_in[1];
  const float* c1b = (const float*)d_in[2];
  const float* c2w = (const float*)d_in[3];
  const float* c2b = (const float*)d_in[4];
  const float* c3w = (const float*)d_in[5];
  const float* c3b = (const float*)d_in[6];
  const float* fcw = (const float*)d_in[7];
  const float* fcb = (const float*)d_in[8];
  const float* gw  = (const float*)d_in[9];
  const float* gb  = (const float*)d_in[10];
  const float* ew1 = (const float*)d_in[11];
  const float* eb1 = (const float*)d_in[12];
  const float* ew2 = (const float*)d_in[13];
  const float* eb2 = (const float*)d_in[14];
  const float* lng = (const float*)d_in[15];
  const float* lnb = (const float*)d_in[16];
  const float* ow  = (const float*)d_in[17];
  const float* ob  = (const float*)d_in[18];
  char* ws = (char*)d_ws;
  const bool bigws = ws_size >= WS_BIG;   // host-side branch, resolved at capture time
  const size_t oW1TH = bigws ? OFF2_W1TH : OFF_W1TH;
  const size_t oW1TL = bigws ? OFF2_W1TL : OFF_W1TL;
  const size_t oW2TH = bigws ? OFF2_W2TH : OFF_W2TH;
  const size_t oW2TL = bigws ? OFF2_W2TL : OFF_W2TL;
  const size_t oWFCH = bigws ? OFF2_WFCH : OFF_WFCH;
  const size_t oWFCL = bigws ? OFF2_WFCL : OFF_WFCL;
  const size_t oOWH  = bigws ? OFF2_OWH  : OFF_OWH;
  const size_t oOWL  = bigws ? OFF2_OWL  : OFF_OWL;

  float* Bb   = (float*)(ws + OFF_B);
  float* P0   = (float*)(ws + OFF_P0);
  float* P1   = (float*)(ws + OFF_P1);
  float* P2   = (float*)(ws + OFF_P2);
  float* P3   = (float*)(ws + OFF_P3);
  unsigned short* Chh = (unsigned short*)(ws + OFF_CHH);
  unsigned short* Chl = (unsigned short*)(ws + OFF_CHL);
  unsigned short* wBh = (unsigned short*)(ws + OFF_CHH);   // aliases Chh (written after conv12)
  unsigned short* wBl = (unsigned short*)(ws + OFF_WBL);
  unsigned short* wA1h = (unsigned short*)(ws + OFF_WA1H);
  unsigned short* wA1l = (unsigned short*)(ws + OFF_WA1L);
  unsigned short* wAh = (unsigned short*)(ws + OFF_FEAT);  // aliases feat (written later)
  unsigned short* wAl = (unsigned short*)(ws + OFF_WAL);
  unsigned short* w1th = (unsigned short*)(ws + oW1TH);
  unsigned short* w1tl = (unsigned short*)(ws + oW1TL);
  unsigned short* w2th = (unsigned short*)(ws + oW2TH);
  unsigned short* w2tl = (unsigned short*)(ws + oW2TL);
  unsigned short* wfh = (unsigned short*)(ws + oWFCH);
  unsigned short* wfl = (unsigned short*)(ws + oWFCL);
  unsigned short* owph = (unsigned short*)(ws + oOWH);
  unsigned short* owpl = (unsigned short*)(ws + oOWL);
  unsigned short* yh = (unsigned short*)(ws + OFF_P0);     // aliases P0 (dead after gate)
  unsigned short* yl = (unsigned short*)(ws + OFF_P1);     // aliases P1
  float* feat = (float*)(ws + OFF_FEAT);
  float* moe  = (float*)(ws + OFF_MOE);
  int*   cnt  = (int*)(ws + OFF_CNT);
  float* gsum = (float*)(ws + OFF_GSUM);
  int*   lrow = (int*)(ws + OFF_LROW);
  float* lgv  = (float*)(ws + OFF_LG);
  float* outp = (float*)d_out;

  hipMemsetAsync(ws + OFF_MOE, 0, 4194304 + 128, stream);

  hipLaunchKernelGGL(k_wprep,  dim3(364),     dim3(256), 0, stream,
                     c1w, wA1h, wA1l, c2w, wBh, wBl, c3w, wAh, wAl);
  hipLaunchKernelGGL(k_conv12, dim3(4096),    dim3(512), 0, stream, x, wA1h, wA1l, c1b, wBh, wBl, c2b, Bb);
  // conv3; in big-ws mode the extra 3200 blocks run the weight packs concurrently
  hipLaunchKernelGGL(k_conv3,  dim3(bigws ? 7296 : 4096), dim3(256), 0, stream,
                     Bb, wAh, wAl, c3b, Chh, Chl,
                     ew1, w1th, w1tl, ew2, w2th, w2tl, fcw, wfh, wfl, ow, owph, owpl);
  if (!bigws)   // fallback: packed weights alias Bb -> must pack after conv3, standalone
    hipLaunchKernelGGL(k_packall, dim3(3200), dim3(256), 0, stream,
                       ew1, w1th, w1tl, ew2, w2th, w2tl, fcw, wfh, wfl, ow, owph, owpl);
  hipLaunchKernelGGL(k_fc,     dim3(128, 1, 4), dim3(256), 0, stream, Chh, Chl, wfh, wfl, P0, P1, P2, P3);
  hipLaunchKernelGGL(k_gate,   dim3(256),     dim3(256), 0, stream, P0, P1, P2, P3, fcb, gw, gb,
                     feat, cnt, gsum, lrow, lgv);
  hipLaunchKernelGGL(k_moe,    dim3(256, 16, 4), dim3(256), 0, stream, feat, w1th, w1tl, w2th, w2tl,
                     eb1, eb2, cnt, lrow, lgv, moe);
  hipLaunchKernelGGL(k_ln,     dim3(4097),    dim3(256), 0, stream, feat, moe, lng, lnb, yh, yl,
                     gsum, outp + (size_t)NB*NCLS);
  hipLaunchKernelGGL(k_out,    dim3(128, 16), dim3(256), 0, stream, yh, yl, owph, owpl, ob, outp);
}